// Round 1
// baseline (1341.153 us; speedup 1.0000x reference)
//
#include <hip/hip_runtime.h>
#include <hip/hip_bf16.h>
#include <math.h>

#define BB 8
#define NN 1024
#define CC 768
#define HH 8
#define HD 96
#define EE 24
#define NT (BB*NN)          // 8192 tokens
#define NSLOT (NT*HH)       // 65536 (token,h) slots
#define CAP 8192            // per-expert bucket capacity (<= NT since top-k distinct)
#define ASCALE 0.10206207261596575f  // 96^-0.5

// ws layout (bytes)
#define WS_CNT    0                       // 24 int
#define WS_IMP    96                      // 24 f32
#define WS_ZSUM   192                     // 1 f32 (pad to 256)
#define WS_G      256                     // NSLOT f32
#define WS_BUCKET (WS_G + NSLOT*4)        // E*CAP int
#define WS_KV     (WS_BUCKET + EE*CAP*4)  // NT*192 f32
#define WS_Q      (WS_KV + NT*192*4)      // NSLOT*96 f32
#define WS_O      (WS_Q + NSLOT*HD*4)     // NSLOT*96 f32

// ---------------- gating: logits, softmax, top-8, buckets, aux partials ----
__global__ __launch_bounds__(256) void gate_kernel(
    const float* __restrict__ x, const float* __restrict__ Wg_all,
    const int* __restrict__ task_p, float* __restrict__ ws_f,
    int* __restrict__ ws_i)
{
  int w = threadIdx.x >> 6, lane = threadIdx.x & 63;
  int token = blockIdx.x * 4 + w;
  const float* Wg = Wg_all + (size_t)task_p[0] * CC * EE;
  const float* xr = x + (size_t)token * CC;

  float part[EE];
  #pragma unroll
  for (int e = 0; e < EE; e++) part[e] = 0.f;
  for (int c = lane; c < CC; c += 64) {
    float xv = xr[c];
    const float4* w4 = (const float4*)(Wg + c * EE);
    float wv[EE];
    #pragma unroll
    for (int q = 0; q < 6; q++) *(float4*)&wv[q * 4] = w4[q];
    #pragma unroll
    for (int e = 0; e < EE; e++) part[e] += xv * wv[e];
  }
  #pragma unroll
  for (int e = 0; e < EE; e++) {
    float v = part[e];
    #pragma unroll
    for (int s = 32; s > 0; s >>= 1) v += __shfl_xor(v, s);
    part[e] = v;
  }
  // all lanes hold the full 24 logits now
  float mx = part[0];
  #pragma unroll
  for (int e = 1; e < EE; e++) mx = fmaxf(mx, part[e]);
  float se = 0.f; float probs[EE];
  #pragma unroll
  for (int e = 0; e < EE; e++) { probs[e] = __expf(part[e] - mx); se += probs[e]; }
  float inv = 1.f / se;
  #pragma unroll
  for (int e = 0; e < EE; e++) probs[e] *= inv;
  float lse = mx + __logf(se);

  // top-8 (strict > keeps lowest index on ties, matching lax.top_k)
  unsigned taken = 0u;
  float gsum = 0.f;
  int my_e = 0; float my_p = 0.f;
  #pragma unroll
  for (int h = 0; h < HH; h++) {
    float best = -1.f; int bi = 0;
    #pragma unroll
    for (int e = 0; e < EE; e++) {
      bool ok = !((taken >> e) & 1u) && (probs[e] > best);
      best = ok ? probs[e] : best;
      bi   = ok ? e : bi;
    }
    taken |= 1u << bi;
    gsum += best;
    if (lane == h) { my_e = bi; my_p = best; }
  }
  float ginv = 1.f / (gsum + 1e-6f);

  int* cnt = ws_i;
  float* gbuf = ws_f + WS_G / 4;
  int* bucket = ws_i + WS_BUCKET / 4;
  if (lane < HH) {
    gbuf[token * HH + lane] = my_p * ginv;
    int pos = atomicAdd(&cnt[my_e], 1);
    bucket[my_e * CAP + pos] = token * HH + lane;
  }

  __shared__ float pl[4][EE];
  __shared__ float zl[4];
  if (lane < EE) pl[w][lane] = probs[lane];
  if (lane == 0) zl[w] = lse * lse;
  __syncthreads();
  int t = threadIdx.x;
  if (t < EE) {
    float s = pl[0][t] + pl[1][t] + pl[2][t] + pl[3][t];
    atomicAdd(ws_f + WS_IMP / 4 + t, s);
  }
  if (t == EE) atomicAdd(ws_f + WS_ZSUM / 4, zl[0] + zl[1] + zl[2] + zl[3]);
}

// ---------------- kv = x @ W_kv ----------------
__global__ __launch_bounds__(192) void kv_kernel(
    const float* __restrict__ x, const float* __restrict__ Wkv,
    float* __restrict__ kv)
{
  __shared__ float xs[16][CC];   // 48 KB
  int t = threadIdx.x;
  int tok0 = blockIdx.x * 16;
  for (int i = 0; i < 64; i++) {
    int f = i * 192 + t;
    int r = f / CC, c = f % CC;
    xs[r][c] = x[(size_t)(tok0 + r) * CC + c];
  }
  __syncthreads();
  float acc[16];
  #pragma unroll
  for (int r = 0; r < 16; r++) acc[r] = 0.f;
  for (int k = 0; k < CC; k += 4) {
    float w0 = Wkv[(k + 0) * 192 + t];
    float w1 = Wkv[(k + 1) * 192 + t];
    float w2 = Wkv[(k + 2) * 192 + t];
    float w3 = Wkv[(k + 3) * 192 + t];
    #pragma unroll
    for (int r = 0; r < 16; r++) {
      float4 a = *(const float4*)&xs[r][k];
      acc[r] += a.x * w0 + a.y * w1 + a.z * w2 + a.w * w3;
    }
  }
  for (int r = 0; r < 16; r++)
    kv[(size_t)(tok0 + r) * 192 + t] = acc[r];
}

// ---------------- gathered q projection: q[slot] = x[token] @ W_in[e] ------
__global__ __launch_bounds__(256) void qproj_kernel(
    const float* __restrict__ x, const float* __restrict__ Win,
    const int* __restrict__ ws_i, float* __restrict__ qbuf)
{
  int e = blockIdx.x >> 7;              // 128 tiles per expert
  int t0 = (blockIdx.x & 127) * 64;
  int cnt = ws_i[e];
  if (t0 >= cnt) return;
  int nrows = min(64, cnt - t0);
  const int* bucket = ws_i + WS_BUCKET / 4 + e * CAP + t0;

  __shared__ int slot_s[64];
  __shared__ int tok_s[64];
  __shared__ float As[64][68];
  __shared__ float Bs[64][100];
  int t = threadIdx.x;
  if (t < 64) {
    int slot = bucket[min(t, nrows - 1)];
    slot_s[t] = slot;
    tok_s[t] = slot >> 3;
  }
  __syncthreads();

  float acc[4][6];
  #pragma unroll
  for (int i = 0; i < 4; i++)
    #pragma unroll
    for (int c = 0; c < 6; c++) acc[i][c] = 0.f;
  int ty = t >> 4, tx = t & 15;
  int R0 = ty * 4, C0 = tx * 6;

  for (int kb = 0; kb < CC; kb += 64) {
    #pragma unroll
    for (int i = 0; i < 16; i++) {
      int f = i * 256 + t;
      int r = f >> 6, c = f & 63;
      As[r][c] = x[(size_t)tok_s[r] * CC + kb + c];
    }
    #pragma unroll
    for (int i = 0; i < 24; i++) {
      int f = i * 256 + t;
      int kr = f / 96, d = f % 96;
      Bs[kr][d] = Win[((size_t)e * CC + kb + kr) * 96 + d];
    }
    __syncthreads();
    for (int k = 0; k < 64; k += 4) {
      float4 a[4];
      #pragma unroll
      for (int i = 0; i < 4; i++) a[i] = *(const float4*)&As[R0 + i][k];
      #pragma unroll
      for (int j = 0; j < 4; j++) {
        float bj[6];
        #pragma unroll
        for (int c = 0; c < 6; c++) bj[c] = Bs[k + j][C0 + c];
        #pragma unroll
        for (int i = 0; i < 4; i++) {
          float av = (j == 0) ? a[i].x : (j == 1) ? a[i].y : (j == 2) ? a[i].z : a[i].w;
          #pragma unroll
          for (int c = 0; c < 6; c++) acc[i][c] += av * bj[c];
        }
      }
    }
    __syncthreads();
  }
  #pragma unroll
  for (int i = 0; i < 4; i++) {
    int r = R0 + i;
    if (r < nrows) {
      int slot = slot_s[r];
      #pragma unroll
      for (int c = 0; c < 6; c++) qbuf[(size_t)slot * 96 + C0 + c] = acc[i][c];
    }
  }
}

// ---------------- flash attention, fp32 ----------------
__global__ __launch_bounds__(256) void attn_kernel(
    const float* __restrict__ qbuf, const float* __restrict__ kvbuf,
    float* __restrict__ obuf)
{
  int bh = blockIdx.y;
  int b = bh >> 3, h = bh & 7;
  int i0 = blockIdx.x * 64;
  __shared__ float Qs[64][100];
  __shared__ float Ks[64][100];
  __shared__ float Vs[64][100];
  __shared__ float S[64][68];
  __shared__ float mrow[64], lrow[64], arow[64];
  int t = threadIdx.x;
  #pragma unroll
  for (int i = 0; i < 24; i++) {
    int f = i * 256 + t;
    int r = f / 96, d = f % 96;
    Qs[r][d] = qbuf[((size_t)((b * NN + i0 + r) * HH + h)) * 96 + d];
  }
  if (t < 64) { mrow[t] = -1e30f; lrow[t] = 0.f; }
  float o[4][6];
  #pragma unroll
  for (int i = 0; i < 4; i++)
    #pragma unroll
    for (int c = 0; c < 6; c++) o[i][c] = 0.f;
  int ty = t >> 4, tx = t & 15;
  int R0 = ty * 4, C0s = tx * 4, C0v = tx * 6;

  for (int jt = 0; jt < 16; jt++) {
    __syncthreads();
    int j0 = jt * 64;
    #pragma unroll
    for (int i = 0; i < 24; i++) {
      int f = i * 256 + t;
      int r = f / 96, d = f % 96;
      const float* kvr = kvbuf + (size_t)(b * NN + j0 + r) * 192;
      Ks[r][d] = kvr[d];
      Vs[r][d] = kvr[96 + d];
    }
    __syncthreads();
    // S = scale * Q @ K^T
    float acc[4][4];
    #pragma unroll
    for (int i = 0; i < 4; i++)
      #pragma unroll
      for (int j = 0; j < 4; j++) acc[i][j] = 0.f;
    for (int k = 0; k < 96; k += 4) {
      float4 qv[4], kv4[4];
      #pragma unroll
      for (int i = 0; i < 4; i++) qv[i] = *(const float4*)&Qs[R0 + i][k];
      #pragma unroll
      for (int j = 0; j < 4; j++) kv4[j] = *(const float4*)&Ks[C0s + j][k];
      #pragma unroll
      for (int i = 0; i < 4; i++)
        #pragma unroll
        for (int j = 0; j < 4; j++)
          acc[i][j] += qv[i].x * kv4[j].x + qv[i].y * kv4[j].y +
                       qv[i].z * kv4[j].z + qv[i].w * kv4[j].w;
    }
    #pragma unroll
    for (int i = 0; i < 4; i++)
      #pragma unroll
      for (int j = 0; j < 4; j++)
        S[R0 + i][C0s + j] = acc[i][j] * ASCALE;
    __syncthreads();
    // online softmax stats (4 lanes per row, same wave)
    {
      int row = t >> 2, part = t & 3;
      float tm = -1e30f;
      #pragma unroll
      for (int c = 0; c < 16; c++) tm = fmaxf(tm, S[row][part * 16 + c]);
      tm = fmaxf(tm, __shfl_xor(tm, 1));
      tm = fmaxf(tm, __shfl_xor(tm, 2));
      float mo = mrow[row];
      float mn = fmaxf(mo, tm);
      float al = __expf(mo - mn);
      float ts = 0.f;
      #pragma unroll
      for (int c = 0; c < 16; c++) {
        float ev = __expf(S[row][part * 16 + c] - mn);
        S[row][part * 16 + c] = ev;
        ts += ev;
      }
      ts += __shfl_xor(ts, 1);
      ts += __shfl_xor(ts, 2);
      if (part == 0) {
        mrow[row] = mn;
        lrow[row] = lrow[row] * al + ts;
        arow[row] = al;
      }
    }
    __syncthreads();
    // O = O*alpha + P @ V
    #pragma unroll
    for (int i = 0; i < 4; i++) {
      float al = arow[R0 + i];
      #pragma unroll
      for (int c = 0; c < 6; c++) o[i][c] *= al;
    }
    for (int k = 0; k < 64; k += 4) {
      float4 p4[4];
      #pragma unroll
      for (int i = 0; i < 4; i++) p4[i] = *(const float4*)&S[R0 + i][k];
      #pragma unroll
      for (int j = 0; j < 4; j++) {
        float v[6];
        #pragma unroll
        for (int c = 0; c < 6; c++) v[c] = Vs[k + j][C0v + c];
        #pragma unroll
        for (int i = 0; i < 4; i++) {
          float pv = (j == 0) ? p4[i].x : (j == 1) ? p4[i].y : (j == 2) ? p4[i].z : p4[i].w;
          #pragma unroll
          for (int c = 0; c < 6; c++) o[i][c] += pv * v[c];
        }
      }
    }
  }
  __syncthreads();
  #pragma unroll
  for (int i = 0; i < 4; i++) {
    float invl = 1.f / lrow[R0 + i];
    size_t slot = (size_t)((b * NN + i0 + R0 + i) * HH + h);
    #pragma unroll
    for (int c = 0; c < 6; c++)
      obuf[slot * 96 + C0v + c] = o[i][c] * invl;
  }
}

// ------------- gathered output projection with atomic accumulation --------
__global__ __launch_bounds__(256) void oproj_kernel(
    const float* __restrict__ obuf, const float* __restrict__ Wout,
    const int* __restrict__ ws_i, const float* __restrict__ ws_f,
    float* __restrict__ out)
{
  int e = blockIdx.x >> 8;               // 256 tiles per expert
  int t0 = (blockIdx.x & 255) * 32;
  int cnt = ws_i[e];
  if (t0 >= cnt) return;
  int nrows = min(32, cnt - t0);
  const int* bucket = ws_i + WS_BUCKET / 4 + e * CAP + t0;
  const float* gbuf = ws_f + WS_G / 4;

  __shared__ float As[32][100];
  __shared__ int tok_s[32];
  int t = threadIdx.x;
  if (t < 32) {
    int slot = bucket[min(t, nrows - 1)];
    tok_s[t] = slot >> 3;
  }
  #pragma unroll
  for (int i = 0; i < 12; i++) {
    int f = i * 256 + t;
    int r = f / 96, d = f % 96;
    int slot = bucket[min(r, nrows - 1)];
    As[r][d] = obuf[(size_t)slot * 96 + d] * gbuf[slot];
  }
  __syncthreads();

  float acc[32][3];
  #pragma unroll
  for (int r = 0; r < 32; r++)
    #pragma unroll
    for (int c = 0; c < 3; c++) acc[r][c] = 0.f;

  for (int k = 0; k < 96; k += 4) {
    float w[4][3];
    #pragma unroll
    for (int j = 0; j < 4; j++)
      #pragma unroll
      for (int c = 0; c < 3; c++)
        w[j][c] = Wout[((size_t)e * 96 + k + j) * CC + c * 256 + t];
    #pragma unroll
    for (int r = 0; r < 32; r++) {
      float4 a = *(const float4*)&As[r][k];
      #pragma unroll
      for (int c = 0; c < 3; c++)
        acc[r][c] += a.x * w[0][c] + a.y * w[1][c] + a.z * w[2][c] + a.w * w[3][c];
    }
  }
  #pragma unroll
  for (int r = 0; r < 32; r++) {
    if (r < nrows) {
      size_t base = (size_t)tok_s[r] * CC + t;
      #pragma unroll
      for (int c = 0; c < 3; c++)
        atomicAdd(&out[base + c * 256], acc[r][c]);
    }
  }
}

// ---------------- aux loss ----------------
__global__ void aux_kernel(const float* __restrict__ ws_f,
                           const int* __restrict__ ws_i, float* __restrict__ out)
{
  if (threadIdx.x == 0 && blockIdx.x == 0) {
    float sw = 0.f;
    for (int e = 0; e < EE; e++) {
      float imp = ws_f[WS_IMP / 4 + e] / (float)NT;
      float load = (float)ws_i[e] / (float)(NT * HH);
      sw += imp * load;
    }
    float zl = ws_f[WS_ZSUM / 4] / (float)NT;
    out[(size_t)NT * CC] = 0.1f * ((float)EE * sw) + 0.001f * zl;
  }
}

extern "C" void kernel_launch(void* const* d_in, const int* in_sizes, int n_in,
                              void* d_out, int out_size, void* d_ws, size_t ws_size,
                              hipStream_t stream)
{
  const float* x    = (const float*)d_in[0];
  const float* Wg   = (const float*)d_in[1];
  const float* Win  = (const float*)d_in[2];
  const float* Wout = (const float*)d_in[3];
  const float* Wkv  = (const float*)d_in[4];
  const int*   task = (const int*)d_in[5];
  float* out = (float*)d_out;
  float* ws_f = (float*)d_ws;
  int*   ws_i = (int*)d_ws;

  hipMemsetAsync(d_ws, 0, 256, stream);
  hipMemsetAsync(d_out, 0, (size_t)out_size * sizeof(float), stream);

  gate_kernel<<<NT / 4, 256, 0, stream>>>(x, Wg, task, ws_f, ws_i);
  kv_kernel<<<NT / 16, 192, 0, stream>>>(x, Wkv, ws_f + WS_KV / 4);
  qproj_kernel<<<EE * 128, 256, 0, stream>>>(x, Win, ws_i, ws_f + WS_Q / 4);
  attn_kernel<<<dim3(16, 64), 256, 0, stream>>>(ws_f + WS_Q / 4, ws_f + WS_KV / 4,
                                                ws_f + WS_O / 4);
  oproj_kernel<<<EE * 256, 256, 0, stream>>>(ws_f + WS_O / 4, Wout, ws_i, ws_f, out);
  aux_kernel<<<1, 64, 0, stream>>>(ws_f, ws_i, out);
}

// Round 2
// 758.909 us; speedup vs baseline: 1.7672x; 1.7672x over previous
//
#include <hip/hip_runtime.h>
#include <hip/hip_bf16.h>
#include <math.h>

#define BB 8
#define NN 1024
#define CC 768
#define HH 8
#define HD 96
#define EE 24
#define NT (BB*NN)          // 8192 tokens
#define NSLOT (NT*HH)       // 65536 (token,h) slots
#define CAP 8192            // per-expert bucket capacity
#define ASCALE 0.10206207261596575f  // 96^-0.5

typedef unsigned short u16;
typedef __attribute__((ext_vector_type(8))) short s16x8;
typedef __attribute__((ext_vector_type(4))) float f32x4;

__device__ inline u16 f2b(float f) {  // RNE float->bf16 bits
  unsigned u = __builtin_bit_cast(unsigned, f);
  unsigned r = u + 0x7fffu + ((u >> 16) & 1u);
  return (u16)(r >> 16);
}

// ws layout (bytes)
#define WS_CNT    0                        // 24 int
#define WS_IMP    96                       // 24 f32
#define WS_ZSUM   192                      // 1 f32 (pad to 256)
#define WS_G      256                      // NSLOT f32
#define WS_BUCKET (WS_G + NSLOT*4)         // E*CAP int
#define WS_KVB    (WS_BUCKET + EE*CAP*4)   // NT*192 u16 (bf16 kv)
#define WS_QB     (WS_KVB + NT*192*2)      // NSLOT*96 u16 (bf16 q)
#define WS_O      (WS_QB + (size_t)NSLOT*96*2)  // NSLOT*96 f32

// ---------------- gating: logits, softmax, top-8, buckets, aux partials ----
__global__ __launch_bounds__(256) void gate_kernel(
    const float* __restrict__ x, const float* __restrict__ Wg_all,
    const int* __restrict__ task_p, float* __restrict__ ws_f,
    int* __restrict__ ws_i)
{
  int w = threadIdx.x >> 6, lane = threadIdx.x & 63;
  int token = blockIdx.x * 4 + w;
  const float* Wg = Wg_all + (size_t)task_p[0] * CC * EE;
  const float* xr = x + (size_t)token * CC;

  float part[EE];
  #pragma unroll
  for (int e = 0; e < EE; e++) part[e] = 0.f;
  for (int c = lane; c < CC; c += 64) {
    float xv = xr[c];
    const float4* w4 = (const float4*)(Wg + c * EE);
    float wv[EE];
    #pragma unroll
    for (int q = 0; q < 6; q++) *(float4*)&wv[q * 4] = w4[q];
    #pragma unroll
    for (int e = 0; e < EE; e++) part[e] += xv * wv[e];
  }
  #pragma unroll
  for (int e = 0; e < EE; e++) {
    float v = part[e];
    #pragma unroll
    for (int s = 32; s > 0; s >>= 1) v += __shfl_xor(v, s);
    part[e] = v;
  }
  float mx = part[0];
  #pragma unroll
  for (int e = 1; e < EE; e++) mx = fmaxf(mx, part[e]);
  float se = 0.f; float probs[EE];
  #pragma unroll
  for (int e = 0; e < EE; e++) { probs[e] = __expf(part[e] - mx); se += probs[e]; }
  float inv = 1.f / se;
  #pragma unroll
  for (int e = 0; e < EE; e++) probs[e] *= inv;
  float lse = mx + __logf(se);

  unsigned taken = 0u;
  float gsum = 0.f;
  int my_e = 0; float my_p = 0.f;
  #pragma unroll
  for (int h = 0; h < HH; h++) {
    float best = -1.f; int bi = 0;
    #pragma unroll
    for (int e = 0; e < EE; e++) {
      bool ok = !((taken >> e) & 1u) && (probs[e] > best);
      best = ok ? probs[e] : best;
      bi   = ok ? e : bi;
    }
    taken |= 1u << bi;
    gsum += best;
    if (lane == h) { my_e = bi; my_p = best; }
  }
  float ginv = 1.f / (gsum + 1e-6f);

  int* cnt = ws_i;
  float* gbuf = ws_f + WS_G / 4;
  int* bucket = ws_i + WS_BUCKET / 4;
  if (lane < HH) {
    gbuf[token * HH + lane] = my_p * ginv;
    int pos = atomicAdd(&cnt[my_e], 1);
    bucket[my_e * CAP + pos] = token * HH + lane;
  }

  __shared__ float pl[4][EE];
  __shared__ float zl[4];
  if (lane < EE) pl[w][lane] = probs[lane];
  if (lane == 0) zl[w] = lse * lse;
  __syncthreads();
  int t = threadIdx.x;
  if (t < EE) {
    float s = pl[0][t] + pl[1][t] + pl[2][t] + pl[3][t];
    atomicAdd(ws_f + WS_IMP / 4 + t, s);
  }
  if (t == EE) atomicAdd(ws_f + WS_ZSUM / 4, zl[0] + zl[1] + zl[2] + zl[3]);
}

// ---------------- kv = x @ W_kv  (bf16 out) ----------------
__global__ __launch_bounds__(192) void kv_kernel(
    const float* __restrict__ x, const float* __restrict__ Wkv,
    u16* __restrict__ kvb)
{
  __shared__ float xs[16][CC];   // 48 KB
  int t = threadIdx.x;
  int tok0 = blockIdx.x * 16;
  for (int i = 0; i < 64; i++) {
    int f = i * 192 + t;
    int r = f / CC, c = f % CC;
    xs[r][c] = x[(size_t)(tok0 + r) * CC + c];
  }
  __syncthreads();
  float acc[16];
  #pragma unroll
  for (int r = 0; r < 16; r++) acc[r] = 0.f;
  for (int k = 0; k < CC; k += 4) {
    float w0 = Wkv[(k + 0) * 192 + t];
    float w1 = Wkv[(k + 1) * 192 + t];
    float w2 = Wkv[(k + 2) * 192 + t];
    float w3 = Wkv[(k + 3) * 192 + t];
    #pragma unroll
    for (int r = 0; r < 16; r++) {
      float4 a = *(const float4*)&xs[r][k];
      acc[r] += a.x * w0 + a.y * w1 + a.z * w2 + a.w * w3;
    }
  }
  for (int r = 0; r < 16; r++)
    kvb[(size_t)(tok0 + r) * 192 + t] = f2b(acc[r]);
}

// ---------------- gathered q projection (bf16 out) ------
__global__ __launch_bounds__(256) void qproj_kernel(
    const float* __restrict__ x, const float* __restrict__ Win,
    const int* __restrict__ ws_i, u16* __restrict__ qbuf)
{
  int e = blockIdx.x >> 7;
  int t0 = (blockIdx.x & 127) * 64;
  int cnt = ws_i[e];
  if (t0 >= cnt) return;
  int nrows = min(64, cnt - t0);
  const int* bucket = ws_i + WS_BUCKET / 4 + e * CAP + t0;

  __shared__ int slot_s[64];
  __shared__ int tok_s[64];
  __shared__ float As[64][68];
  __shared__ float Bs[64][100];
  int t = threadIdx.x;
  if (t < 64) {
    int slot = bucket[min(t, nrows - 1)];
    slot_s[t] = slot;
    tok_s[t] = slot >> 3;
  }
  __syncthreads();

  float acc[4][6];
  #pragma unroll
  for (int i = 0; i < 4; i++)
    #pragma unroll
    for (int c = 0; c < 6; c++) acc[i][c] = 0.f;
  int ty = t >> 4, tx = t & 15;
  int R0 = ty * 4, C0 = tx * 6;

  for (int kb = 0; kb < CC; kb += 64) {
    #pragma unroll
    for (int i = 0; i < 16; i++) {
      int f = i * 256 + t;
      int r = f >> 6, c = f & 63;
      As[r][c] = x[(size_t)tok_s[r] * CC + kb + c];
    }
    #pragma unroll
    for (int i = 0; i < 24; i++) {
      int f = i * 256 + t;
      int kr = f / 96, d = f % 96;
      Bs[kr][d] = Win[((size_t)e * CC + kb + kr) * 96 + d];
    }
    __syncthreads();
    for (int k = 0; k < 64; k += 4) {
      float4 a[4];
      #pragma unroll
      for (int i = 0; i < 4; i++) a[i] = *(const float4*)&As[R0 + i][k];
      #pragma unroll
      for (int j = 0; j < 4; j++) {
        float bj[6];
        #pragma unroll
        for (int c = 0; c < 6; c++) bj[c] = Bs[k + j][C0 + c];
        #pragma unroll
        for (int i = 0; i < 4; i++) {
          float av = (j == 0) ? a[i].x : (j == 1) ? a[i].y : (j == 2) ? a[i].z : a[i].w;
          #pragma unroll
          for (int c = 0; c < 6; c++) acc[i][c] += av * bj[c];
        }
      }
    }
    __syncthreads();
  }
  #pragma unroll
  for (int i = 0; i < 4; i++) {
    int r = R0 + i;
    if (r < nrows) {
      int slot = slot_s[r];
      #pragma unroll
      for (int c = 0; c < 6; c++) qbuf[(size_t)slot * 96 + C0 + c] = f2b(acc[i][c]);
    }
  }
}

// ---------------- flash attention, bf16 MFMA ----------------
// block: 256 thr / 4 waves; 64 q-rows per block (16 per wave); KV step 64.
__global__ __launch_bounds__(256) void attn_kernel(
    const u16* __restrict__ qb, const u16* __restrict__ kvb,
    float* __restrict__ obuf)
{
  __shared__ u16 Ks[64][104];   // K row-major, padded (stride 52 dw)
  __shared__ u16 Vt[96][72];    // V transposed [d][j], padded (stride 36 dw)
  __shared__ u16 Ps[64][72];    // P per-wave-private rows, padded
  int bh = blockIdx.y;
  int b = bh >> 3, h = bh & 7;
  int i0 = blockIdx.x * 64;
  int t = threadIdx.x;
  int w = t >> 6, l = t & 63;
  int wq0 = w * 16;
  int lr = l & 15;    // 0..15
  int lg = l >> 4;    // 0..3

  // Q fragments (A-layout: row=lr, k = lg*8 + ks*32 + [0..7])
  s16x8 qf[3];
  {
    int qrow = i0 + wq0 + lr;
    const u16* qp = qb + ((size_t)((b * NN + qrow) * HH + h)) * HD + lg * 8;
    qf[0] = *(const s16x8*)(qp);
    qf[1] = *(const s16x8*)(qp + 32);
    qf[2] = *(const s16x8*)(qp + 64);
  }

  f32x4 o[6];
  #pragma unroll
  for (int c = 0; c < 6; c++) o[c] = (f32x4)(0.f);
  float m[4], lsum[4];
  #pragma unroll
  for (int r = 0; r < 4; r++) { m[r] = -1e30f; lsum[r] = 0.f; }

  int kj = t >> 2, kp = t & 3;   // K staging: row kj, 24-elem part kp
  int vj = t & 63, vd = t >> 6;  // V staging: kv row vj, 24-d set vd

  for (int jt = 0; jt < 16; jt++) {
    int j0 = jt * 64;
    __syncthreads();
    // stage K tile (row-major)
    {
      const u16* src = kvb + (size_t)(b * NN + j0 + kj) * 192 + kp * 24;
      s16x8 a0 = *(const s16x8*)(src);
      s16x8 a1 = *(const s16x8*)(src + 8);
      s16x8 a2 = *(const s16x8*)(src + 16);
      *(s16x8*)&Ks[kj][kp * 24]      = a0;
      *(s16x8*)&Ks[kj][kp * 24 + 8]  = a1;
      *(s16x8*)&Ks[kj][kp * 24 + 16] = a2;
    }
    // stage V tile transposed: Vt[d][j]
    {
      const u16* src = kvb + (size_t)(b * NN + j0 + vj) * 192 + 96 + vd * 24;
      s16x8 a0 = *(const s16x8*)(src);
      s16x8 a1 = *(const s16x8*)(src + 8);
      s16x8 a2 = *(const s16x8*)(src + 16);
      #pragma unroll
      for (int s = 0; s < 8; s++) Vt[vd * 24 + s][vj]      = ((u16*)&a0)[s];
      #pragma unroll
      for (int s = 0; s < 8; s++) Vt[vd * 24 + 8 + s][vj]  = ((u16*)&a1)[s];
      #pragma unroll
      for (int s = 0; s < 8; s++) Vt[vd * 24 + 16 + s][vj] = ((u16*)&a2)[s];
    }
    __syncthreads();

    // S = Q @ K^T  (D-layout: row = lg*4+reg, col = c*16+lr)
    f32x4 sacc[4];
    #pragma unroll
    for (int c = 0; c < 4; c++) sacc[c] = (f32x4)(0.f);
    #pragma unroll
    for (int ks = 0; ks < 3; ks++) {
      #pragma unroll
      for (int c = 0; c < 4; c++) {
        s16x8 kbf = *(const s16x8*)&Ks[c * 16 + lr][ks * 32 + lg * 8];
        sacc[c] = __builtin_amdgcn_mfma_f32_16x16x32_bf16(qf[ks], kbf, sacc[c], 0, 0, 0);
      }
    }

    // online softmax per owned row (reg = 0..3)
    #pragma unroll
    for (int reg = 0; reg < 4; reg++) {
      float v = fmaxf(fmaxf(sacc[0][reg], sacc[1][reg]),
                      fmaxf(sacc[2][reg], sacc[3][reg]));
      v = fmaxf(v, __shfl_xor(v, 1));
      v = fmaxf(v, __shfl_xor(v, 2));
      v = fmaxf(v, __shfl_xor(v, 4));
      v = fmaxf(v, __shfl_xor(v, 8));
      float rmax = v * ASCALE;
      float mn = fmaxf(m[reg], rmax);
      float al = __expf(m[reg] - mn);
      m[reg] = mn;
      float ts = 0.f;
      int prow = wq0 + lg * 4 + reg;
      #pragma unroll
      for (int c = 0; c < 4; c++) {
        float p = __expf(sacc[c][reg] * ASCALE - mn);
        ts += p;
        Ps[prow][c * 16 + lr] = f2b(p);
      }
      ts += __shfl_xor(ts, 1);
      ts += __shfl_xor(ts, 2);
      ts += __shfl_xor(ts, 4);
      ts += __shfl_xor(ts, 8);
      lsum[reg] = lsum[reg] * al + ts;
      #pragma unroll
      for (int c = 0; c < 6; c++) o[c][reg] *= al;
    }

    // O += P @ V   (A: P rows, B: Vt contiguous)
    #pragma unroll
    for (int ks = 0; ks < 2; ks++) {
      s16x8 pa = *(const s16x8*)&Ps[wq0 + lr][ks * 32 + lg * 8];
      #pragma unroll
      for (int c = 0; c < 6; c++) {
        s16x8 vb = *(const s16x8*)&Vt[c * 16 + lr][ks * 32 + lg * 8];
        o[c] = __builtin_amdgcn_mfma_f32_16x16x32_bf16(pa, vb, o[c], 0, 0, 0);
      }
    }
  }

  // write O / l
  #pragma unroll
  for (int reg = 0; reg < 4; reg++) {
    float inv = 1.f / lsum[reg];
    int qrow = i0 + wq0 + lg * 4 + reg;
    size_t base = ((size_t)((b * NN + qrow) * HH + h)) * HD;
    #pragma unroll
    for (int c = 0; c < 6; c++)
      obuf[base + c * 16 + lr] = o[c][reg] * inv;
  }
}

// ------------- gathered output projection with atomic accumulation --------
__global__ __launch_bounds__(256) void oproj_kernel(
    const float* __restrict__ obuf, const float* __restrict__ Wout,
    const int* __restrict__ ws_i, const float* __restrict__ ws_f,
    float* __restrict__ out)
{
  int e = blockIdx.x >> 8;
  int t0 = (blockIdx.x & 255) * 32;
  int cnt = ws_i[e];
  if (t0 >= cnt) return;
  int nrows = min(32, cnt - t0);
  const int* bucket = ws_i + WS_BUCKET / 4 + e * CAP + t0;
  const float* gbuf = ws_f + WS_G / 4;

  __shared__ float As[32][100];
  __shared__ int tok_s[32];
  int t = threadIdx.x;
  if (t < 32) {
    int slot = bucket[min(t, nrows - 1)];
    tok_s[t] = slot >> 3;
  }
  #pragma unroll
  for (int i = 0; i < 12; i++) {
    int f = i * 256 + t;
    int r = f / 96, d = f % 96;
    int slot = bucket[min(r, nrows - 1)];
    As[r][d] = obuf[(size_t)slot * 96 + d] * gbuf[slot];
  }
  __syncthreads();

  float acc[32][3];
  #pragma unroll
  for (int r = 0; r < 32; r++)
    #pragma unroll
    for (int c = 0; c < 3; c++) acc[r][c] = 0.f;

  for (int k = 0; k < 96; k += 4) {
    float w[4][3];
    #pragma unroll
    for (int j = 0; j < 4; j++)
      #pragma unroll
      for (int c = 0; c < 3; c++)
        w[j][c] = Wout[((size_t)e * 96 + k + j) * CC + c * 256 + t];
    #pragma unroll
    for (int r = 0; r < 32; r++) {
      float4 a = *(const float4*)&As[r][k];
      #pragma unroll
      for (int c = 0; c < 3; c++)
        acc[r][c] += a.x * w[0][c] + a.y * w[1][c] + a.z * w[2][c] + a.w * w[3][c];
    }
  }
  #pragma unroll
  for (int r = 0; r < 32; r++) {
    if (r < nrows) {
      size_t base = (size_t)tok_s[r] * CC + t;
      #pragma unroll
      for (int c = 0; c < 3; c++)
        atomicAdd(&out[base + c * 256], acc[r][c]);
    }
  }
}

// ---------------- aux loss ----------------
__global__ void aux_kernel(const float* __restrict__ ws_f,
                           const int* __restrict__ ws_i, float* __restrict__ out)
{
  if (threadIdx.x == 0 && blockIdx.x == 0) {
    float sw = 0.f;
    for (int e = 0; e < EE; e++) {
      float imp = ws_f[WS_IMP / 4 + e] / (float)NT;
      float load = (float)ws_i[e] / (float)(NT * HH);
      sw += imp * load;
    }
    float zl = ws_f[WS_ZSUM / 4] / (float)NT;
    out[(size_t)NT * CC] = 0.1f * ((float)EE * sw) + 0.001f * zl;
  }
}

extern "C" void kernel_launch(void* const* d_in, const int* in_sizes, int n_in,
                              void* d_out, int out_size, void* d_ws, size_t ws_size,
                              hipStream_t stream)
{
  const float* x    = (const float*)d_in[0];
  const float* Wg   = (const float*)d_in[1];
  const float* Win  = (const float*)d_in[2];
  const float* Wout = (const float*)d_in[3];
  const float* Wkv  = (const float*)d_in[4];
  const int*   task = (const int*)d_in[5];
  float* out = (float*)d_out;
  float* ws_f = (float*)d_ws;
  int*   ws_i = (int*)d_ws;
  u16*   kvb  = (u16*)((char*)d_ws + WS_KVB);
  u16*   qbuf = (u16*)((char*)d_ws + WS_QB);
  float* obuf = (float*)((char*)d_ws + WS_O);

  hipMemsetAsync(d_ws, 0, 256, stream);
  hipMemsetAsync(d_out, 0, (size_t)out_size * sizeof(float), stream);

  gate_kernel<<<NT / 4, 256, 0, stream>>>(x, Wg, task, ws_f, ws_i);
  kv_kernel<<<NT / 16, 192, 0, stream>>>(x, Wkv, kvb);
  qproj_kernel<<<EE * 128, 256, 0, stream>>>(x, Win, ws_i, qbuf);
  attn_kernel<<<dim3(16, 64), 256, 0, stream>>>(qbuf, kvb, obuf);
  oproj_kernel<<<EE * 256, 256, 0, stream>>>(obuf, Wout, ws_i, ws_f, out);
  aux_kernel<<<1, 64, 0, stream>>>(ws_f, ws_i, out);
}

// Round 3
// 443.692 us; speedup vs baseline: 3.0227x; 1.7104x over previous
//
#include <hip/hip_runtime.h>
#include <hip/hip_bf16.h>
#include <math.h>

#define BB 8
#define NN 1024
#define CC 768
#define HH 8
#define HD 96
#define EE 24
#define NT (BB*NN)          // 8192 tokens
#define NSLOT (NT*HH)       // 65536 (token,h) slots
#define EC (EE*HD)          // 2304
#define ASCALE 0.10206207261596575f  // 96^-0.5

typedef unsigned short u16;
typedef unsigned char u8;
typedef __attribute__((ext_vector_type(8))) short s16x8;
typedef __attribute__((ext_vector_type(4))) float f32x4;

__device__ inline u16 f2b(float f) {  // RNE float->bf16 bits
  unsigned u = __builtin_bit_cast(unsigned, f);
  unsigned r = u + 0x7fffu + ((u >> 16) & 1u);
  return (u16)(r >> 16);
}

// ws layout (bytes)
#define WS_CNT   0                         // 24 int
#define WS_IMP   96                        // 24 f32
#define WS_ZSUM  192                       // 1 f32 (pad to 256)
#define WS_G     256                       // NSLOT f32
#define WS_EID   (WS_G + NSLOT*4)          // NSLOT u8
#define WS_KVB   (WS_EID + NSLOT)          // NT*192 u16
#define WS_WIN   (WS_KVB + NT*192*2)       // EC*CC u16   (W_in^T  [e*96+d][c])
#define WS_WOUT  (WS_WIN + EC*CC*2)        // CC*EC u16   (W_out^T [c][e*96+d])
#define WS_WKV   (WS_WOUT + (size_t)CC*EC*2)  // 192*CC u16 (W_kv^T [j][c])
#define WS_QA    (WS_WKV + 192*CC*2)       // NT*EC u16   (q_all bf16)
#define WS_Z     (WS_QA + (size_t)NT*EC*2) // NT*EC u16   (z bf16)

// ---------------- gating: logits, softmax, top-8, eids, aux partials ----
__global__ __launch_bounds__(256) void gate_kernel(
    const float* __restrict__ x, const float* __restrict__ Wg_all,
    const int* __restrict__ task_p, float* __restrict__ ws_f,
    int* __restrict__ ws_i, u8* __restrict__ eids)
{
  int w = threadIdx.x >> 6, lane = threadIdx.x & 63;
  int token = blockIdx.x * 4 + w;
  const float* Wg = Wg_all + (size_t)task_p[0] * CC * EE;
  const float* xr = x + (size_t)token * CC;

  float part[EE];
  #pragma unroll
  for (int e = 0; e < EE; e++) part[e] = 0.f;
  for (int c = lane; c < CC; c += 64) {
    float xv = xr[c];
    const float4* w4 = (const float4*)(Wg + c * EE);
    float wv[EE];
    #pragma unroll
    for (int q = 0; q < 6; q++) *(float4*)&wv[q * 4] = w4[q];
    #pragma unroll
    for (int e = 0; e < EE; e++) part[e] += xv * wv[e];
  }
  #pragma unroll
  for (int e = 0; e < EE; e++) {
    float v = part[e];
    #pragma unroll
    for (int s = 32; s > 0; s >>= 1) v += __shfl_xor(v, s);
    part[e] = v;
  }
  float mx = part[0];
  #pragma unroll
  for (int e = 1; e < EE; e++) mx = fmaxf(mx, part[e]);
  float se = 0.f; float probs[EE];
  #pragma unroll
  for (int e = 0; e < EE; e++) { probs[e] = __expf(part[e] - mx); se += probs[e]; }
  float inv = 1.f / se;
  #pragma unroll
  for (int e = 0; e < EE; e++) probs[e] *= inv;
  float lse = mx + __logf(se);

  unsigned taken = 0u;
  float gsum = 0.f;
  int my_e = 0; float my_p = 0.f;
  #pragma unroll
  for (int h = 0; h < HH; h++) {
    float best = -1.f; int bi = 0;
    #pragma unroll
    for (int e = 0; e < EE; e++) {
      bool ok = !((taken >> e) & 1u) && (probs[e] > best);
      best = ok ? probs[e] : best;
      bi   = ok ? e : bi;
    }
    taken |= 1u << bi;
    gsum += best;
    if (lane == h) { my_e = bi; my_p = best; }
  }
  float ginv = 1.f / (gsum + 1e-6f);

  int* cnt = ws_i;
  float* gbuf = ws_f + WS_G / 4;
  if (lane < HH) {
    gbuf[token * HH + lane] = my_p * ginv;
    eids[token * HH + lane] = (u8)my_e;
    atomicAdd(&cnt[my_e], 1);
  }

  __shared__ float pl[4][EE];
  __shared__ float zl[4];
  if (lane < EE) pl[w][lane] = probs[lane];
  if (lane == 0) zl[w] = lse * lse;
  __syncthreads();
  int t = threadIdx.x;
  if (t < EE) {
    float s = pl[0][t] + pl[1][t] + pl[2][t] + pl[3][t];
    atomicAdd(ws_f + WS_IMP / 4 + t, s);
  }
  if (t == EE) atomicAdd(ws_f + WS_ZSUM / 4, zl[0] + zl[1] + zl[2] + zl[3]);
}

// -------- batched transpose + f32->bf16: dst[e*dB + c*dR + r] = src[e*sB + r*C + c]
__global__ __launch_bounds__(256) void transpose_kernel(
    const float* __restrict__ src, u16* __restrict__ dst,
    int R, int C, int sB, int dR, int dB)
{
  __shared__ float tile[32][33];
  int e = blockIdx.z;
  const float* s = src + (size_t)e * sB;
  int t = threadIdx.x;
  int tr = t >> 5, tc = t & 31;
  #pragma unroll
  for (int i = 0; i < 4; i++) {
    int r = blockIdx.x * 32 + tr + i * 8;
    int c = blockIdx.y * 32 + tc;
    tile[tr + i * 8][tc] = s[(size_t)r * C + c];
  }
  __syncthreads();
  #pragma unroll
  for (int i = 0; i < 4; i++) {
    int sc = blockIdx.y * 32 + tr + i * 8;   // dst row (= src col)
    int sr = blockIdx.x * 32 + tc;           // dst col (= src row)
    dst[(size_t)e * dB + (size_t)sc * dR + sr] = f2b(tile[tc][tr + i * 8]);
  }
}

// -------- dense MFMA GEMM: C[M][N] = A[M][K] @ Bt[N][K]^T --------
// 256 threads, 4 waves in 2x2; BK=64; A fp32 (converted) or bf16; out f32 or bf16.
template<int BM, int BN, bool A_F32, bool OUT_F32>
__global__ __launch_bounds__(256) void gemm_kernel(
    const void* __restrict__ Ap, const u16* __restrict__ Bt,
    void* __restrict__ Cp, int M, int N, int K)
{
  constexpr int WM = BM / 2, WN = BN / 2;
  constexpr int FM = WM / 16, FN = WN / 16;
  __shared__ u16 As[BM][72];
  __shared__ u16 Bs[BN][72];
  int t = threadIdx.x;
  int w = t >> 6, l = t & 63;
  int lr = l & 15, lg = l >> 4;
  int wr = w >> 1, wc = w & 1;
  int row0 = blockIdx.x * BM;
  int col0 = blockIdx.y * BN;

  f32x4 acc[FM][FN];
  #pragma unroll
  for (int i = 0; i < FM; i++)
    #pragma unroll
    for (int j = 0; j < FN; j++) acc[i][j] = (f32x4)(0.f);

  for (int kb = 0; kb < K; kb += 64) {
    __syncthreads();
    // stage A tile [BM][64]
    #pragma unroll
    for (int i = 0; i < BM / 32; i++) {
      int cid = i * 256 + t;
      int r = cid >> 3, sub = cid & 7;
      if (A_F32) {
        const float* src = (const float*)Ap + (size_t)(row0 + r) * K + kb + sub * 8;
        float4 a0 = *(const float4*)src;
        float4 a1 = *(const float4*)(src + 4);
        union { s16x8 v; u16 u[8]; } pk;
        pk.u[0] = f2b(a0.x); pk.u[1] = f2b(a0.y); pk.u[2] = f2b(a0.z); pk.u[3] = f2b(a0.w);
        pk.u[4] = f2b(a1.x); pk.u[5] = f2b(a1.y); pk.u[6] = f2b(a1.z); pk.u[7] = f2b(a1.w);
        *(s16x8*)&As[r][sub * 8] = pk.v;
      } else {
        const u16* src = (const u16*)Ap + (size_t)(row0 + r) * K + kb + sub * 8;
        *(s16x8*)&As[r][sub * 8] = *(const s16x8*)src;
      }
    }
    // stage B tile [BN][64] from Bt (already bf16, K-major)
    #pragma unroll
    for (int i = 0; i < BN / 32; i++) {
      int cid = i * 256 + t;
      int r = cid >> 3, sub = cid & 7;
      const u16* src = Bt + (size_t)(col0 + r) * K + kb + sub * 8;
      *(s16x8*)&Bs[r][sub * 8] = *(const s16x8*)src;
    }
    __syncthreads();
    #pragma unroll
    for (int ks = 0; ks < 2; ks++) {
      s16x8 af[FM], bf[FN];
      #pragma unroll
      for (int i = 0; i < FM; i++)
        af[i] = *(const s16x8*)&As[wr * WM + i * 16 + lr][ks * 32 + lg * 8];
      #pragma unroll
      for (int j = 0; j < FN; j++)
        bf[j] = *(const s16x8*)&Bs[wc * WN + j * 16 + lr][ks * 32 + lg * 8];
      #pragma unroll
      for (int i = 0; i < FM; i++)
        #pragma unroll
        for (int j = 0; j < FN; j++)
          acc[i][j] = __builtin_amdgcn_mfma_f32_16x16x32_bf16(af[i], bf[j], acc[i][j], 0, 0, 0);
    }
  }
  // epilogue: D layout col=lr, row=lg*4+reg
  #pragma unroll
  for (int i = 0; i < FM; i++)
    #pragma unroll
    for (int j = 0; j < FN; j++)
      #pragma unroll
      for (int reg = 0; reg < 4; reg++) {
        int r = row0 + wr * WM + i * 16 + lg * 4 + reg;
        int c = col0 + wc * WN + j * 16 + lr;
        if (OUT_F32) ((float*)Cp)[(size_t)r * N + c] = acc[i][j][reg];
        else ((u16*)Cp)[(size_t)r * N + c] = f2b(acc[i][j][reg]);
      }
}

// ---------------- flash attention, bf16 MFMA; writes z = g * o (bf16) -----
__global__ __launch_bounds__(256) void attn_kernel(
    const u16* __restrict__ qall, const u16* __restrict__ kvb,
    const u8* __restrict__ eids, const float* __restrict__ gbuf,
    u16* __restrict__ z)
{
  __shared__ u16 Ks[64][104];
  __shared__ u16 Vt[96][72];
  __shared__ u16 Ps[64][72];
  int bh = blockIdx.y;
  int b = bh >> 3, h = bh & 7;
  int i0 = blockIdx.x * 64;
  int t = threadIdx.x;
  int w = t >> 6, l = t & 63;
  int wq0 = w * 16;
  int lr = l & 15;
  int lg = l >> 4;

  // Q fragments from q_all via per-slot expert id
  s16x8 qf[3];
  {
    int tok = b * NN + i0 + wq0 + lr;
    int e = eids[tok * HH + h];
    const u16* qp = qall + (size_t)tok * EC + e * HD + lg * 8;
    qf[0] = *(const s16x8*)(qp);
    qf[1] = *(const s16x8*)(qp + 32);
    qf[2] = *(const s16x8*)(qp + 64);
  }

  f32x4 o[6];
  #pragma unroll
  for (int c = 0; c < 6; c++) o[c] = (f32x4)(0.f);
  float m[4], lsum[4];
  #pragma unroll
  for (int r = 0; r < 4; r++) { m[r] = -1e30f; lsum[r] = 0.f; }

  int kj = t >> 2, kp = t & 3;
  int vj = t & 63, vd = t >> 6;

  for (int jt = 0; jt < 16; jt++) {
    int j0 = jt * 64;
    __syncthreads();
    {
      const u16* src = kvb + (size_t)(b * NN + j0 + kj) * 192 + kp * 24;
      s16x8 a0 = *(const s16x8*)(src);
      s16x8 a1 = *(const s16x8*)(src + 8);
      s16x8 a2 = *(const s16x8*)(src + 16);
      *(s16x8*)&Ks[kj][kp * 24]      = a0;
      *(s16x8*)&Ks[kj][kp * 24 + 8]  = a1;
      *(s16x8*)&Ks[kj][kp * 24 + 16] = a2;
    }
    {
      const u16* src = kvb + (size_t)(b * NN + j0 + vj) * 192 + 96 + vd * 24;
      s16x8 a0 = *(const s16x8*)(src);
      s16x8 a1 = *(const s16x8*)(src + 8);
      s16x8 a2 = *(const s16x8*)(src + 16);
      #pragma unroll
      for (int s = 0; s < 8; s++) Vt[vd * 24 + s][vj]      = ((u16*)&a0)[s];
      #pragma unroll
      for (int s = 0; s < 8; s++) Vt[vd * 24 + 8 + s][vj]  = ((u16*)&a1)[s];
      #pragma unroll
      for (int s = 0; s < 8; s++) Vt[vd * 24 + 16 + s][vj] = ((u16*)&a2)[s];
    }
    __syncthreads();

    f32x4 sacc[4];
    #pragma unroll
    for (int c = 0; c < 4; c++) sacc[c] = (f32x4)(0.f);
    #pragma unroll
    for (int ks = 0; ks < 3; ks++) {
      #pragma unroll
      for (int c = 0; c < 4; c++) {
        s16x8 kbf = *(const s16x8*)&Ks[c * 16 + lr][ks * 32 + lg * 8];
        sacc[c] = __builtin_amdgcn_mfma_f32_16x16x32_bf16(qf[ks], kbf, sacc[c], 0, 0, 0);
      }
    }

    #pragma unroll
    for (int reg = 0; reg < 4; reg++) {
      float v = fmaxf(fmaxf(sacc[0][reg], sacc[1][reg]),
                      fmaxf(sacc[2][reg], sacc[3][reg]));
      v = fmaxf(v, __shfl_xor(v, 1));
      v = fmaxf(v, __shfl_xor(v, 2));
      v = fmaxf(v, __shfl_xor(v, 4));
      v = fmaxf(v, __shfl_xor(v, 8));
      float rmax = v * ASCALE;
      float mn = fmaxf(m[reg], rmax);
      float al = __expf(m[reg] - mn);
      m[reg] = mn;
      float ts = 0.f;
      int prow = wq0 + lg * 4 + reg;
      #pragma unroll
      for (int c = 0; c < 4; c++) {
        float p = __expf(sacc[c][reg] * ASCALE - mn);
        ts += p;
        Ps[prow][c * 16 + lr] = f2b(p);
      }
      ts += __shfl_xor(ts, 1);
      ts += __shfl_xor(ts, 2);
      ts += __shfl_xor(ts, 4);
      ts += __shfl_xor(ts, 8);
      lsum[reg] = lsum[reg] * al + ts;
      #pragma unroll
      for (int c = 0; c < 6; c++) o[c][reg] *= al;
    }

    #pragma unroll
    for (int ks = 0; ks < 2; ks++) {
      s16x8 pa = *(const s16x8*)&Ps[wq0 + lr][ks * 32 + lg * 8];
      #pragma unroll
      for (int c = 0; c < 6; c++) {
        s16x8 vb = *(const s16x8*)&Vt[c * 16 + lr][ks * 32 + lg * 8];
        o[c] = __builtin_amdgcn_mfma_f32_16x16x32_bf16(pa, vb, o[c], 0, 0, 0);
      }
    }
  }

  // write z[tok][e*96+d] = g * o / l   (bf16)
  #pragma unroll
  for (int reg = 0; reg < 4; reg++) {
    int tok = b * NN + i0 + wq0 + lg * 4 + reg;
    int slot = tok * HH + h;
    int e = eids[slot];
    float g = gbuf[slot];
    float inv = g / lsum[reg];
    size_t base = (size_t)tok * EC + e * HD;
    #pragma unroll
    for (int c = 0; c < 6; c++)
      z[base + c * 16 + lr] = f2b(o[c][reg] * inv);
  }
}

// ---------------- aux loss ----------------
__global__ void aux_kernel(const float* __restrict__ ws_f,
                           const int* __restrict__ ws_i, float* __restrict__ out)
{
  if (threadIdx.x == 0 && blockIdx.x == 0) {
    float sw = 0.f;
    for (int e = 0; e < EE; e++) {
      float imp = ws_f[WS_IMP / 4 + e] / (float)NT;
      float load = (float)ws_i[e] / (float)(NT * HH);
      sw += imp * load;
    }
    float zl = ws_f[WS_ZSUM / 4] / (float)NT;
    out[(size_t)NT * CC] = 0.1f * ((float)EE * sw) + 0.001f * zl;
  }
}

extern "C" void kernel_launch(void* const* d_in, const int* in_sizes, int n_in,
                              void* d_out, int out_size, void* d_ws, size_t ws_size,
                              hipStream_t stream)
{
  const float* x    = (const float*)d_in[0];
  const float* Wg   = (const float*)d_in[1];
  const float* Win  = (const float*)d_in[2];
  const float* Wout = (const float*)d_in[3];
  const float* Wkv  = (const float*)d_in[4];
  const int*   task = (const int*)d_in[5];
  float* out = (float*)d_out;
  float* ws_f = (float*)d_ws;
  int*   ws_i = (int*)d_ws;
  u8*  eids = (u8*)((char*)d_ws + WS_EID);
  u16* kvb  = (u16*)((char*)d_ws + WS_KVB);
  u16* winT = (u16*)((char*)d_ws + WS_WIN);
  u16* woutT= (u16*)((char*)d_ws + WS_WOUT);
  u16* wkvT = (u16*)((char*)d_ws + WS_WKV);
  u16* qall = (u16*)((char*)d_ws + WS_QA);
  u16* z    = (u16*)((char*)d_ws + WS_Z);

  hipMemsetAsync(d_ws, 0, 256, stream);
  hipMemsetAsync(z, 0, (size_t)NT * EC * 2, stream);

  // weight transposes (f32 -> bf16)
  transpose_kernel<<<dim3(CC/32, HD/32, EE), 256, 0, stream>>>(Win, winT, CC, HD, CC*HD, CC, HD*CC);
  transpose_kernel<<<dim3(HD/32, CC/32, EE), 256, 0, stream>>>(Wout, woutT, HD, CC, HD*CC, EC, HD);
  transpose_kernel<<<dim3(CC/32, 192/32, 1), 256, 0, stream>>>(Wkv, wkvT, CC, 192, 0, CC, 0);

  gate_kernel<<<NT / 4, 256, 0, stream>>>(x, Wg, task, ws_f, ws_i, eids);

  // kv = x @ W_kv            (M=8192, N=192,  K=768)
  gemm_kernel<128, 64, true, false><<<dim3(NT/128, 192/64), 256, 0, stream>>>(
      x, wkvT, kvb, NT, 192, CC);
  // q_all = x @ W_in (all e) (M=8192, N=2304, K=768)
  gemm_kernel<128, 128, true, false><<<dim3(NT/128, EC/128), 256, 0, stream>>>(
      x, winT, qall, NT, EC, CC);

  attn_kernel<<<dim3(16, 64), 256, 0, stream>>>(qall, kvb, eids, ws_f + WS_G/4, z);

  // out = z @ W_out          (M=8192, N=768,  K=2304)
  gemm_kernel<64, 128, false, true><<<dim3(NT/64, CC/128), 256, 0, stream>>>(
      z, woutT, out, NT, CC, EC);

  aux_kernel<<<1, 64, 0, stream>>>(ws_f, ws_i, out);
}

// Round 4
// 330.082 us; speedup vs baseline: 4.0631x; 1.3442x over previous
//
#include <hip/hip_runtime.h>
#include <hip/hip_bf16.h>
#include <math.h>

#define BB 8
#define NN 1024
#define CC 768
#define HH 8
#define HD 96
#define EE 24
#define NT (BB*NN)          // 8192 tokens
#define NSLOT (NT*HH)       // 65536 (token,h) slots
#define EC (EE*HD)          // 2304
#define ASCALE 0.10206207261596575f  // 96^-0.5

typedef unsigned short u16;
typedef unsigned char u8;
typedef unsigned long long u64;
typedef __attribute__((ext_vector_type(8))) short s16x8;
typedef __attribute__((ext_vector_type(4))) float f32x4;

__device__ inline u16 f2b(float f) {  // RNE float->bf16 bits
  unsigned u = __builtin_bit_cast(unsigned, f);
  unsigned r = u + 0x7fffu + ((u >> 16) & 1u);
  return (u16)(r >> 16);
}

// ws layout (bytes)
#define WS_CNT   0                         // 24 int
#define WS_IMP   96                        // 24 f32
#define WS_ZSUM  192                       // 1 f32 (pad to 256)
#define WS_G     256                       // NSLOT f32
#define WS_EID   (WS_G + NSLOT*4)          // NSLOT u8
#define WS_KVB   (WS_EID + NSLOT)          // NT*192 u16
#define WS_WIN   (WS_KVB + NT*192*2)       // EC*CC u16   (W_in^T  [e*96+d][c])
#define WS_WOUT  (WS_WIN + EC*CC*2)        // CC*EC u16   (W_out^T [c][e*96+d])
#define WS_WKV   (WS_WOUT + (size_t)CC*EC*2)  // 192*CC u16 (W_kv^T [j][c])
#define WS_QA    (WS_WKV + 192*CC*2)       // NT*EC u16   (q_all bf16)
#define WS_Z     (WS_QA + (size_t)NT*EC*2) // NT*EC u16   (z bf16)

// ---- gating: tiled fp32 GEMM (64 tok x 24 exp) + softmax + top-8 fused ----
// 256 threads / 4 waves; wave w owns experts 6w..6w+5 for all 64 tokens.
__global__ __launch_bounds__(256) void gate_kernel(
    const float* __restrict__ x, const float* __restrict__ Wg_all,
    const int* __restrict__ task_p, float* __restrict__ ws_f,
    int* __restrict__ ws_i, u8* __restrict__ eids)
{
  __shared__ float xs[64][65];    // pad 65: (r+k)%32 banks
  __shared__ float wgs[64][24];   // wave-uniform reads -> broadcast
  __shared__ float lg[64][26];    // logits, then probs
  __shared__ float zl[64];
  __shared__ int hist[EE];

  int t = threadIdx.x;
  int w = t >> 6, r = t & 63;
  int e0 = w * 6;
  int tok0 = blockIdx.x * 64;
  const float* Wg = Wg_all + (size_t)task_p[0] * CC * EE;

  if (t < EE) hist[t] = 0;

  float acc[6];
  #pragma unroll
  for (int c = 0; c < 6; c++) acc[c] = 0.f;

  for (int kb = 0; kb < CC; kb += 64) {
    __syncthreads();
    // stage x tile [64][64] (float4, coalesced)
    #pragma unroll
    for (int i = 0; i < 4; i++) {
      int idx = i * 256 + t;
      int rr = idx >> 4, cc = (idx & 15) << 2;
      *(float4*)&xs[rr][cc] = *(const float4*)&x[(size_t)(tok0 + rr) * CC + kb + cc];
    }
    // stage Wg tile [64][24] (float2, coalesced)
    #pragma unroll
    for (int i = 0; i < 3; i++) {
      int idx = i * 256 + t;
      int kk = idx / 12, c2 = idx % 12;
      *(float2*)&wgs[kk][c2 * 2] = *(const float2*)&Wg[(size_t)(kb + kk) * EE + c2 * 2];
    }
    __syncthreads();
    #pragma unroll 16
    for (int k = 0; k < 64; k++) {
      float xv = xs[r][k];
      float2 w01 = *(const float2*)&wgs[k][e0];
      float2 w23 = *(const float2*)&wgs[k][e0 + 2];
      float2 w45 = *(const float2*)&wgs[k][e0 + 4];
      acc[0] += xv * w01.x; acc[1] += xv * w01.y;
      acc[2] += xv * w23.x; acc[3] += xv * w23.y;
      acc[4] += xv * w45.x; acc[5] += xv * w45.y;
    }
  }
  __syncthreads();
  #pragma unroll
  for (int c = 0; c < 6; c++) lg[r][e0 + c] = acc[c];
  __syncthreads();

  if (t < 64) {
    int token = tok0 + t;
    float l[EE];
    #pragma unroll
    for (int e = 0; e < EE; e++) l[e] = lg[t][e];
    float mx = l[0];
    #pragma unroll
    for (int e = 1; e < EE; e++) mx = fmaxf(mx, l[e]);
    float se = 0.f; float probs[EE];
    #pragma unroll
    for (int e = 0; e < EE; e++) { probs[e] = __expf(l[e] - mx); se += probs[e]; }
    float inv = 1.f / se;
    #pragma unroll
    for (int e = 0; e < EE; e++) probs[e] *= inv;
    float lse = mx + __logf(se);
    zl[t] = lse * lse;

    // top-8, strict > keeps lowest index on ties (matches lax.top_k)
    unsigned taken = 0u;
    float gsum = 0.f;
    float my_g[8]; int my_e[8];
    #pragma unroll
    for (int h = 0; h < HH; h++) {
      float best = -1.f; int bi = 0;
      #pragma unroll
      for (int e = 0; e < EE; e++) {
        bool ok = !((taken >> e) & 1u) && (probs[e] > best);
        best = ok ? probs[e] : best;
        bi   = ok ? e : bi;
      }
      taken |= 1u << bi;
      gsum += best;
      my_g[h] = best; my_e[h] = bi;
    }
    float ginv = 1.f / (gsum + 1e-6f);
    float4 g0, g1;
    g0.x = my_g[0] * ginv; g0.y = my_g[1] * ginv; g0.z = my_g[2] * ginv; g0.w = my_g[3] * ginv;
    g1.x = my_g[4] * ginv; g1.y = my_g[5] * ginv; g1.z = my_g[6] * ginv; g1.w = my_g[7] * ginv;
    float* gbuf = ws_f + WS_G / 4;
    *(float4*)&gbuf[(size_t)token * HH]     = g0;
    *(float4*)&gbuf[(size_t)token * HH + 4] = g1;
    u64 pk = 0;
    #pragma unroll
    for (int h = 0; h < HH; h++) pk |= (u64)(u8)my_e[h] << (8 * h);
    *(u64*)&eids[(size_t)token * HH] = pk;
    #pragma unroll
    for (int h = 0; h < HH; h++) atomicAdd(&hist[my_e[h]], 1);
    // probs back to LDS for importance reduction
    #pragma unroll
    for (int e = 0; e < EE; e++) lg[t][e] = probs[e];
  }
  __syncthreads();
  if (t < EE) {
    float s = 0.f;
    #pragma unroll 8
    for (int rr = 0; rr < 64; rr++) s += lg[rr][t];
    atomicAdd(ws_f + WS_IMP / 4 + t, s);
    atomicAdd(&ws_i[t], hist[t]);
  } else if (t == 32) {
    float s = 0.f;
    #pragma unroll 8
    for (int rr = 0; rr < 64; rr++) s += zl[rr];
    atomicAdd(ws_f + WS_ZSUM / 4, s);
  }
}

// -------- batched transpose + f32->bf16: dst[e*dB + c*dR + r] = src[e*sB + r*C + c]
__global__ __launch_bounds__(256) void transpose_kernel(
    const float* __restrict__ src, u16* __restrict__ dst,
    int R, int C, int sB, int dR, int dB)
{
  __shared__ float tile[32][33];
  int e = blockIdx.z;
  const float* s = src + (size_t)e * sB;
  int t = threadIdx.x;
  int tr = t >> 5, tc = t & 31;
  #pragma unroll
  for (int i = 0; i < 4; i++) {
    int r = blockIdx.x * 32 + tr + i * 8;
    int c = blockIdx.y * 32 + tc;
    tile[tr + i * 8][tc] = s[(size_t)r * C + c];
  }
  __syncthreads();
  #pragma unroll
  for (int i = 0; i < 4; i++) {
    int sc = blockIdx.y * 32 + tr + i * 8;   // dst row (= src col)
    int sr = blockIdx.x * 32 + tc;           // dst col (= src row)
    dst[(size_t)e * dB + (size_t)sc * dR + sr] = f2b(tile[tc][tr + i * 8]);
  }
}

// -------- dense MFMA GEMM: C[M][N] = A[M][K] @ Bt[N][K]^T --------
// 256 threads, 4 waves in 2x2; BK=64; A fp32 (converted) or bf16; out f32 or bf16.
template<int BM, int BN, bool A_F32, bool OUT_F32>
__global__ __launch_bounds__(256) void gemm_kernel(
    const void* __restrict__ Ap, const u16* __restrict__ Bt,
    void* __restrict__ Cp, int M, int N, int K)
{
  constexpr int WM = BM / 2, WN = BN / 2;
  constexpr int FM = WM / 16, FN = WN / 16;
  __shared__ u16 As[BM][72];
  __shared__ u16 Bs[BN][72];
  int t = threadIdx.x;
  int w = t >> 6, l = t & 63;
  int lr = l & 15, lg = l >> 4;
  int wr = w >> 1, wc = w & 1;
  int row0 = blockIdx.x * BM;
  int col0 = blockIdx.y * BN;

  f32x4 acc[FM][FN];
  #pragma unroll
  for (int i = 0; i < FM; i++)
    #pragma unroll
    for (int j = 0; j < FN; j++) acc[i][j] = (f32x4)(0.f);

  for (int kb = 0; kb < K; kb += 64) {
    __syncthreads();
    // stage A tile [BM][64]
    #pragma unroll
    for (int i = 0; i < BM / 32; i++) {
      int cid = i * 256 + t;
      int r = cid >> 3, sub = cid & 7;
      if (A_F32) {
        const float* src = (const float*)Ap + (size_t)(row0 + r) * K + kb + sub * 8;
        float4 a0 = *(const float4*)src;
        float4 a1 = *(const float4*)(src + 4);
        union { s16x8 v; u16 u[8]; } pk;
        pk.u[0] = f2b(a0.x); pk.u[1] = f2b(a0.y); pk.u[2] = f2b(a0.z); pk.u[3] = f2b(a0.w);
        pk.u[4] = f2b(a1.x); pk.u[5] = f2b(a1.y); pk.u[6] = f2b(a1.z); pk.u[7] = f2b(a1.w);
        *(s16x8*)&As[r][sub * 8] = pk.v;
      } else {
        const u16* src = (const u16*)Ap + (size_t)(row0 + r) * K + kb + sub * 8;
        *(s16x8*)&As[r][sub * 8] = *(const s16x8*)src;
      }
    }
    // stage B tile [BN][64] from Bt (already bf16, K-major)
    #pragma unroll
    for (int i = 0; i < BN / 32; i++) {
      int cid = i * 256 + t;
      int r = cid >> 3, sub = cid & 7;
      const u16* src = Bt + (size_t)(col0 + r) * K + kb + sub * 8;
      *(s16x8*)&Bs[r][sub * 8] = *(const s16x8*)src;
    }
    __syncthreads();
    #pragma unroll
    for (int ks = 0; ks < 2; ks++) {
      s16x8 af[FM], bf[FN];
      #pragma unroll
      for (int i = 0; i < FM; i++)
        af[i] = *(const s16x8*)&As[wr * WM + i * 16 + lr][ks * 32 + lg * 8];
      #pragma unroll
      for (int j = 0; j < FN; j++)
        bf[j] = *(const s16x8*)&Bs[wc * WN + j * 16 + lr][ks * 32 + lg * 8];
      #pragma unroll
      for (int i = 0; i < FM; i++)
        #pragma unroll
        for (int j = 0; j < FN; j++)
          acc[i][j] = __builtin_amdgcn_mfma_f32_16x16x32_bf16(af[i], bf[j], acc[i][j], 0, 0, 0);
    }
  }
  // epilogue: D layout col=lr, row=lg*4+reg
  #pragma unroll
  for (int i = 0; i < FM; i++)
    #pragma unroll
    for (int j = 0; j < FN; j++)
      #pragma unroll
      for (int reg = 0; reg < 4; reg++) {
        int r = row0 + wr * WM + i * 16 + lg * 4 + reg;
        int c = col0 + wc * WN + j * 16 + lr;
        if (OUT_F32) ((float*)Cp)[(size_t)r * N + c] = acc[i][j][reg];
        else ((u16*)Cp)[(size_t)r * N + c] = f2b(acc[i][j][reg]);
      }
}

// ---------------- flash attention, bf16 MFMA; writes z = g * o (bf16) -----
__global__ __launch_bounds__(256) void attn_kernel(
    const u16* __restrict__ qall, const u16* __restrict__ kvb,
    const u8* __restrict__ eids, const float* __restrict__ gbuf,
    u16* __restrict__ z)
{
  __shared__ u16 Ks[64][104];
  __shared__ u16 Vt[96][72];
  __shared__ u16 Ps[64][72];
  int bh = blockIdx.y;
  int b = bh >> 3, h = bh & 7;
  int i0 = blockIdx.x * 64;
  int t = threadIdx.x;
  int w = t >> 6, l = t & 63;
  int wq0 = w * 16;
  int lr = l & 15;
  int lg = l >> 4;

  // Q fragments from q_all via per-slot expert id
  s16x8 qf[3];
  {
    int tok = b * NN + i0 + wq0 + lr;
    int e = eids[tok * HH + h];
    const u16* qp = qall + (size_t)tok * EC + e * HD + lg * 8;
    qf[0] = *(const s16x8*)(qp);
    qf[1] = *(const s16x8*)(qp + 32);
    qf[2] = *(const s16x8*)(qp + 64);
  }

  f32x4 o[6];
  #pragma unroll
  for (int c = 0; c < 6; c++) o[c] = (f32x4)(0.f);
  float m[4], lsum[4];
  #pragma unroll
  for (int r = 0; r < 4; r++) { m[r] = -1e30f; lsum[r] = 0.f; }

  int kj = t >> 2, kp = t & 3;
  int vj = t & 63, vd = t >> 6;

  for (int jt = 0; jt < 16; jt++) {
    int j0 = jt * 64;
    __syncthreads();
    {
      const u16* src = kvb + (size_t)(b * NN + j0 + kj) * 192 + kp * 24;
      s16x8 a0 = *(const s16x8*)(src);
      s16x8 a1 = *(const s16x8*)(src + 8);
      s16x8 a2 = *(const s16x8*)(src + 16);
      *(s16x8*)&Ks[kj][kp * 24]      = a0;
      *(s16x8*)&Ks[kj][kp * 24 + 8]  = a1;
      *(s16x8*)&Ks[kj][kp * 24 + 16] = a2;
    }
    {
      const u16* src = kvb + (size_t)(b * NN + j0 + vj) * 192 + 96 + vd * 24;
      s16x8 a0 = *(const s16x8*)(src);
      s16x8 a1 = *(const s16x8*)(src + 8);
      s16x8 a2 = *(const s16x8*)(src + 16);
      #pragma unroll
      for (int s = 0; s < 8; s++) Vt[vd * 24 + s][vj]      = ((u16*)&a0)[s];
      #pragma unroll
      for (int s = 0; s < 8; s++) Vt[vd * 24 + 8 + s][vj]  = ((u16*)&a1)[s];
      #pragma unroll
      for (int s = 0; s < 8; s++) Vt[vd * 24 + 16 + s][vj] = ((u16*)&a2)[s];
    }
    __syncthreads();

    f32x4 sacc[4];
    #pragma unroll
    for (int c = 0; c < 4; c++) sacc[c] = (f32x4)(0.f);
    #pragma unroll
    for (int ks = 0; ks < 3; ks++) {
      #pragma unroll
      for (int c = 0; c < 4; c++) {
        s16x8 kbf = *(const s16x8*)&Ks[c * 16 + lr][ks * 32 + lg * 8];
        sacc[c] = __builtin_amdgcn_mfma_f32_16x16x32_bf16(qf[ks], kbf, sacc[c], 0, 0, 0);
      }
    }

    #pragma unroll
    for (int reg = 0; reg < 4; reg++) {
      float v = fmaxf(fmaxf(sacc[0][reg], sacc[1][reg]),
                      fmaxf(sacc[2][reg], sacc[3][reg]));
      v = fmaxf(v, __shfl_xor(v, 1));
      v = fmaxf(v, __shfl_xor(v, 2));
      v = fmaxf(v, __shfl_xor(v, 4));
      v = fmaxf(v, __shfl_xor(v, 8));
      float rmax = v * ASCALE;
      float mn = fmaxf(m[reg], rmax);
      float al = __expf(m[reg] - mn);
      m[reg] = mn;
      float ts = 0.f;
      int prow = wq0 + lg * 4 + reg;
      #pragma unroll
      for (int c = 0; c < 4; c++) {
        float p = __expf(sacc[c][reg] * ASCALE - mn);
        ts += p;
        Ps[prow][c * 16 + lr] = f2b(p);
      }
      ts += __shfl_xor(ts, 1);
      ts += __shfl_xor(ts, 2);
      ts += __shfl_xor(ts, 4);
      ts += __shfl_xor(ts, 8);
      lsum[reg] = lsum[reg] * al + ts;
      #pragma unroll
      for (int c = 0; c < 6; c++) o[c][reg] *= al;
    }

    #pragma unroll
    for (int ks = 0; ks < 2; ks++) {
      s16x8 pa = *(const s16x8*)&Ps[wq0 + lr][ks * 32 + lg * 8];
      #pragma unroll
      for (int c = 0; c < 6; c++) {
        s16x8 vb = *(const s16x8*)&Vt[c * 16 + lr][ks * 32 + lg * 8];
        o[c] = __builtin_amdgcn_mfma_f32_16x16x32_bf16(pa, vb, o[c], 0, 0, 0);
      }
    }
  }

  // write z[tok][e*96+d] = g * o / l   (bf16)
  #pragma unroll
  for (int reg = 0; reg < 4; reg++) {
    int tok = b * NN + i0 + wq0 + lg * 4 + reg;
    int slot = tok * HH + h;
    int e = eids[slot];
    float g = gbuf[slot];
    float inv = g / lsum[reg];
    size_t base = (size_t)tok * EC + e * HD;
    #pragma unroll
    for (int c = 0; c < 6; c++)
      z[base + c * 16 + lr] = f2b(o[c][reg] * inv);
  }
}

// ---------------- aux loss ----------------
__global__ void aux_kernel(const float* __restrict__ ws_f,
                           const int* __restrict__ ws_i, float* __restrict__ out)
{
  if (threadIdx.x == 0 && blockIdx.x == 0) {
    float sw = 0.f;
    for (int e = 0; e < EE; e++) {
      float imp = ws_f[WS_IMP / 4 + e] / (float)NT;
      float load = (float)ws_i[e] / (float)(NT * HH);
      sw += imp * load;
    }
    float zl = ws_f[WS_ZSUM / 4] / (float)NT;
    out[(size_t)NT * CC] = 0.1f * ((float)EE * sw) + 0.001f * zl;
  }
}

extern "C" void kernel_launch(void* const* d_in, const int* in_sizes, int n_in,
                              void* d_out, int out_size, void* d_ws, size_t ws_size,
                              hipStream_t stream)
{
  const float* x    = (const float*)d_in[0];
  const float* Wg   = (const float*)d_in[1];
  const float* Win  = (const float*)d_in[2];
  const float* Wout = (const float*)d_in[3];
  const float* Wkv  = (const float*)d_in[4];
  const int*   task = (const int*)d_in[5];
  float* out = (float*)d_out;
  float* ws_f = (float*)d_ws;
  int*   ws_i = (int*)d_ws;
  u8*  eids = (u8*)((char*)d_ws + WS_EID);
  u16* kvb  = (u16*)((char*)d_ws + WS_KVB);
  u16* winT = (u16*)((char*)d_ws + WS_WIN);
  u16* woutT= (u16*)((char*)d_ws + WS_WOUT);
  u16* wkvT = (u16*)((char*)d_ws + WS_WKV);
  u16* qall = (u16*)((char*)d_ws + WS_QA);
  u16* z    = (u16*)((char*)d_ws + WS_Z);

  hipMemsetAsync(d_ws, 0, 256, stream);
  hipMemsetAsync(z, 0, (size_t)NT * EC * 2, stream);

  // weight transposes (f32 -> bf16)
  transpose_kernel<<<dim3(CC/32, HD/32, EE), 256, 0, stream>>>(Win, winT, CC, HD, CC*HD, CC, HD*CC);
  transpose_kernel<<<dim3(HD/32, CC/32, EE), 256, 0, stream>>>(Wout, woutT, HD, CC, HD*CC, EC, HD);
  transpose_kernel<<<dim3(CC/32, 192/32, 1), 256, 0, stream>>>(Wkv, wkvT, CC, 192, 0, CC, 0);

  gate_kernel<<<NT / 64, 256, 0, stream>>>(x, Wg, task, ws_f, ws_i, eids);

  // kv = x @ W_kv            (M=8192, N=192,  K=768)
  gemm_kernel<128, 64, true, false><<<dim3(NT/128, 192/64), 256, 0, stream>>>(
      x, wkvT, kvb, NT, 192, CC);
  // q_all = x @ W_in (all e) (M=8192, N=2304, K=768)
  gemm_kernel<128, 128, true, false><<<dim3(NT/128, EC/128), 256, 0, stream>>>(
      x, winT, qall, NT, EC, CC);

  attn_kernel<<<dim3(16, 64), 256, 0, stream>>>(qall, kvb, eids, ws_f + WS_G/4, z);

  // out = z @ W_out          (M=8192, N=768,  K=2304)
  gemm_kernel<64, 128, false, true><<<dim3(NT/64, CC/128), 256, 0, stream>>>(
      z, woutT, out, NT, CC, EC);

  aux_kernel<<<1, 64, 0, stream>>>(ws_f, ws_i, out);
}

// Round 5
// 249.847 us; speedup vs baseline: 5.3679x; 1.3211x over previous
//
#include <hip/hip_runtime.h>
#include <hip/hip_bf16.h>
#include <math.h>

#define BB 8
#define NN 1024
#define CC 768
#define HH 8
#define HD 96
#define EE 24
#define NT (BB*NN)          // 8192 tokens
#define NSLOT (NT*HH)       // 65536 (token,h) slots
#define EC (EE*HD)          // 2304
#define ASCALE 0.10206207261596575f  // 96^-0.5

typedef unsigned short u16;
typedef unsigned char u8;
typedef unsigned long long u64;
typedef __attribute__((ext_vector_type(8))) short s16x8;
typedef __attribute__((ext_vector_type(4))) float f32x4;

__device__ __forceinline__ u16 f2b(float f) {  // RNE float->bf16 bits
  unsigned u = __builtin_bit_cast(unsigned, f);
  unsigned r = u + 0x7fffu + ((u >> 16) & 1u);
  return (u16)(r >> 16);
}

__device__ __forceinline__ void gload16(const u16* g, u16* lds) {
  __builtin_amdgcn_global_load_lds(
      (const __attribute__((address_space(1))) void*)g,
      (__attribute__((address_space(3))) void*)lds, 16, 0, 0);
}

// ws layout (bytes)
#define WS_CNT   0
#define WS_IMP   96
#define WS_ZSUM  192
#define WS_G     256
#define WS_EID   (WS_G + NSLOT*4)
#define WS_KVK   (WS_EID + NSLOT)
#define WS_VT    (WS_KVK + NT*96*2)
#define WS_WIN   (WS_VT + (size_t)96*NT*2)
#define WS_WOUT  (WS_WIN + (size_t)EC*CC*2)
#define WS_WKV   (WS_WOUT + (size_t)CC*EC*2)
#define WS_QA    (WS_WKV + 192*CC*2)
#define WS_Z     (WS_QA + (size_t)NT*EC*2)
#define WS_XB    WS_Z    // aliases z; xb dead before z memset

// ---- gating: tiled fp32 GEMM + softmax + top-8 fused; also emits xb=bf16(x)
__global__ __launch_bounds__(256) void gate_kernel(
    const float* __restrict__ x, const float* __restrict__ Wg_all,
    const int* __restrict__ task_p, float* __restrict__ ws_f,
    int* __restrict__ ws_i, u8* __restrict__ eids, u16* __restrict__ xb)
{
  __shared__ float xs[64][65];
  __shared__ float wgs[64][24];
  __shared__ float lgt[64][26];
  __shared__ float zlo[64];
  __shared__ int hist[EE];

  int t = threadIdx.x;
  int w = t >> 6, r = t & 63;
  int e0 = w * 6;
  int tok0 = blockIdx.x * 64;
  const float* Wg = Wg_all + (size_t)task_p[0] * CC * EE;

  if (t < EE) hist[t] = 0;

  float acc[6];
  #pragma unroll
  for (int c = 0; c < 6; c++) acc[c] = 0.f;

  for (int kb = 0; kb < CC; kb += 64) {
    __syncthreads();
    #pragma unroll
    for (int i = 0; i < 4; i++) {
      int idx = i * 256 + t;
      int rr = idx >> 4, cc = (idx & 15) << 2;
      float4 v = *(const float4*)&x[(size_t)(tok0 + rr) * CC + kb + cc];
      *(float4*)&xs[rr][cc] = v;
      u64 pk = (u64)f2b(v.x) | ((u64)f2b(v.y) << 16) |
               ((u64)f2b(v.z) << 32) | ((u64)f2b(v.w) << 48);
      *(u64*)&xb[(size_t)(tok0 + rr) * CC + kb + cc] = pk;
    }
    #pragma unroll
    for (int i = 0; i < 3; i++) {
      int idx = i * 256 + t;
      int kk = idx / 12, c2 = idx % 12;
      *(float2*)&wgs[kk][c2 * 2] = *(const float2*)&Wg[(size_t)(kb + kk) * EE + c2 * 2];
    }
    __syncthreads();
    #pragma unroll 16
    for (int k = 0; k < 64; k++) {
      float xv = xs[r][k];
      float2 w01 = *(const float2*)&wgs[k][e0];
      float2 w23 = *(const float2*)&wgs[k][e0 + 2];
      float2 w45 = *(const float2*)&wgs[k][e0 + 4];
      acc[0] += xv * w01.x; acc[1] += xv * w01.y;
      acc[2] += xv * w23.x; acc[3] += xv * w23.y;
      acc[4] += xv * w45.x; acc[5] += xv * w45.y;
    }
  }
  __syncthreads();
  #pragma unroll
  for (int c = 0; c < 6; c++) lgt[r][e0 + c] = acc[c];
  __syncthreads();

  if (t < 64) {
    int token = tok0 + t;
    float l[EE];
    #pragma unroll
    for (int e = 0; e < EE; e++) l[e] = lgt[t][e];
    float mx = l[0];
    #pragma unroll
    for (int e = 1; e < EE; e++) mx = fmaxf(mx, l[e]);
    float se = 0.f; float probs[EE];
    #pragma unroll
    for (int e = 0; e < EE; e++) { probs[e] = __expf(l[e] - mx); se += probs[e]; }
    float inv = 1.f / se;
    #pragma unroll
    for (int e = 0; e < EE; e++) probs[e] *= inv;
    float lse = mx + __logf(se);
    zlo[t] = lse * lse;

    unsigned taken = 0u;
    float gsum = 0.f;
    float my_g[8]; int my_e[8];
    #pragma unroll
    for (int h = 0; h < HH; h++) {
      float best = -1.f; int bi = 0;
      #pragma unroll
      for (int e = 0; e < EE; e++) {
        bool ok = !((taken >> e) & 1u) && (probs[e] > best);
        best = ok ? probs[e] : best;
        bi   = ok ? e : bi;
      }
      taken |= 1u << bi;
      gsum += best;
      my_g[h] = best; my_e[h] = bi;
    }
    float ginv = 1.f / (gsum + 1e-6f);
    float4 g0, g1;
    g0.x = my_g[0] * ginv; g0.y = my_g[1] * ginv; g0.z = my_g[2] * ginv; g0.w = my_g[3] * ginv;
    g1.x = my_g[4] * ginv; g1.y = my_g[5] * ginv; g1.z = my_g[6] * ginv; g1.w = my_g[7] * ginv;
    float* gbuf = ws_f + WS_G / 4;
    *(float4*)&gbuf[(size_t)token * HH]     = g0;
    *(float4*)&gbuf[(size_t)token * HH + 4] = g1;
    u64 pk = 0;
    #pragma unroll
    for (int h = 0; h < HH; h++) pk |= (u64)(u8)my_e[h] << (8 * h);
    *(u64*)&eids[(size_t)token * HH] = pk;
    #pragma unroll
    for (int h = 0; h < HH; h++) atomicAdd(&hist[my_e[h]], 1);
    #pragma unroll
    for (int e = 0; e < EE; e++) lgt[t][e] = probs[e];
  }
  __syncthreads();
  if (t < EE) {
    float s = 0.f;
    #pragma unroll 8
    for (int rr = 0; rr < 64; rr++) s += lgt[rr][t];
    atomicAdd(ws_f + WS_IMP / 4 + t, s);
    atomicAdd(&ws_i[t], hist[t]);
  } else if (t == 32) {
    float s = 0.f;
    #pragma unroll 8
    for (int rr = 0; rr < 64; rr++) s += zlo[rr];
    atomicAdd(ws_f + WS_ZSUM / 4, s);
  }
}

// -------- batched transpose + f32->bf16 --------
__global__ __launch_bounds__(256) void transpose_kernel(
    const float* __restrict__ src, u16* __restrict__ dst,
    int R, int C, int sB, int dR, int dB)
{
  __shared__ float tile[32][33];
  int e = blockIdx.z;
  const float* s = src + (size_t)e * sB;
  int t = threadIdx.x;
  int tr = t >> 5, tc = t & 31;
  #pragma unroll
  for (int i = 0; i < 4; i++) {
    int r = blockIdx.x * 32 + tr + i * 8;
    int c = blockIdx.y * 32 + tc;
    tile[tr + i * 8][tc] = s[(size_t)r * C + c];
  }
  __syncthreads();
  #pragma unroll
  for (int i = 0; i < 4; i++) {
    int sc = blockIdx.y * 32 + tr + i * 8;
    int sr = blockIdx.x * 32 + tc;
    dst[(size_t)e * dB + (size_t)sc * dR + sr] = f2b(tile[tc][tr + i * 8]);
  }
}

// -------- dense MFMA GEMM, bf16 A/B, global_load_lds staging --------
// grid: (N/BN, M/BM) -- consecutive blocks share the A row-panel (L2)
template<int BM, int BN, bool OUT_F32>
__global__ __launch_bounds__(256) void gemm_kernel(
    const u16* __restrict__ A, const u16* __restrict__ Bt,
    void* __restrict__ Cp, int M, int N, int K)
{
  constexpr int WM = BM / 2, WN = BN / 2;
  constexpr int FM = WM / 16, FN = WN / 16;
  __shared__ u16 As[BM][64];
  __shared__ u16 Bs[BN][64];
  int t = threadIdx.x;
  int w = t >> 6, l = t & 63;
  int lr = l & 15, lg = l >> 4;
  int wr = w >> 1, wc = w & 1;
  int col0 = blockIdx.x * BN, row0 = blockIdx.y * BM;

  f32x4 acc[FM][FN];
  #pragma unroll
  for (int i = 0; i < FM; i++)
    #pragma unroll
    for (int j = 0; j < FN; j++) acc[i][j] = (f32x4)(0.f);

  int sr = t >> 3;   // linear per wave: dest = base + lane*16B
  int sc = t & 7;
  for (int kb = 0; kb < K; kb += 64) {
    __syncthreads();
    #pragma unroll
    for (int i = 0; i < BM / 32; i++) {
      int rr = i * 32 + sr;
      int ch = sc ^ (rr & 7);      // inverse-swizzled source chunk
      gload16(A + (size_t)(row0 + rr) * K + kb + ch * 8, &As[rr][sc * 8]);
    }
    #pragma unroll
    for (int i = 0; i < BN / 32; i++) {
      int rr = i * 32 + sr;
      int ch = sc ^ (rr & 7);
      gload16(Bt + (size_t)(col0 + rr) * K + kb + ch * 8, &Bs[rr][sc * 8]);
    }
    __syncthreads();
    #pragma unroll
    for (int ks = 0; ks < 2; ks++) {
      s16x8 af[FM], bf[FN];
      #pragma unroll
      for (int i = 0; i < FM; i++)
        af[i] = *(const s16x8*)&As[wr * WM + i * 16 + lr][8 * ((ks * 4 + lg) ^ (lr & 7))];
      #pragma unroll
      for (int j = 0; j < FN; j++)
        bf[j] = *(const s16x8*)&Bs[wc * WN + j * 16 + lr][8 * ((ks * 4 + lg) ^ (lr & 7))];
      #pragma unroll
      for (int i = 0; i < FM; i++)
        #pragma unroll
        for (int j = 0; j < FN; j++)
          acc[i][j] = __builtin_amdgcn_mfma_f32_16x16x32_bf16(af[i], bf[j], acc[i][j], 0, 0, 0);
    }
  }
  #pragma unroll
  for (int i = 0; i < FM; i++)
    #pragma unroll
    for (int j = 0; j < FN; j++)
      #pragma unroll
      for (int reg = 0; reg < 4; reg++) {
        int rr = row0 + wr * WM + i * 16 + lg * 4 + reg;
        int cc = col0 + wc * WN + j * 16 + lr;
        if (OUT_F32) ((float*)Cp)[(size_t)rr * N + cc] = acc[i][j][reg];
        else ((u16*)Cp)[(size_t)rr * N + cc] = f2b(acc[i][j][reg]);
      }
}

// -------- kv projection -> kvbk[tok][96] (K) + vtb[d][tok] (V^T) --------
__global__ __launch_bounds__(256) void kvproj_kernel(
    const u16* __restrict__ xb, const u16* __restrict__ wkvT,
    u16* __restrict__ kvbk, u16* __restrict__ vtb)
{
  __shared__ u16 As[128][64];
  __shared__ u16 Bs[64][64];
  int t = threadIdx.x;
  int w = t >> 6, l = t & 63;
  int lr = l & 15, lg = l >> 4;
  int wr = w >> 1, wc = w & 1;
  int col0 = blockIdx.x * 64, row0 = blockIdx.y * 128;

  f32x4 acc[4][2];
  #pragma unroll
  for (int i = 0; i < 4; i++)
    #pragma unroll
    for (int j = 0; j < 2; j++) acc[i][j] = (f32x4)(0.f);

  int sr = t >> 3, sc = t & 7;
  for (int kb = 0; kb < CC; kb += 64) {
    __syncthreads();
    #pragma unroll
    for (int i = 0; i < 4; i++) {
      int rr = i * 32 + sr;
      int ch = sc ^ (rr & 7);
      gload16(xb + (size_t)(row0 + rr) * CC + kb + ch * 8, &As[rr][sc * 8]);
    }
    #pragma unroll
    for (int i = 0; i < 2; i++) {
      int rr = i * 32 + sr;
      int ch = sc ^ (rr & 7);
      gload16(wkvT + (size_t)(col0 + rr) * CC + kb + ch * 8, &Bs[rr][sc * 8]);
    }
    __syncthreads();
    #pragma unroll
    for (int ks = 0; ks < 2; ks++) {
      s16x8 af[4], bf[2];
      #pragma unroll
      for (int i = 0; i < 4; i++)
        af[i] = *(const s16x8*)&As[wr * 64 + i * 16 + lr][8 * ((ks * 4 + lg) ^ (lr & 7))];
      #pragma unroll
      for (int j = 0; j < 2; j++)
        bf[j] = *(const s16x8*)&Bs[wc * 32 + j * 16 + lr][8 * ((ks * 4 + lg) ^ (lr & 7))];
      #pragma unroll
      for (int i = 0; i < 4; i++)
        #pragma unroll
        for (int j = 0; j < 2; j++)
          acc[i][j] = __builtin_amdgcn_mfma_f32_16x16x32_bf16(af[i], bf[j], acc[i][j], 0, 0, 0);
    }
  }
  #pragma unroll
  for (int i = 0; i < 4; i++)
    #pragma unroll
    for (int j = 0; j < 2; j++) {
      int cb = col0 + wc * 32 + j * 16 + lr;
      int rb = row0 + wr * 64 + i * 16 + lg * 4;
      if (cb < 96) {
        #pragma unroll
        for (int reg = 0; reg < 4; reg++)
          kvbk[(size_t)(rb + reg) * 96 + cb] = f2b(acc[i][j][reg]);
      } else {
        u64 pk = (u64)f2b(acc[i][j][0]) | ((u64)f2b(acc[i][j][1]) << 16) |
                 ((u64)f2b(acc[i][j][2]) << 32) | ((u64)f2b(acc[i][j][3]) << 48);
        *(u64*)&vtb[(size_t)(cb - 96) * NT + rb] = pk;
      }
    }
}

// ---------------- flash attention: 8 waves = 8 heads, 32 tokens/block -----
__global__ __launch_bounds__(512) void attn_kernel(
    const u16* __restrict__ qall, const u16* __restrict__ kvbk,
    const u16* __restrict__ vtb, const u8* __restrict__ eids,
    const float* __restrict__ gbuf, u16* __restrict__ z)
{
  __shared__ u16 Ks[64][128];
  __shared__ u16 Vt[96][64];
  __shared__ u16 Ps[8][32][64];
  int b = blockIdx.y;
  int tok0 = blockIdx.x * 32;
  int t = threadIdx.x;
  int w = t >> 6, l = t & 63;     // wave = head
  int lr = l & 15, lg = l >> 4;

  s16x8 qf[2][3];
  #pragma unroll
  for (int i = 0; i < 2; i++) {
    int tok = b * NN + tok0 + i * 16 + lr;
    int e = eids[tok * HH + w];
    const u16* qp = qall + (size_t)tok * EC + e * HD;
    #pragma unroll
    for (int ks = 0; ks < 3; ks++)
      qf[i][ks] = *(const s16x8*)(qp + ks * 32 + lg * 8);
  }

  s16x8 vb1;   // ones column -> row-sums l via MFMA
  {
    u16 o1 = (lr == 0) ? (u16)0x3F80 : (u16)0;
    #pragma unroll
    for (int s = 0; s < 8; s++) ((u16*)&vb1)[s] = o1;
  }

  f32x4 o[2][6], ol[2];
  #pragma unroll
  for (int i = 0; i < 2; i++) {
    ol[i] = (f32x4)(0.f);
    #pragma unroll
    for (int c = 0; c < 6; c++) o[i][c] = (f32x4)(0.f);
  }
  float m[2][4];
  #pragma unroll
  for (int i = 0; i < 2; i++)
    #pragma unroll
    for (int reg = 0; reg < 4; reg++) m[i][reg] = -1e30f;

  for (int jt = 0; jt < 16; jt++) {
    int j0 = jt * 64;
    __syncthreads();
    #pragma unroll
    for (int rr = 0; rr < 2; rr++) {
      int idx = rr * 512 + t;
      if (idx < 768) {
        int kj = idx / 12, kc = idx - kj * 12;
        const u16* src = kvbk + (size_t)(b * NN + j0 + kj) * 96 + kc * 8;
        *(s16x8*)&Ks[kj][8 * (kc ^ (kj & 7))] = *(const s16x8*)src;
      }
    }
    #pragma unroll
    for (int rr = 0; rr < 2; rr++) {
      int idx = rr * 512 + t;
      if (idx < 768) {
        int vd = idx >> 3, ch = idx & 7;
        const u16* src = vtb + (size_t)vd * NT + b * NN + j0 + ch * 8;
        *(s16x8*)&Vt[vd][8 * (ch ^ (vd & 7))] = *(const s16x8*)src;
      }
    }
    __syncthreads();

    f32x4 sa[2][4];
    #pragma unroll
    for (int i = 0; i < 2; i++)
      #pragma unroll
      for (int c = 0; c < 4; c++) sa[i][c] = (f32x4)(0.f);
    #pragma unroll
    for (int ks = 0; ks < 3; ks++) {
      #pragma unroll
      for (int c = 0; c < 4; c++) {
        s16x8 kbf = *(const s16x8*)&Ks[c * 16 + lr][8 * ((ks * 4 + lg) ^ (lr & 7))];
        sa[0][c] = __builtin_amdgcn_mfma_f32_16x16x32_bf16(qf[0][ks], kbf, sa[0][c], 0, 0, 0);
        sa[1][c] = __builtin_amdgcn_mfma_f32_16x16x32_bf16(qf[1][ks], kbf, sa[1][c], 0, 0, 0);
      }
    }

    float rmax[2][4];
    int need = 0;
    #pragma unroll
    for (int i = 0; i < 2; i++)
      #pragma unroll
      for (int reg = 0; reg < 4; reg++) {
        float v = fmaxf(fmaxf(sa[i][0][reg], sa[i][1][reg]),
                        fmaxf(sa[i][2][reg], sa[i][3][reg]));
        v = fmaxf(v, __shfl_xor(v, 1));
        v = fmaxf(v, __shfl_xor(v, 2));
        v = fmaxf(v, __shfl_xor(v, 4));
        v = fmaxf(v, __shfl_xor(v, 8));
        v *= ASCALE;
        rmax[i][reg] = v;
        need |= (v > m[i][reg]) ? 1 : 0;
      }
    if (__any(need)) {
      #pragma unroll
      for (int i = 0; i < 2; i++)
        #pragma unroll
        for (int reg = 0; reg < 4; reg++) {
          float mn = fmaxf(m[i][reg], rmax[i][reg]);
          float al = __expf(m[i][reg] - mn);
          m[i][reg] = mn;
          #pragma unroll
          for (int c = 0; c < 6; c++) o[i][c][reg] *= al;
          ol[i][reg] *= al;
        }
    }

    #pragma unroll
    for (int i = 0; i < 2; i++)
      #pragma unroll
      for (int reg = 0; reg < 4; reg++) {
        int r = i * 16 + lg * 4 + reg;
        u16* prow = &Ps[w][r][0];
        float mm = m[i][reg];
        #pragma unroll
        for (int c = 0; c < 4; c++) {
          float p = __expf(sa[i][c][reg] * ASCALE - mm);
          int col = c * 16 + lr;
          prow[8 * ((col >> 3) ^ (r & 7)) + (col & 7)] = f2b(p);
        }
      }

    #pragma unroll
    for (int ks = 0; ks < 2; ks++) {
      int swz = 8 * ((ks * 4 + lg) ^ (lr & 7));
      s16x8 pa0 = *(const s16x8*)&Ps[w][lr][swz];
      s16x8 pa1 = *(const s16x8*)&Ps[w][16 + lr][swz];
      #pragma unroll
      for (int c = 0; c < 6; c++) {
        s16x8 vb = *(const s16x8*)&Vt[c * 16 + lr][swz];
        o[0][c] = __builtin_amdgcn_mfma_f32_16x16x32_bf16(pa0, vb, o[0][c], 0, 0, 0);
        o[1][c] = __builtin_amdgcn_mfma_f32_16x16x32_bf16(pa1, vb, o[1][c], 0, 0, 0);
      }
      ol[0] = __builtin_amdgcn_mfma_f32_16x16x32_bf16(pa0, vb1, ol[0], 0, 0, 0);
      ol[1] = __builtin_amdgcn_mfma_f32_16x16x32_bf16(pa1, vb1, ol[1], 0, 0, 0);
    }
  }

  #pragma unroll
  for (int i = 0; i < 2; i++)
    #pragma unroll
    for (int reg = 0; reg < 4; reg++) {
      float lv = __shfl(ol[i][reg], (l & 48));
      int tok = b * NN + tok0 + i * 16 + lg * 4 + reg;
      int slot = tok * HH + w;
      float sc = gbuf[slot] / lv;
      int e = eids[slot];
      u16* zp = z + (size_t)tok * EC + e * HD;
      #pragma unroll
      for (int c = 0; c < 6; c++)
        zp[c * 16 + lr] = f2b(o[i][c][reg] * sc);
    }
}

// ---------------- aux loss ----------------
__global__ void aux_kernel(const float* __restrict__ ws_f,
                           const int* __restrict__ ws_i, float* __restrict__ out)
{
  if (threadIdx.x == 0 && blockIdx.x == 0) {
    float sw = 0.f;
    for (int e = 0; e < EE; e++) {
      float imp = ws_f[WS_IMP / 4 + e] / (float)NT;
      float load = (float)ws_i[e] / (float)(NT * HH);
      sw += imp * load;
    }
    float zl = ws_f[WS_ZSUM / 4] / (float)NT;
    out[(size_t)NT * CC] = 0.1f * ((float)EE * sw) + 0.001f * zl;
  }
}

extern "C" void kernel_launch(void* const* d_in, const int* in_sizes, int n_in,
                              void* d_out, int out_size, void* d_ws, size_t ws_size,
                              hipStream_t stream)
{
  const float* x    = (const float*)d_in[0];
  const float* Wg   = (const float*)d_in[1];
  const float* Win  = (const float*)d_in[2];
  const float* Wout = (const float*)d_in[3];
  const float* Wkv  = (const float*)d_in[4];
  const int*   task = (const int*)d_in[5];
  float* out = (float*)d_out;
  float* ws_f = (float*)d_ws;
  int*   ws_i = (int*)d_ws;
  u8*  eids = (u8*)((char*)d_ws + WS_EID);
  u16* kvbk = (u16*)((char*)d_ws + WS_KVK);
  u16* vtb  = (u16*)((char*)d_ws + WS_VT);
  u16* winT = (u16*)((char*)d_ws + WS_WIN);
  u16* woutT= (u16*)((char*)d_ws + WS_WOUT);
  u16* wkvT = (u16*)((char*)d_ws + WS_WKV);
  u16* qall = (u16*)((char*)d_ws + WS_QA);
  u16* z    = (u16*)((char*)d_ws + WS_Z);
  u16* xb   = (u16*)((char*)d_ws + WS_XB);

  hipMemsetAsync(d_ws, 0, 256, stream);

  transpose_kernel<<<dim3(CC/32, HD/32, EE), 256, 0, stream>>>(Win, winT, CC, HD, CC*HD, CC, HD*CC);
  transpose_kernel<<<dim3(HD/32, CC/32, EE), 256, 0, stream>>>(Wout, woutT, HD, CC, HD*CC, EC, HD);
  transpose_kernel<<<dim3(CC/32, 192/32, 1), 256, 0, stream>>>(Wkv, wkvT, CC, 192, 0, CC, 0);

  gate_kernel<<<NT / 64, 256, 0, stream>>>(x, Wg, task, ws_f, ws_i, eids, xb);

  kvproj_kernel<<<dim3(3, NT/128), 256, 0, stream>>>(xb, wkvT, kvbk, vtb);
  gemm_kernel<128, 128, false><<<dim3(EC/128, NT/128), 256, 0, stream>>>(
      xb, winT, qall, NT, EC, CC);

  hipMemsetAsync(z, 0, (size_t)NT * EC * 2, stream);   // xb dead; z aliases it

  attn_kernel<<<dim3(NN/32, BB), 512, 0, stream>>>(qall, kvbk, vtb, eids, ws_f + WS_G/4, z);

  gemm_kernel<128, 128, true><<<dim3(CC/128, NT/128), 256, 0, stream>>>(
      z, woutT, out, NT, CC, EC);

  aux_kernel<<<1, 64, 0, stream>>>(ws_f, ws_i, out);
}

// Round 6
// 230.673 us; speedup vs baseline: 5.8141x; 1.0831x over previous
//
#include <hip/hip_runtime.h>
#include <hip/hip_bf16.h>
#include <math.h>

#define BB 8
#define NN 1024
#define CC 768
#define HH 8
#define HD 96
#define EE 24
#define NT (BB*NN)          // 8192 tokens
#define NSLOT (NT*HH)       // 65536 (token,h) slots
#define EC (EE*HD)          // 2304
#define ASCALE 0.10206207261596575f  // 96^-0.5

typedef unsigned short u16;
typedef unsigned char u8;
typedef unsigned int u32;
typedef unsigned long long u64;
typedef __attribute__((ext_vector_type(8))) short s16x8;
typedef __attribute__((ext_vector_type(4))) float f32x4;

__device__ __forceinline__ u16 f2b(float f) {  // RNE float->bf16 bits
  unsigned u = __builtin_bit_cast(unsigned, f);
  unsigned r = u + 0x7fffu + ((u >> 16) & 1u);
  return (u16)(r >> 16);
}

__device__ __forceinline__ void gload16(const u16* g, u16* lds) {
  __builtin_amdgcn_global_load_lds(
      (const __attribute__((address_space(1))) void*)g,
      (__attribute__((address_space(3))) void*)lds, 16, 0, 0);
}

// ws layout (bytes)
#define WS_CNT   0
#define WS_IMP   96
#define WS_ZSUM  192
#define WS_G     256
#define WS_EID   (WS_G + NSLOT*4)
#define WS_KVK   (WS_EID + NSLOT)
#define WS_VT    (WS_KVK + NT*96*2)
#define WS_WIN   (WS_VT + (size_t)96*NT*2)
#define WS_WOUT  (WS_WIN + (size_t)EC*CC*2)
#define WS_WKV   (WS_WOUT + (size_t)CC*EC*2)
#define WS_QA    (WS_WKV + 192*CC*2)
#define WS_Z     (WS_QA + (size_t)NT*EC*2)
#define WS_XB    WS_Z    // aliases z; xb dead before z memset

// ---- gating: tiled fp32 GEMM + softmax + top-8 fused; also emits xb=bf16(x)
__global__ __launch_bounds__(256) void gate_kernel(
    const float* __restrict__ x, const float* __restrict__ Wg_all,
    const int* __restrict__ task_p, float* __restrict__ ws_f,
    int* __restrict__ ws_i, u8* __restrict__ eids, u16* __restrict__ xb)
{
  __shared__ float xs[64][65];
  __shared__ float wgs[64][24];
  __shared__ float lgt[64][26];
  __shared__ float zlo[64];
  __shared__ int hist[EE];

  int t = threadIdx.x;
  int w = t >> 6, r = t & 63;
  int e0 = w * 6;
  int tok0 = blockIdx.x * 64;
  const float* Wg = Wg_all + (size_t)task_p[0] * CC * EE;

  if (t < EE) hist[t] = 0;

  float acc[6];
  #pragma unroll
  for (int c = 0; c < 6; c++) acc[c] = 0.f;

  for (int kb = 0; kb < CC; kb += 64) {
    __syncthreads();
    #pragma unroll
    for (int i = 0; i < 4; i++) {
      int idx = i * 256 + t;
      int rr = idx >> 4, cc = (idx & 15) << 2;
      float4 v = *(const float4*)&x[(size_t)(tok0 + rr) * CC + kb + cc];
      *(float4*)&xs[rr][cc] = v;
      u64 pk = (u64)f2b(v.x) | ((u64)f2b(v.y) << 16) |
               ((u64)f2b(v.z) << 32) | ((u64)f2b(v.w) << 48);
      *(u64*)&xb[(size_t)(tok0 + rr) * CC + kb + cc] = pk;
    }
    #pragma unroll
    for (int i = 0; i < 3; i++) {
      int idx = i * 256 + t;
      int kk = idx / 12, c2 = idx % 12;
      *(float2*)&wgs[kk][c2 * 2] = *(const float2*)&Wg[(size_t)(kb + kk) * EE + c2 * 2];
    }
    __syncthreads();
    #pragma unroll 16
    for (int k = 0; k < 64; k++) {
      float xv = xs[r][k];
      float2 w01 = *(const float2*)&wgs[k][e0];
      float2 w23 = *(const float2*)&wgs[k][e0 + 2];
      float2 w45 = *(const float2*)&wgs[k][e0 + 4];
      acc[0] += xv * w01.x; acc[1] += xv * w01.y;
      acc[2] += xv * w23.x; acc[3] += xv * w23.y;
      acc[4] += xv * w45.x; acc[5] += xv * w45.y;
    }
  }
  __syncthreads();
  #pragma unroll
  for (int c = 0; c < 6; c++) lgt[r][e0 + c] = acc[c];
  __syncthreads();

  if (t < 64) {
    int token = tok0 + t;
    float l[EE];
    #pragma unroll
    for (int e = 0; e < EE; e++) l[e] = lgt[t][e];
    float mx = l[0];
    #pragma unroll
    for (int e = 1; e < EE; e++) mx = fmaxf(mx, l[e]);
    float se = 0.f; float probs[EE];
    #pragma unroll
    for (int e = 0; e < EE; e++) { probs[e] = __expf(l[e] - mx); se += probs[e]; }
    float inv = 1.f / se;
    #pragma unroll
    for (int e = 0; e < EE; e++) probs[e] *= inv;
    float lse = mx + __logf(se);
    zlo[t] = lse * lse;

    unsigned taken = 0u;
    float gsum = 0.f;
    float my_g[8]; int my_e[8];
    #pragma unroll
    for (int h = 0; h < HH; h++) {
      float best = -1.f; int bi = 0;
      #pragma unroll
      for (int e = 0; e < EE; e++) {
        bool ok = !((taken >> e) & 1u) && (probs[e] > best);
        best = ok ? probs[e] : best;
        bi   = ok ? e : bi;
      }
      taken |= 1u << bi;
      gsum += best;
      my_g[h] = best; my_e[h] = bi;
    }
    float ginv = 1.f / (gsum + 1e-6f);
    float4 g0, g1;
    g0.x = my_g[0] * ginv; g0.y = my_g[1] * ginv; g0.z = my_g[2] * ginv; g0.w = my_g[3] * ginv;
    g1.x = my_g[4] * ginv; g1.y = my_g[5] * ginv; g1.z = my_g[6] * ginv; g1.w = my_g[7] * ginv;
    float* gbuf = ws_f + WS_G / 4;
    *(float4*)&gbuf[(size_t)token * HH]     = g0;
    *(float4*)&gbuf[(size_t)token * HH + 4] = g1;
    u64 pk = 0;
    #pragma unroll
    for (int h = 0; h < HH; h++) pk |= (u64)(u8)my_e[h] << (8 * h);
    *(u64*)&eids[(size_t)token * HH] = pk;
    #pragma unroll
    for (int h = 0; h < HH; h++) atomicAdd(&hist[my_e[h]], 1);
    #pragma unroll
    for (int e = 0; e < EE; e++) lgt[t][e] = probs[e];
  }
  __syncthreads();
  if (t < EE) {
    float s = 0.f;
    #pragma unroll 8
    for (int rr = 0; rr < 64; rr++) s += lgt[rr][t];
    atomicAdd(ws_f + WS_IMP / 4 + t, s);
    atomicAdd(&ws_i[t], hist[t]);
  } else if (t == 32) {
    float s = 0.f;
    #pragma unroll 8
    for (int rr = 0; rr < 64; rr++) s += zlo[rr];
    atomicAdd(ws_f + WS_ZSUM / 4, s);
  }
}

// -------- batched transpose + f32->bf16 --------
__global__ __launch_bounds__(256) void transpose_kernel(
    const float* __restrict__ src, u16* __restrict__ dst,
    int R, int C, int sB, int dR, int dB)
{
  __shared__ float tile[32][33];
  int e = blockIdx.z;
  const float* s = src + (size_t)e * sB;
  int t = threadIdx.x;
  int tr = t >> 5, tc = t & 31;
  #pragma unroll
  for (int i = 0; i < 4; i++) {
    int r = blockIdx.x * 32 + tr + i * 8;
    int c = blockIdx.y * 32 + tc;
    tile[tr + i * 8][tc] = s[(size_t)r * C + c];
  }
  __syncthreads();
  #pragma unroll
  for (int i = 0; i < 4; i++) {
    int sc = blockIdx.y * 32 + tr + i * 8;
    int sr = blockIdx.x * 32 + tc;
    dst[(size_t)e * dB + (size_t)sc * dR + sr] = f2b(tile[tc][tr + i * 8]);
  }
}

// -------- dense MFMA GEMM, bf16 A/B, global_load_lds staging --------
// grid: (N/BN, M/BM) -- consecutive blocks share the A row-panel (L2)
template<int BM, int BN, bool OUT_F32>
__global__ __launch_bounds__(256) void gemm_kernel(
    const u16* __restrict__ A, const u16* __restrict__ Bt,
    void* __restrict__ Cp, int M, int N, int K)
{
  constexpr int WM = BM / 2, WN = BN / 2;
  constexpr int FM = WM / 16, FN = WN / 16;
  __shared__ u16 As[BM][64];
  __shared__ u16 Bs[BN][64];
  int t = threadIdx.x;
  int w = t >> 6, l = t & 63;
  int lr = l & 15, lg = l >> 4;
  int wr = w >> 1, wc = w & 1;
  int col0 = blockIdx.x * BN, row0 = blockIdx.y * BM;

  f32x4 acc[FM][FN];
  #pragma unroll
  for (int i = 0; i < FM; i++)
    #pragma unroll
    for (int j = 0; j < FN; j++) acc[i][j] = (f32x4)(0.f);

  int sr = t >> 3;   // linear per wave: dest = base + lane*16B
  int sc = t & 7;
  for (int kb = 0; kb < K; kb += 64) {
    __syncthreads();
    #pragma unroll
    for (int i = 0; i < BM / 32; i++) {
      int rr = i * 32 + sr;
      int ch = sc ^ (rr & 7);      // inverse-swizzled source chunk
      gload16(A + (size_t)(row0 + rr) * K + kb + ch * 8, &As[rr][sc * 8]);
    }
    #pragma unroll
    for (int i = 0; i < BN / 32; i++) {
      int rr = i * 32 + sr;
      int ch = sc ^ (rr & 7);
      gload16(Bt + (size_t)(col0 + rr) * K + kb + ch * 8, &Bs[rr][sc * 8]);
    }
    __syncthreads();
    #pragma unroll
    for (int ks = 0; ks < 2; ks++) {
      s16x8 af[FM], bf[FN];
      #pragma unroll
      for (int i = 0; i < FM; i++)
        af[i] = *(const s16x8*)&As[wr * WM + i * 16 + lr][8 * ((ks * 4 + lg) ^ (lr & 7))];
      #pragma unroll
      for (int j = 0; j < FN; j++)
        bf[j] = *(const s16x8*)&Bs[wc * WN + j * 16 + lr][8 * ((ks * 4 + lg) ^ (lr & 7))];
      #pragma unroll
      for (int i = 0; i < FM; i++)
        #pragma unroll
        for (int j = 0; j < FN; j++)
          acc[i][j] = __builtin_amdgcn_mfma_f32_16x16x32_bf16(af[i], bf[j], acc[i][j], 0, 0, 0);
    }
  }
  #pragma unroll
  for (int i = 0; i < FM; i++)
    #pragma unroll
    for (int j = 0; j < FN; j++)
      #pragma unroll
      for (int reg = 0; reg < 4; reg++) {
        int rr = row0 + wr * WM + i * 16 + lg * 4 + reg;
        int cc = col0 + wc * WN + j * 16 + lr;
        if (OUT_F32) ((float*)Cp)[(size_t)rr * N + cc] = acc[i][j][reg];
        else ((u16*)Cp)[(size_t)rr * N + cc] = f2b(acc[i][j][reg]);
      }
}

// -------- kv projection -> kvbk[tok][96] (K) + vtb[d][tok] (V^T) --------
__global__ __launch_bounds__(256) void kvproj_kernel(
    const u16* __restrict__ xb, const u16* __restrict__ wkvT,
    u16* __restrict__ kvbk, u16* __restrict__ vtb)
{
  __shared__ u16 As[128][64];
  __shared__ u16 Bs[64][64];
  int t = threadIdx.x;
  int w = t >> 6, l = t & 63;
  int lr = l & 15, lg = l >> 4;
  int wr = w >> 1, wc = w & 1;
  int col0 = blockIdx.x * 64, row0 = blockIdx.y * 128;

  f32x4 acc[4][2];
  #pragma unroll
  for (int i = 0; i < 4; i++)
    #pragma unroll
    for (int j = 0; j < 2; j++) acc[i][j] = (f32x4)(0.f);

  int sr = t >> 3, sc = t & 7;
  for (int kb = 0; kb < CC; kb += 64) {
    __syncthreads();
    #pragma unroll
    for (int i = 0; i < 4; i++) {
      int rr = i * 32 + sr;
      int ch = sc ^ (rr & 7);
      gload16(xb + (size_t)(row0 + rr) * CC + kb + ch * 8, &As[rr][sc * 8]);
    }
    #pragma unroll
    for (int i = 0; i < 2; i++) {
      int rr = i * 32 + sr;
      int ch = sc ^ (rr & 7);
      gload16(wkvT + (size_t)(col0 + rr) * CC + kb + ch * 8, &Bs[rr][sc * 8]);
    }
    __syncthreads();
    #pragma unroll
    for (int ks = 0; ks < 2; ks++) {
      s16x8 af[4], bf[2];
      #pragma unroll
      for (int i = 0; i < 4; i++)
        af[i] = *(const s16x8*)&As[wr * 64 + i * 16 + lr][8 * ((ks * 4 + lg) ^ (lr & 7))];
      #pragma unroll
      for (int j = 0; j < 2; j++)
        bf[j] = *(const s16x8*)&Bs[wc * 32 + j * 16 + lr][8 * ((ks * 4 + lg) ^ (lr & 7))];
      #pragma unroll
      for (int i = 0; i < 4; i++)
        #pragma unroll
        for (int j = 0; j < 2; j++)
          acc[i][j] = __builtin_amdgcn_mfma_f32_16x16x32_bf16(af[i], bf[j], acc[i][j], 0, 0, 0);
    }
  }
  #pragma unroll
  for (int i = 0; i < 4; i++)
    #pragma unroll
    for (int j = 0; j < 2; j++) {
      int cb = col0 + wc * 32 + j * 16 + lr;
      int rb = row0 + wr * 64 + i * 16 + lg * 4;
      if (cb < 96) {
        #pragma unroll
        for (int reg = 0; reg < 4; reg++)
          kvbk[(size_t)(rb + reg) * 96 + cb] = f2b(acc[i][j][reg]);
      } else {
        u64 pk = (u64)f2b(acc[i][j][0]) | ((u64)f2b(acc[i][j][1]) << 16) |
                 ((u64)f2b(acc[i][j][2]) << 32) | ((u64)f2b(acc[i][j][3]) << 48);
        *(u64*)&vtb[(size_t)(cb - 96) * NT + rb] = pk;
      }
    }
}

// ---- flash attention: 8 waves = 8 heads, 16 tokens/block, swapped QK^T ----
// S^T = mfma(K_frag, Q_frag): lane owns full k-row for q = lane&15.
__global__ __launch_bounds__(512, 4) void attn_kernel(
    const u16* __restrict__ qall, const u16* __restrict__ kvbk,
    const u16* __restrict__ vtb, const u8* __restrict__ eids,
    const float* __restrict__ gbuf, u16* __restrict__ z)
{
  __shared__ u16 Ks[64][128];        // 16 KB, 16B-chunk XOR swizzle
  __shared__ u16 Vt[96][64];         // 12 KB, [d][key] swizzled
  __shared__ u32 Psw[8][16][36];     // 18 KB, u32-packed P rows per wave
  int b = blockIdx.y;
  int tok0 = blockIdx.x * 16;
  int t = threadIdx.x;
  int w = t >> 6, l = t & 63;        // wave = head
  int lr = l & 15, lg = l >> 4;

  // Q B-fragments (row = q = lr)
  s16x8 qf[3];
  {
    int tok = b * NN + tok0 + lr;
    int e = eids[tok * HH + w];
    const u16* qp = qall + (size_t)tok * EC + e * HD;
    #pragma unroll
    for (int ks = 0; ks < 3; ks++)
      qf[ks] = *(const s16x8*)(qp + ks * 32 + lg * 8);
  }

  f32x4 o[6];
  #pragma unroll
  for (int c = 0; c < 6; c++) o[c] = (f32x4)(0.f);
  float m = -1e30f, lsum = 0.f;

  for (int jt = 0; jt < 16; jt++) {
    int j0 = jt * 64;
    __syncthreads();
    // stage K [64][96] swizzled chunks
    #pragma unroll
    for (int rr = 0; rr < 2; rr++) {
      int idx = rr * 512 + t;
      if (idx < 768) {
        int kj = idx / 12, kc = idx - kj * 12;
        const u16* src = kvbk + (size_t)(b * NN + j0 + kj) * 96 + kc * 8;
        *(s16x8*)&Ks[kj][8 * (kc ^ (kj & 7))] = *(const s16x8*)src;
      }
    }
    // stage V^T rows
    #pragma unroll
    for (int rr = 0; rr < 2; rr++) {
      int idx = rr * 512 + t;
      if (idx < 768) {
        int vd = idx >> 3, ch = idx & 7;
        const u16* src = vtb + (size_t)vd * NT + b * NN + j0 + ch * 8;
        *(s16x8*)&Vt[vd][8 * (ch ^ (vd & 7))] = *(const s16x8*)src;
      }
    }
    __syncthreads();

    // S^T = K Q^T : sacc[c][reg] = S[k = c*16 + lg*4 + reg][q = lr]
    f32x4 sacc[4];
    #pragma unroll
    for (int c = 0; c < 4; c++) sacc[c] = (f32x4)(0.f);
    #pragma unroll
    for (int ks = 0; ks < 3; ks++) {
      #pragma unroll
      for (int c = 0; c < 4; c++) {
        s16x8 kbf = *(const s16x8*)&Ks[c * 16 + lr][8 * ((ks * 4 + lg) ^ (lr & 7))];
        sacc[c] = __builtin_amdgcn_mfma_f32_16x16x32_bf16(kbf, qf[ks], sacc[c], 0, 0, 0);
      }
    }

    // row max over k for q=lr: local 16 + 2 shuffles
    float pm = sacc[0][0];
    #pragma unroll
    for (int c = 0; c < 4; c++)
      #pragma unroll
      for (int reg = 0; reg < 4; reg++) pm = fmaxf(pm, sacc[c][reg]);
    pm = fmaxf(pm, __shfl_xor(pm, 16));
    pm = fmaxf(pm, __shfl_xor(pm, 32));
    pm *= ASCALE;

    // defer-max: rescale only when max grows past threshold
    if (!__all(pm - m <= 8.f)) {
      float mn = fmaxf(m, pm);
      float al = __expf(m - mn);
      m = mn;
      lsum *= al;
      float a0 = __shfl(al, lg * 4 + 0);
      float a1 = __shfl(al, lg * 4 + 1);
      float a2 = __shfl(al, lg * 4 + 2);
      float a3 = __shfl(al, lg * 4 + 3);
      #pragma unroll
      for (int c = 0; c < 6; c++) {
        o[c][0] *= a0; o[c][1] *= a1; o[c][2] *= a2; o[c][3] *= a3;
      }
    }

    // P = exp(S*scale - m); pack to bf16 pairs; row-sum
    float ts = 0.f;
    #pragma unroll
    for (int c = 0; c < 4; c++) {
      float p0 = __expf(sacc[c][0] * ASCALE - m);
      float p1 = __expf(sacc[c][1] * ASCALE - m);
      float p2 = __expf(sacc[c][2] * ASCALE - m);
      float p3 = __expf(sacc[c][3] * ASCALE - m);
      ts += (p0 + p1) + (p2 + p3);
      u32 pk0 = (u32)f2b(p0) | ((u32)f2b(p1) << 16);
      u32 pk1 = (u32)f2b(p2) | ((u32)f2b(p3) << 16);
      uint2 pk; pk.x = pk0; pk.y = pk1;
      *(uint2*)&Psw[w][lr][c * 8 + lg * 2] = pk;   // k-pairs c*16+lg*4 .. +3
    }
    ts += __shfl_xor(ts, 16);
    ts += __shfl_xor(ts, 32);
    lsum += ts;

    // O += P V  (A-frag from Psw, B-frag from Vt; same-wave, no barrier)
    #pragma unroll
    for (int ks = 0; ks < 2; ks++) {
      s16x8 pa = *(const s16x8*)&Psw[w][lr][ks * 16 + lg * 4];
      #pragma unroll
      for (int c = 0; c < 6; c++) {
        s16x8 vb = *(const s16x8*)&Vt[c * 16 + lr][8 * ((ks * 4 + lg) ^ (lr & 7))];
        o[c] = __builtin_amdgcn_mfma_f32_16x16x32_bf16(pa, vb, o[c], 0, 0, 0);
      }
    }
  }

  // epilogue: O rows q' = lg*4+reg; l and g fetched per row
  #pragma unroll
  for (int reg = 0; reg < 4; reg++) {
    float lv = __shfl(lsum, lg * 4 + reg);
    int tok = b * NN + tok0 + lg * 4 + reg;
    int slot = tok * HH + w;
    float sc = gbuf[slot] / lv;
    int e = eids[slot];
    u16* zp = z + (size_t)tok * EC + e * HD;
    #pragma unroll
    for (int c = 0; c < 6; c++)
      zp[c * 16 + lr] = f2b(o[c][reg] * sc);
  }
}

// ---------------- aux loss ----------------
__global__ void aux_kernel(const float* __restrict__ ws_f,
                           const int* __restrict__ ws_i, float* __restrict__ out)
{
  if (threadIdx.x == 0 && blockIdx.x == 0) {
    float sw = 0.f;
    for (int e = 0; e < EE; e++) {
      float imp = ws_f[WS_IMP / 4 + e] / (float)NT;
      float load = (float)ws_i[e] / (float)(NT * HH);
      sw += imp * load;
    }
    float zl = ws_f[WS_ZSUM / 4] / (float)NT;
    out[(size_t)NT * CC] = 0.1f * ((float)EE * sw) + 0.001f * zl;
  }
}

extern "C" void kernel_launch(void* const* d_in, const int* in_sizes, int n_in,
                              void* d_out, int out_size, void* d_ws, size_t ws_size,
                              hipStream_t stream)
{
  const float* x    = (const float*)d_in[0];
  const float* Wg   = (const float*)d_in[1];
  const float* Win  = (const float*)d_in[2];
  const float* Wout = (const float*)d_in[3];
  const float* Wkv  = (const float*)d_in[4];
  const int*   task = (const int*)d_in[5];
  float* out = (float*)d_out;
  float* ws_f = (float*)d_ws;
  int*   ws_i = (int*)d_ws;
  u8*  eids = (u8*)((char*)d_ws + WS_EID);
  u16* kvbk = (u16*)((char*)d_ws + WS_KVK);
  u16* vtb  = (u16*)((char*)d_ws + WS_VT);
  u16* winT = (u16*)((char*)d_ws + WS_WIN);
  u16* woutT= (u16*)((char*)d_ws + WS_WOUT);
  u16* wkvT = (u16*)((char*)d_ws + WS_WKV);
  u16* qall = (u16*)((char*)d_ws + WS_QA);
  u16* z    = (u16*)((char*)d_ws + WS_Z);
  u16* xb   = (u16*)((char*)d_ws + WS_XB);

  hipMemsetAsync(d_ws, 0, 256, stream);

  transpose_kernel<<<dim3(CC/32, HD/32, EE), 256, 0, stream>>>(Win, winT, CC, HD, CC*HD, CC, HD*CC);
  transpose_kernel<<<dim3(HD/32, CC/32, EE), 256, 0, stream>>>(Wout, woutT, HD, CC, HD*CC, EC, HD);
  transpose_kernel<<<dim3(CC/32, 192/32, 1), 256, 0, stream>>>(Wkv, wkvT, CC, 192, 0, CC, 0);

  gate_kernel<<<NT / 64, 256, 0, stream>>>(x, Wg, task, ws_f, ws_i, eids, xb);

  kvproj_kernel<<<dim3(3, NT/128), 256, 0, stream>>>(xb, wkvT, kvbk, vtb);
  gemm_kernel<128, 128, false><<<dim3(EC/128, NT/128), 256, 0, stream>>>(
      xb, winT, qall, NT, EC, CC);

  hipMemsetAsync(z, 0, (size_t)NT * EC * 2, stream);   // xb dead; z aliases it

  attn_kernel<<<dim3(NN/16, BB), 512, 0, stream>>>(qall, kvbk, vtb, eids, ws_f + WS_G/4, z);

  gemm_kernel<128, 128, true><<<dim3(CC/128, NT/128), 256, 0, stream>>>(
      z, woutT, out, NT, CC, EC);

  aux_kernel<<<1, 64, 0, stream>>>(ws_f, ws_i, out);
}

// Round 8
// 223.074 us; speedup vs baseline: 6.0121x; 1.0341x over previous
//
#include <hip/hip_runtime.h>
#include <hip/hip_bf16.h>
#include <math.h>

#define BB 8
#define NN 1024
#define CC 768
#define HH 8
#define HD 96
#define EE 24
#define NT (BB*NN)          // 8192 tokens
#define NSLOT (NT*HH)       // 65536 (token,h) slots
#define EC (EE*HD)          // 2304
#define ASCALE 0.10206207261596575f  // 96^-0.5

typedef unsigned short u16;
typedef unsigned char u8;
typedef unsigned int u32;
typedef unsigned long long u64;
typedef __attribute__((ext_vector_type(8))) short s16x8;
typedef __attribute__((ext_vector_type(4))) float f32x4;
typedef __attribute__((ext_vector_type(16))) float f32x16;

__device__ __forceinline__ u16 f2b(float f) {  // RNE float->bf16 bits
  unsigned u = __builtin_bit_cast(unsigned, f);
  unsigned r = u + 0x7fffu + ((u >> 16) & 1u);
  return (u16)(r >> 16);
}

__device__ __forceinline__ void gload16(const u16* g, u16* lds) {
  __builtin_amdgcn_global_load_lds(
      (const __attribute__((address_space(1))) void*)g,
      (__attribute__((address_space(3))) void*)lds, 16, 0, 0);
}

// ws layout (bytes)
#define WS_CNT   0
#define WS_IMP   96
#define WS_ZSUM  192
#define WS_G     256
#define WS_EID   (WS_G + NSLOT*4)
#define WS_KVK   (WS_EID + NSLOT)             // NT*128 u16 (K, padded+pre-swizzled)
#define WS_VT    (WS_KVK + NT*128*2)          // 96*NT u16 (V^T, in-block pre-swizzled)
#define WS_WIN   (WS_VT + (size_t)96*NT*2)
#define WS_WOUT  (WS_WIN + (size_t)EC*CC*2)
#define WS_WKV   (WS_WOUT + (size_t)CC*EC*2)
#define WS_QA    (WS_WKV + 192*CC*2)
#define WS_Z     (WS_QA + (size_t)NT*EC*2)
#define WS_XB    WS_Z    // aliases z; xb dead before z memset

// ---- gating: tiled fp32 GEMM + softmax + top-8 fused; also emits xb=bf16(x)
__global__ __launch_bounds__(256) void gate_kernel(
    const float* __restrict__ x, const float* __restrict__ Wg_all,
    const int* __restrict__ task_p, float* __restrict__ ws_f,
    int* __restrict__ ws_i, u8* __restrict__ eids, u16* __restrict__ xb)
{
  __shared__ float xs[64][65];
  __shared__ float wgs[64][24];
  __shared__ float lgt[64][26];
  __shared__ float zlo[64];
  __shared__ int hist[EE];

  int t = threadIdx.x;
  int w = t >> 6, r = t & 63;
  int e0 = w * 6;
  int tok0 = blockIdx.x * 64;
  const float* Wg = Wg_all + (size_t)task_p[0] * CC * EE;

  if (t < EE) hist[t] = 0;

  float acc[6];
  #pragma unroll
  for (int c = 0; c < 6; c++) acc[c] = 0.f;

  for (int kb = 0; kb < CC; kb += 64) {
    __syncthreads();
    #pragma unroll
    for (int i = 0; i < 4; i++) {
      int idx = i * 256 + t;
      int rr = idx >> 4, cc = (idx & 15) << 2;
      float4 v = *(const float4*)&x[(size_t)(tok0 + rr) * CC + kb + cc];
      *(float4*)&xs[rr][cc] = v;
      u64 pk = (u64)f2b(v.x) | ((u64)f2b(v.y) << 16) |
               ((u64)f2b(v.z) << 32) | ((u64)f2b(v.w) << 48);
      *(u64*)&xb[(size_t)(tok0 + rr) * CC + kb + cc] = pk;
    }
    #pragma unroll
    for (int i = 0; i < 3; i++) {
      int idx = i * 256 + t;
      int kk = idx / 12, c2 = idx % 12;
      *(float2*)&wgs[kk][c2 * 2] = *(const float2*)&Wg[(size_t)(kb + kk) * EE + c2 * 2];
    }
    __syncthreads();
    #pragma unroll 16
    for (int k = 0; k < 64; k++) {
      float xv = xs[r][k];
      float2 w01 = *(const float2*)&wgs[k][e0];
      float2 w23 = *(const float2*)&wgs[k][e0 + 2];
      float2 w45 = *(const float2*)&wgs[k][e0 + 4];
      acc[0] += xv * w01.x; acc[1] += xv * w01.y;
      acc[2] += xv * w23.x; acc[3] += xv * w23.y;
      acc[4] += xv * w45.x; acc[5] += xv * w45.y;
    }
  }
  __syncthreads();
  #pragma unroll
  for (int c = 0; c < 6; c++) lgt[r][e0 + c] = acc[c];
  __syncthreads();

  if (t < 64) {
    int token = tok0 + t;
    float l[EE];
    #pragma unroll
    for (int e = 0; e < EE; e++) l[e] = lgt[t][e];
    float mx = l[0];
    #pragma unroll
    for (int e = 1; e < EE; e++) mx = fmaxf(mx, l[e]);
    float se = 0.f; float probs[EE];
    #pragma unroll
    for (int e = 0; e < EE; e++) { probs[e] = __expf(l[e] - mx); se += probs[e]; }
    float inv = 1.f / se;
    #pragma unroll
    for (int e = 0; e < EE; e++) probs[e] *= inv;
    float lse = mx + __logf(se);
    zlo[t] = lse * lse;

    unsigned taken = 0u;
    float gsum = 0.f;
    float my_g[8]; int my_e[8];
    #pragma unroll
    for (int h = 0; h < HH; h++) {
      float best = -1.f; int bi = 0;
      #pragma unroll
      for (int e = 0; e < EE; e++) {
        bool ok = !((taken >> e) & 1u) && (probs[e] > best);
        best = ok ? probs[e] : best;
        bi   = ok ? e : bi;
      }
      taken |= 1u << bi;
      gsum += best;
      my_g[h] = best; my_e[h] = bi;
    }
    float ginv = 1.f / (gsum + 1e-6f);
    float4 g0, g1;
    g0.x = my_g[0] * ginv; g0.y = my_g[1] * ginv; g0.z = my_g[2] * ginv; g0.w = my_g[3] * ginv;
    g1.x = my_g[4] * ginv; g1.y = my_g[5] * ginv; g1.z = my_g[6] * ginv; g1.w = my_g[7] * ginv;
    float* gbuf = ws_f + WS_G / 4;
    *(float4*)&gbuf[(size_t)token * HH]     = g0;
    *(float4*)&gbuf[(size_t)token * HH + 4] = g1;
    u64 pk = 0;
    #pragma unroll
    for (int h = 0; h < HH; h++) pk |= (u64)(u8)my_e[h] << (8 * h);
    *(u64*)&eids[(size_t)token * HH] = pk;
    #pragma unroll
    for (int h = 0; h < HH; h++) atomicAdd(&hist[my_e[h]], 1);
    #pragma unroll
    for (int e = 0; e < EE; e++) lgt[t][e] = probs[e];
  }
  __syncthreads();
  if (t < EE) {
    float s = 0.f;
    #pragma unroll 8
    for (int rr = 0; rr < 64; rr++) s += lgt[rr][t];
    atomicAdd(ws_f + WS_IMP / 4 + t, s);
    atomicAdd(&ws_i[t], hist[t]);
  } else if (t == 32) {
    float s = 0.f;
    #pragma unroll 8
    for (int rr = 0; rr < 64; rr++) s += zlo[rr];
    atomicAdd(ws_f + WS_ZSUM / 4, s);
  }
}

// -------- batched transpose + f32->bf16 --------
__global__ __launch_bounds__(256) void transpose_kernel(
    const float* __restrict__ src, u16* __restrict__ dst,
    int R, int C, int sB, int dR, int dB)
{
  __shared__ float tile[32][33];
  int e = blockIdx.z;
  const float* s = src + (size_t)e * sB;
  int t = threadIdx.x;
  int tr = t >> 5, tc = t & 31;
  #pragma unroll
  for (int i = 0; i < 4; i++) {
    int r = blockIdx.x * 32 + tr + i * 8;
    int c = blockIdx.y * 32 + tc;
    tile[tr + i * 8][tc] = s[(size_t)r * C + c];
  }
  __syncthreads();
  #pragma unroll
  for (int i = 0; i < 4; i++) {
    int sc = blockIdx.y * 32 + tr + i * 8;
    int sr = blockIdx.x * 32 + tc;
    dst[(size_t)e * dB + (size_t)sc * dR + sr] = f2b(tile[tc][tr + i * 8]);
  }
}

// -------- dense MFMA GEMM, bf16 A/B, global_load_lds staging --------
template<int BM, int BN, bool OUT_F32>
__global__ __launch_bounds__(256) void gemm_kernel(
    const u16* __restrict__ A, const u16* __restrict__ Bt,
    void* __restrict__ Cp, int M, int N, int K)
{
  constexpr int WM = BM / 2, WN = BN / 2;
  constexpr int FM = WM / 16, FN = WN / 16;
  __shared__ u16 As[BM][64];
  __shared__ u16 Bs[BN][64];
  int t = threadIdx.x;
  int w = t >> 6, l = t & 63;
  int lr = l & 15, lg = l >> 4;
  int wr = w >> 1, wc = w & 1;
  int col0 = blockIdx.x * BN, row0 = blockIdx.y * BM;

  f32x4 acc[FM][FN];
  #pragma unroll
  for (int i = 0; i < FM; i++)
    #pragma unroll
    for (int j = 0; j < FN; j++) acc[i][j] = (f32x4)(0.f);

  int sr = t >> 3;
  int sc = t & 7;
  for (int kb = 0; kb < K; kb += 64) {
    __syncthreads();
    #pragma unroll
    for (int i = 0; i < BM / 32; i++) {
      int rr = i * 32 + sr;
      int ch = sc ^ (rr & 7);
      gload16(A + (size_t)(row0 + rr) * K + kb + ch * 8, &As[rr][sc * 8]);
    }
    #pragma unroll
    for (int i = 0; i < BN / 32; i++) {
      int rr = i * 32 + sr;
      int ch = sc ^ (rr & 7);
      gload16(Bt + (size_t)(col0 + rr) * K + kb + ch * 8, &Bs[rr][sc * 8]);
    }
    __syncthreads();
    #pragma unroll
    for (int ks = 0; ks < 2; ks++) {
      s16x8 af[FM], bf[FN];
      #pragma unroll
      for (int i = 0; i < FM; i++)
        af[i] = *(const s16x8*)&As[wr * WM + i * 16 + lr][8 * ((ks * 4 + lg) ^ (lr & 7))];
      #pragma unroll
      for (int j = 0; j < FN; j++)
        bf[j] = *(const s16x8*)&Bs[wc * WN + j * 16 + lr][8 * ((ks * 4 + lg) ^ (lr & 7))];
      #pragma unroll
      for (int i = 0; i < FM; i++)
        #pragma unroll
        for (int j = 0; j < FN; j++)
          acc[i][j] = __builtin_amdgcn_mfma_f32_16x16x32_bf16(af[i], bf[j], acc[i][j], 0, 0, 0);
    }
  }
  #pragma unroll
  for (int i = 0; i < FM; i++)
    #pragma unroll
    for (int j = 0; j < FN; j++)
      #pragma unroll
      for (int reg = 0; reg < 4; reg++) {
        int rr = row0 + wr * WM + i * 16 + lg * 4 + reg;
        int cc = col0 + wc * WN + j * 16 + lr;
        if (OUT_F32) ((float*)Cp)[(size_t)rr * N + cc] = acc[i][j][reg];
        else ((u16*)Cp)[(size_t)rr * N + cc] = f2b(acc[i][j][reg]);
      }
}

// -------- kv projection -> kvbk (padded 128, pre-swizzled K) + vtb (V^T, pre-swizzled)
__global__ __launch_bounds__(256) void kvproj_kernel(
    const u16* __restrict__ xb, const u16* __restrict__ wkvT,
    u16* __restrict__ kvbk, u16* __restrict__ vtb)
{
  __shared__ u16 As[128][64];
  __shared__ u16 Bs[64][64];
  int t = threadIdx.x;
  int w = t >> 6, l = t & 63;
  int lr = l & 15, lg = l >> 4;
  int wr = w >> 1, wc = w & 1;
  int col0 = blockIdx.x * 64, row0 = blockIdx.y * 128;

  f32x4 acc[4][2];
  #pragma unroll
  for (int i = 0; i < 4; i++)
    #pragma unroll
    for (int j = 0; j < 2; j++) acc[i][j] = (f32x4)(0.f);

  int sr = t >> 3, sc = t & 7;
  for (int kb = 0; kb < CC; kb += 64) {
    __syncthreads();
    #pragma unroll
    for (int i = 0; i < 4; i++) {
      int rr = i * 32 + sr;
      int ch = sc ^ (rr & 7);
      gload16(xb + (size_t)(row0 + rr) * CC + kb + ch * 8, &As[rr][sc * 8]);
    }
    #pragma unroll
    for (int i = 0; i < 2; i++) {
      int rr = i * 32 + sr;
      int ch = sc ^ (rr & 7);
      gload16(wkvT + (size_t)(col0 + rr) * CC + kb + ch * 8, &Bs[rr][sc * 8]);
    }
    __syncthreads();
    #pragma unroll
    for (int ks = 0; ks < 2; ks++) {
      s16x8 af[4], bf[2];
      #pragma unroll
      for (int i = 0; i < 4; i++)
        af[i] = *(const s16x8*)&As[wr * 64 + i * 16 + lr][8 * ((ks * 4 + lg) ^ (lr & 7))];
      #pragma unroll
      for (int j = 0; j < 2; j++)
        bf[j] = *(const s16x8*)&Bs[wc * 32 + j * 16 + lr][8 * ((ks * 4 + lg) ^ (lr & 7))];
      #pragma unroll
      for (int i = 0; i < 4; i++)
        #pragma unroll
        for (int j = 0; j < 2; j++)
          acc[i][j] = __builtin_amdgcn_mfma_f32_16x16x32_bf16(af[i], bf[j], acc[i][j], 0, 0, 0);
    }
  }
  #pragma unroll
  for (int i = 0; i < 4; i++)
    #pragma unroll
    for (int j = 0; j < 2; j++) {
      int cb = col0 + wc * 32 + j * 16 + lr;
      int rb = row0 + wr * 64 + i * 16 + lg * 4;
      if (cb < 96) {
        int ch = cb >> 3, ci = cb & 7;
        #pragma unroll
        for (int reg = 0; reg < 4; reg++) {
          int tok = rb + reg;
          kvbk[(size_t)tok * 128 + 8 * (ch ^ (tok & 7)) + ci] = f2b(acc[i][j][reg]);
        }
      } else {
        int d = cb - 96;
        u64 pk = (u64)f2b(acc[i][j][0]) | ((u64)f2b(acc[i][j][1]) << 16) |
                 ((u64)f2b(acc[i][j][2]) << 32) | ((u64)f2b(acc[i][j][3]) << 48);
        int blkbase = rb & ~63;
        int ch = (rb & 63) >> 3;
        *(u64*)&vtb[(size_t)d * NT + blkbase + 8 * (ch ^ (d & 7)) + (rb & 7)] = pk;
      }
    }
}

// ---- flash attention: 32x32x16 MFMA, 4 waves = 4 heads (z splits 8 heads) ----
// Swapped S^T = mfma(K, Q); P in-register via shfl_xor(32) pair exchange.
__global__ __launch_bounds__(256, 2) void attn_kernel(
    const u16* __restrict__ qall, const u16* __restrict__ kvbk,
    const u16* __restrict__ vtb, const u8* __restrict__ eids,
    const float* __restrict__ gbuf, u16* __restrict__ z)
{
  __shared__ u16 Ks[2][64][128];   // 32 KB, pre-swizzled layout copied linearly
  __shared__ u16 Vt[2][96][64];    // 24 KB, V^T pre-swizzled
  int b = blockIdx.y;
  int tok0 = blockIdx.x * 32;
  int t = threadIdx.x;
  int w = t >> 6, l = t & 63;
  int h = blockIdx.z * 4 + w;      // wave = head (within z-half)
  int lo = l & 31, hi = l >> 5;

  // Q B-fragment: col q = lo, k(d) = ks*16 + hi*8 + j
  s16x8 qf[6];
  {
    int tok = b * NN + tok0 + lo;
    int e = eids[tok * HH + h];
    const u16* qp = qall + (size_t)tok * EC + e * HD + hi * 8;
    #pragma unroll
    for (int ks = 0; ks < 6; ks++)
      qf[ks] = *(const s16x8*)(qp + ks * 16);
  }

  const u16* kvwin = kvbk + (size_t)(b * NN) * 128;
  const u16* vwin  = vtb + (size_t)(b * NN);

  f32x16 o0 = (f32x16)(0.f), o1 = (f32x16)(0.f), o2 = (f32x16)(0.f);
  float m = -1e30f, lsum = 0.f;

  // prologue: stage tile 0 into buffer 0 (linear copy; swizzle pre-baked)
  #pragma unroll
  for (int k2 = 0; k2 < 4; k2++) {
    int c = t + k2 * 256;
    gload16(kvwin + c * 8, &Ks[0][0][0] + c * 8);
  }
  #pragma unroll
  for (int k2 = 0; k2 < 3; k2++) {
    int c = t + k2 * 256;
    gload16(vwin + (size_t)(c >> 3) * NT + (c & 7) * 8, &Vt[0][0][0] + c * 8);
  }

  for (int jt = 0; jt < 16; jt++) {
    __syncthreads();     // drains vmcnt -> current buffer staged; prev readers done
    if (jt < 15) {
      int j0 = (jt + 1) * 64;
      int nb = (jt + 1) & 1;
      const u16* kb_ = kvwin + (size_t)j0 * 128;
      #pragma unroll
      for (int k2 = 0; k2 < 4; k2++) {
        int c = t + k2 * 256;
        gload16(kb_ + c * 8, &Ks[nb][0][0] + c * 8);
      }
      const u16* vb_ = vwin + j0;
      #pragma unroll
      for (int k2 = 0; k2 < 3; k2++) {
        int c = t + k2 * 256;
        gload16(vb_ + (size_t)(c >> 3) * NT + (c & 7) * 8, &Vt[nb][0][0] + c * 8);
      }
    }
    int buf = jt & 1;

    // ---- S^T = K Q^T : s0/s1 lane holds k=(rg&3)+8*(rg>>2)+4*hi (+32), q=lo
    f32x16 s0 = (f32x16)(0.f), s1 = (f32x16)(0.f);
    #pragma unroll
    for (int ks = 0; ks < 6; ks++) {
      int pos = 8 * ((2 * ks + hi) ^ (lo & 7));
      s16x8 a0 = *(const s16x8*)&Ks[buf][lo][pos];
      s16x8 a1 = *(const s16x8*)&Ks[buf][32 + lo][pos];
      s0 = __builtin_amdgcn_mfma_f32_32x32x16_bf16(a0, qf[ks], s0, 0, 0, 0);
      s1 = __builtin_amdgcn_mfma_f32_32x32x16_bf16(a1, qf[ks], s1, 0, 0, 0);
    }

    // ---- row max (31 local + 1 xor-32)
    float pm = s0[0];
    #pragma unroll
    for (int rg = 1; rg < 16; rg++) pm = fmaxf(pm, s0[rg]);
    #pragma unroll
    for (int rg = 0; rg < 16; rg++) pm = fmaxf(pm, s1[rg]);
    pm = fmaxf(pm, __shfl_xor(pm, 32));
    pm *= ASCALE;

    // ---- defer-max rescale
    if (!__all(pm - m <= 8.f)) {
      float mn = fmaxf(m, pm);
      float al = __expf(m - mn);
      m = mn; lsum *= al;
      #pragma unroll
      for (int rg = 0; rg < 16; rg++) {
        int qrow = (rg & 3) + 8 * (rg >> 2) + 4 * hi;
        float alr = __shfl(al, qrow);
        o0[rg] *= alr; o1[rg] *= alr; o2[rg] *= alr;
      }
    }

    // ---- P = exp(S - m) packed to bf16 pairs; local row-sum
    // wpk[kb][rr][pp] holds P-pairs p = pp + 4*rr + 2*hi + 16*kb (p = k/2)
    float ts = 0.f;
    u32 wpk[2][4][2];
    #pragma unroll
    for (int kb2 = 0; kb2 < 2; kb2++)
      #pragma unroll
      for (int rr = 0; rr < 4; rr++)
        #pragma unroll
        for (int pp = 0; pp < 2; pp++) {
          float eA = __expf((kb2 ? s1[rr * 4 + 2 * pp]     : s0[rr * 4 + 2 * pp])     * ASCALE - m);
          float eB = __expf((kb2 ? s1[rr * 4 + 2 * pp + 1] : s0[rr * 4 + 2 * pp + 1]) * ASCALE - m);
          ts += eA + eB;
          wpk[kb2][rr][pp] = (u32)f2b(eA) | ((u32)f2b(eB) << 16);
        }
    lsum += ts;   // halves combined in epilogue

    // ---- PV A-fragments via symmetric lane<->lane+32 pair exchange
    // A-frag ks needs pairs {8ks+4hi .. 8ks+4hi+3}; own half + partner half.
    s16x8 pa[4];
    #pragma unroll
    for (int ks = 0; ks < 4; ks++) {
      int kb2 = ks >> 1;
      int rlo = (ks & 1) * 2, rhi = rlo + 1;
      u32 own_lo0 = wpk[kb2][rlo][0], own_lo1 = wpk[kb2][rlo][1];
      u32 own_hi0 = wpk[kb2][rhi][0], own_hi1 = wpk[kb2][rhi][1];
      u32 send0 = hi ? own_lo0 : own_hi0;
      u32 send1 = hi ? own_lo1 : own_hi1;
      u32 recv0 = (u32)__shfl_xor((int)send0, 32);
      u32 recv1 = (u32)__shfl_xor((int)send1, 32);
      union { s16x8 v; u32 u[4]; } pu;
      pu.u[0] = hi ? recv0 : own_lo0;
      pu.u[1] = hi ? recv1 : own_lo1;
      pu.u[2] = hi ? own_hi0 : recv0;
      pu.u[3] = hi ? own_hi1 : recv1;
      pa[ks] = pu.v;
    }

    // ---- O += P V : B-frag from Vt, col d = db*32+lo, k = ks*16 + hi*8 + j
    #pragma unroll
    for (int ks = 0; ks < 4; ks++) {
      int pos = 8 * ((2 * ks + hi) ^ (lo & 7));
      s16x8 v0 = *(const s16x8*)&Vt[buf][lo][pos];
      s16x8 v1 = *(const s16x8*)&Vt[buf][32 + lo][pos];
      s16x8 v2 = *(const s16x8*)&Vt[buf][64 + lo][pos];
      o0 = __builtin_amdgcn_mfma_f32_32x32x16_bf16(pa[ks], v0, o0, 0, 0, 0);
      o1 = __builtin_amdgcn_mfma_f32_32x32x16_bf16(pa[ks], v1, o1, 0, 0, 0);
      o2 = __builtin_amdgcn_mfma_f32_32x32x16_bf16(pa[ks], v2, o2, 0, 0, 0);
    }
  }

  // ---- epilogue: z[tok][e*96 + d] = g * o / l
  float lt = lsum + __shfl_xor(lsum, 32);
  #pragma unroll
  for (int rg = 0; rg < 16; rg++) {
    int qrow = (rg & 3) + 8 * (rg >> 2) + 4 * hi;
    float lv = __shfl(lt, qrow);
    int tok = b * NN + tok0 + qrow;
    int slot = tok * HH + h;
    float scl = gbuf[slot] / lv;
    int e = eids[slot];
    u16* zp = z + (size_t)tok * EC + e * HD + lo;
    zp[0]  = f2b(o0[rg] * scl);
    zp[32] = f2b(o1[rg] * scl);
    zp[64] = f2b(o2[rg] * scl);
  }
}

// ---------------- aux loss ----------------
__global__ void aux_kernel(const float* __restrict__ ws_f,
                           const int* __restrict__ ws_i, float* __restrict__ out)
{
  if (threadIdx.x == 0 && blockIdx.x == 0) {
    float sw = 0.f;
    for (int e = 0; e < EE; e++) {
      float imp = ws_f[WS_IMP / 4 + e] / (float)NT;
      float load = (float)ws_i[e] / (float)(NT * HH);
      sw += imp * load;
    }
    float zl = ws_f[WS_ZSUM / 4] / (float)NT;
    out[(size_t)NT * CC] = 0.1f * ((float)EE * sw) + 0.001f * zl;
  }
}

extern "C" void kernel_launch(void* const* d_in, const int* in_sizes, int n_in,
                              void* d_out, int out_size, void* d_ws, size_t ws_size,
                              hipStream_t stream)
{
  const float* x    = (const float*)d_in[0];
  const float* Wg   = (const float*)d_in[1];
  const float* Win  = (const float*)d_in[2];
  const float* Wout = (const float*)d_in[3];
  const float* Wkv  = (const float*)d_in[4];
  const int*   task = (const int*)d_in[5];
  float* out = (float*)d_out;
  float* ws_f = (float*)d_ws;
  int*   ws_i = (int*)d_ws;
  u8*  eids = (u8*)((char*)d_ws + WS_EID);
  u16* kvbk = (u16*)((char*)d_ws + WS_KVK);
  u16* vtb  = (u16*)((char*)d_ws + WS_VT);
  u16* winT = (u16*)((char*)d_ws + WS_WIN);
  u16* woutT= (u16*)((char*)d_ws + WS_WOUT);
  u16* wkvT = (u16*)((char*)d_ws + WS_WKV);
  u16* qall = (u16*)((char*)d_ws + WS_QA);
  u16* z    = (u16*)((char*)d_ws + WS_Z);
  u16* xb   = (u16*)((char*)d_ws + WS_XB);

  hipMemsetAsync(d_ws, 0, 256, stream);

  transpose_kernel<<<dim3(CC/32, HD/32, EE), 256, 0, stream>>>(Win, winT, CC, HD, CC*HD, CC, HD*CC);
  transpose_kernel<<<dim3(HD/32, CC/32, EE), 256, 0, stream>>>(Wout, woutT, HD, CC, HD*CC, EC, HD);
  transpose_kernel<<<dim3(CC/32, 192/32, 1), 256, 0, stream>>>(Wkv, wkvT, CC, 192, 0, CC, 0);

  gate_kernel<<<NT / 64, 256, 0, stream>>>(x, Wg, task, ws_f, ws_i, eids, xb);

  kvproj_kernel<<<dim3(3, NT/128), 256, 0, stream>>>(xb, wkvT, kvbk, vtb);
  gemm_kernel<128, 128, false><<<dim3(EC/128, NT/128), 256, 0, stream>>>(
      xb, winT, qall, NT, EC, CC);

  hipMemsetAsync(z, 0, (size_t)NT * EC * 2, stream);   // xb dead; z aliases it

  attn_kernel<<<dim3(NN/32, BB, 2), 256, 0, stream>>>(qall, kvbk, vtb, eids, ws_f + WS_G/4, z);

  gemm_kernel<128, 128, true><<<dim3(CC/128, NT/128), 256, 0, stream>>>(
      z, woutT, out, NT, CC, EC);

  aux_kernel<<<1, 64, 0, stream>>>(ws_f, ws_i, out);
}

// Round 9
// 200.118 us; speedup vs baseline: 6.7018x; 1.1147x over previous
//
#include <hip/hip_runtime.h>
#include <hip/hip_bf16.h>
#include <math.h>

#define BB 8
#define NN 1024
#define CC 768
#define HH 8
#define HD 96
#define EE 24
#define NT (BB*NN)          // 8192 tokens
#define NSLOT (NT*HH)       // 65536 (token,h) slots
#define EC (EE*HD)          // 2304
#define CAPQ 8192           // per-expert bucket capacity
#define ASCALE 0.10206207261596575f  // 96^-0.5

typedef unsigned short u16;
typedef unsigned char u8;
typedef unsigned int u32;
typedef unsigned long long u64;
typedef __attribute__((ext_vector_type(8))) short s16x8;
typedef __attribute__((ext_vector_type(4))) float f32x4;
typedef __attribute__((ext_vector_type(16))) float f32x16;

__device__ __forceinline__ u16 f2b(float f) {  // RNE float->bf16 bits
  unsigned u = __builtin_bit_cast(unsigned, f);
  unsigned r = u + 0x7fffu + ((u >> 16) & 1u);
  return (u16)(r >> 16);
}

__device__ __forceinline__ void gload16(const u16* g, u16* lds) {
  __builtin_amdgcn_global_load_lds(
      (const __attribute__((address_space(1))) void*)g,
      (__attribute__((address_space(3))) void*)lds, 16, 0, 0);
}

// bijective XCD remap (8 XCDs): contiguous logical chunks per XCD
__device__ __forceinline__ int xcd_remap(int bid, int nwg) {
  int q = nwg >> 3, r = nwg & 7;
  int xcd = bid & 7, idx = bid >> 3;
  return (xcd < r ? xcd * (q + 1) : r * (q + 1) + (xcd - r) * q) + idx;
}

// ws layout (bytes)
#define WS_CNT   0
#define WS_IMP   96
#define WS_ZSUM  192
#define WS_G     256
#define WS_EID   (WS_G + NSLOT*4)
#define WS_KVK   (WS_EID + NSLOT)             // NT*128 u16 (K, padded+pre-swizzled)
#define WS_VT    (WS_KVK + NT*128*2)          // 96*NT u16 (V^T, in-block pre-swizzled)
#define WS_WIN   (WS_VT + (size_t)96*NT*2)
#define WS_WOUT  (WS_WIN + (size_t)EC*CC*2)
#define WS_WKV   (WS_WOUT + (size_t)CC*EC*2)
#define WS_QA    (WS_WKV + 192*CC*2)
#define WS_Z     (WS_QA + (size_t)NT*EC*2)
#define WS_XB    WS_Z                          // aliases z; xb dead before z memset
#define WS_BUCKET (WS_Z + (size_t)16*1024*1024) // aliases z tail; dead before z memset

// ---- gating: tiled fp32 GEMM + softmax + top-8 + buckets; emits xb=bf16(x)
__global__ __launch_bounds__(256) void gate_kernel(
    const float* __restrict__ x, const float* __restrict__ Wg_all,
    const int* __restrict__ task_p, float* __restrict__ ws_f,
    int* __restrict__ ws_i, u8* __restrict__ eids, u16* __restrict__ xb,
    int* __restrict__ bucket)
{
  __shared__ float xs[64][65];
  __shared__ float wgs[64][24];
  __shared__ float lgt[64][26];
  __shared__ float zlo[64];
  __shared__ int hist[EE];
  __shared__ int gbase[EE];

  int t = threadIdx.x;
  int w = t >> 6, r = t & 63;
  int e0 = w * 6;
  int tok0 = blockIdx.x * 64;
  const float* Wg = Wg_all + (size_t)task_p[0] * CC * EE;

  if (t < EE) hist[t] = 0;

  float acc[6];
  #pragma unroll
  for (int c = 0; c < 6; c++) acc[c] = 0.f;

  for (int kb = 0; kb < CC; kb += 64) {
    __syncthreads();
    #pragma unroll
    for (int i = 0; i < 4; i++) {
      int idx = i * 256 + t;
      int rr = idx >> 4, cc = (idx & 15) << 2;
      float4 v = *(const float4*)&x[(size_t)(tok0 + rr) * CC + kb + cc];
      *(float4*)&xs[rr][cc] = v;
      u64 pk = (u64)f2b(v.x) | ((u64)f2b(v.y) << 16) |
               ((u64)f2b(v.z) << 32) | ((u64)f2b(v.w) << 48);
      *(u64*)&xb[(size_t)(tok0 + rr) * CC + kb + cc] = pk;
    }
    #pragma unroll
    for (int i = 0; i < 3; i++) {
      int idx = i * 256 + t;
      int kk = idx / 12, c2 = idx % 12;
      *(float2*)&wgs[kk][c2 * 2] = *(const float2*)&Wg[(size_t)(kb + kk) * EE + c2 * 2];
    }
    __syncthreads();
    #pragma unroll 16
    for (int k = 0; k < 64; k++) {
      float xv = xs[r][k];
      float2 w01 = *(const float2*)&wgs[k][e0];
      float2 w23 = *(const float2*)&wgs[k][e0 + 2];
      float2 w45 = *(const float2*)&wgs[k][e0 + 4];
      acc[0] += xv * w01.x; acc[1] += xv * w01.y;
      acc[2] += xv * w23.x; acc[3] += xv * w23.y;
      acc[4] += xv * w45.x; acc[5] += xv * w45.y;
    }
  }
  __syncthreads();
  #pragma unroll
  for (int c = 0; c < 6; c++) lgt[r][e0 + c] = acc[c];
  __syncthreads();

  int my_e[8], loc[8];
  if (t < 64) {
    int token = tok0 + t;
    float l[EE];
    #pragma unroll
    for (int e = 0; e < EE; e++) l[e] = lgt[t][e];
    float mx = l[0];
    #pragma unroll
    for (int e = 1; e < EE; e++) mx = fmaxf(mx, l[e]);
    float se = 0.f; float probs[EE];
    #pragma unroll
    for (int e = 0; e < EE; e++) { probs[e] = __expf(l[e] - mx); se += probs[e]; }
    float inv = 1.f / se;
    #pragma unroll
    for (int e = 0; e < EE; e++) probs[e] *= inv;
    float lse = mx + __logf(se);
    zlo[t] = lse * lse;

    unsigned taken = 0u;
    float gsum = 0.f;
    float my_g[8];
    #pragma unroll
    for (int h = 0; h < HH; h++) {
      float best = -1.f; int bi = 0;
      #pragma unroll
      for (int e = 0; e < EE; e++) {
        bool ok = !((taken >> e) & 1u) && (probs[e] > best);
        best = ok ? probs[e] : best;
        bi   = ok ? e : bi;
      }
      taken |= 1u << bi;
      gsum += best;
      my_g[h] = best; my_e[h] = bi;
    }
    float ginv = 1.f / (gsum + 1e-6f);
    float4 g0, g1;
    g0.x = my_g[0] * ginv; g0.y = my_g[1] * ginv; g0.z = my_g[2] * ginv; g0.w = my_g[3] * ginv;
    g1.x = my_g[4] * ginv; g1.y = my_g[5] * ginv; g1.z = my_g[6] * ginv; g1.w = my_g[7] * ginv;
    float* gbuf = ws_f + WS_G / 4;
    *(float4*)&gbuf[(size_t)token * HH]     = g0;
    *(float4*)&gbuf[(size_t)token * HH + 4] = g1;
    u64 pk = 0;
    #pragma unroll
    for (int h = 0; h < HH; h++) pk |= (u64)(u8)my_e[h] << (8 * h);
    *(u64*)&eids[(size_t)token * HH] = pk;
    #pragma unroll
    for (int h = 0; h < HH; h++) loc[h] = atomicAdd(&hist[my_e[h]], 1);
    #pragma unroll
    for (int e = 0; e < EE; e++) lgt[t][e] = probs[e];
  }
  __syncthreads();
  if (t < EE) {
    float s = 0.f;
    #pragma unroll 8
    for (int rr = 0; rr < 64; rr++) s += lgt[rr][t];
    atomicAdd(ws_f + WS_IMP / 4 + t, s);
    gbase[t] = atomicAdd(&ws_i[t], hist[t]);
  } else if (t == 32) {
    float s = 0.f;
    #pragma unroll 8
    for (int rr = 0; rr < 64; rr++) s += zlo[rr];
    atomicAdd(ws_f + WS_ZSUM / 4, s);
  }
  __syncthreads();
  if (t < 64) {
    int token = tok0 + t;
    #pragma unroll
    for (int h = 0; h < HH; h++)
      bucket[my_e[h] * CAPQ + gbase[my_e[h]] + loc[h]] = token;
  }
}

// -------- batched transpose + f32->bf16 --------
__global__ __launch_bounds__(256) void transpose_kernel(
    const float* __restrict__ src, u16* __restrict__ dst,
    int R, int C, int sB, int dR, int dB)
{
  __shared__ float tile[32][33];
  int e = blockIdx.z;
  const float* s = src + (size_t)e * sB;
  int t = threadIdx.x;
  int tr = t >> 5, tc = t & 31;
  #pragma unroll
  for (int i = 0; i < 4; i++) {
    int r = blockIdx.x * 32 + tr + i * 8;
    int c = blockIdx.y * 32 + tc;
    tile[tr + i * 8][tc] = s[(size_t)r * C + c];
  }
  __syncthreads();
  #pragma unroll
  for (int i = 0; i < 4; i++) {
    int sc = blockIdx.y * 32 + tr + i * 8;
    int sr = blockIdx.x * 32 + tc;
    dst[(size_t)e * dB + (size_t)sc * dR + sr] = f2b(tile[tc][tr + i * 8]);
  }
}

// -------- dense MFMA GEMM (oproj), bf16 A/B, gload_lds, XCD-swizzled --------
template<int BM, int BN, bool OUT_F32>
__global__ __launch_bounds__(256) void gemm_kernel(
    const u16* __restrict__ A, const u16* __restrict__ Bt,
    void* __restrict__ Cp, int M, int N, int K)
{
  constexpr int WM = BM / 2, WN = BN / 2;
  constexpr int FM = WM / 16, FN = WN / 16;
  __shared__ u16 As[BM][64];
  __shared__ u16 Bs[BN][64];
  int t = threadIdx.x;
  int w = t >> 6, l = t & 63;
  int lr = l & 15, lg = l >> 4;
  int wr = w >> 1, wc = w & 1;
  int nwg = gridDim.x * gridDim.y;
  int logical = xcd_remap(blockIdx.y * gridDim.x + blockIdx.x, nwg);
  int col0 = (logical % gridDim.x) * BN, row0 = (logical / gridDim.x) * BM;

  f32x4 acc[FM][FN];
  #pragma unroll
  for (int i = 0; i < FM; i++)
    #pragma unroll
    for (int j = 0; j < FN; j++) acc[i][j] = (f32x4)(0.f);

  int sr = t >> 3;
  int sc = t & 7;
  for (int kb = 0; kb < K; kb += 64) {
    __syncthreads();
    #pragma unroll
    for (int i = 0; i < BM / 32; i++) {
      int rr = i * 32 + sr;
      int ch = sc ^ (rr & 7);
      gload16(A + (size_t)(row0 + rr) * K + kb + ch * 8, &As[rr][sc * 8]);
    }
    #pragma unroll
    for (int i = 0; i < BN / 32; i++) {
      int rr = i * 32 + sr;
      int ch = sc ^ (rr & 7);
      gload16(Bt + (size_t)(col0 + rr) * K + kb + ch * 8, &Bs[rr][sc * 8]);
    }
    __syncthreads();
    #pragma unroll
    for (int ks = 0; ks < 2; ks++) {
      s16x8 af[FM], bf[FN];
      #pragma unroll
      for (int i = 0; i < FM; i++)
        af[i] = *(const s16x8*)&As[wr * WM + i * 16 + lr][8 * ((ks * 4 + lg) ^ (lr & 7))];
      #pragma unroll
      for (int j = 0; j < FN; j++)
        bf[j] = *(const s16x8*)&Bs[wc * WN + j * 16 + lr][8 * ((ks * 4 + lg) ^ (lr & 7))];
      #pragma unroll
      for (int i = 0; i < FM; i++)
        #pragma unroll
        for (int j = 0; j < FN; j++)
          acc[i][j] = __builtin_amdgcn_mfma_f32_16x16x32_bf16(af[i], bf[j], acc[i][j], 0, 0, 0);
    }
  }
  #pragma unroll
  for (int i = 0; i < FM; i++)
    #pragma unroll
    for (int j = 0; j < FN; j++)
      #pragma unroll
      for (int reg = 0; reg < 4; reg++) {
        int rr = row0 + wr * WM + i * 16 + lg * 4 + reg;
        int cc = col0 + wc * WN + j * 16 + lr;
        if (OUT_F32) ((float*)Cp)[(size_t)rr * N + cc] = acc[i][j][reg];
        else ((u16*)Cp)[(size_t)rr * N + cc] = f2b(acc[i][j][reg]);
      }
}

// -------- gathered q projection: per-expert tiles, 128 rows x 96 cols, K=768
__global__ __launch_bounds__(256) void qproj_kernel(
    const u16* __restrict__ xb, const u16* __restrict__ winT,
    const int* __restrict__ ws_i, const int* __restrict__ bucket,
    u16* __restrict__ qall)
{
  int e = blockIdx.y;
  int t0 = blockIdx.x * 128;
  int cnt = ws_i[e];
  if (t0 >= cnt) return;
  __shared__ u16 As[128][64];
  __shared__ u16 Bs[96][64];
  __shared__ int tok_s[128];
  int t = threadIdx.x;
  if (t < 128) tok_s[t] = bucket[e * CAPQ + min(t0 + t, cnt - 1)];
  __syncthreads();
  int w = t >> 6, l = t & 63;
  int lr = l & 15, lg = l >> 4;
  int wr = w >> 1, wc = w & 1;
  const u16* Bt = winT + (size_t)e * HD * CC;

  f32x4 acc[4][3];
  #pragma unroll
  for (int i = 0; i < 4; i++)
    #pragma unroll
    for (int j = 0; j < 3; j++) acc[i][j] = (f32x4)(0.f);

  int sr = t >> 3, sc = t & 7;
  int atok[4];
  #pragma unroll
  for (int i = 0; i < 4; i++) atok[i] = tok_s[i * 32 + sr];

  for (int kb = 0; kb < CC; kb += 64) {
    __syncthreads();
    #pragma unroll
    for (int i = 0; i < 4; i++) {
      int rr = i * 32 + sr;
      int ch = sc ^ (rr & 7);
      gload16(xb + (size_t)atok[i] * CC + kb + ch * 8, &As[rr][sc * 8]);
    }
    #pragma unroll
    for (int i = 0; i < 3; i++) {
      int rr = i * 32 + sr;
      int ch = sc ^ (rr & 7);
      gload16(Bt + (size_t)rr * CC + kb + ch * 8, &Bs[rr][sc * 8]);
    }
    __syncthreads();
    #pragma unroll
    for (int ks = 0; ks < 2; ks++) {
      s16x8 af[4], bf[3];
      #pragma unroll
      for (int i = 0; i < 4; i++)
        af[i] = *(const s16x8*)&As[wr * 64 + i * 16 + lr][8 * ((ks * 4 + lg) ^ (lr & 7))];
      #pragma unroll
      for (int j = 0; j < 3; j++)
        bf[j] = *(const s16x8*)&Bs[wc * 48 + j * 16 + lr][8 * ((ks * 4 + lg) ^ (lr & 7))];
      #pragma unroll
      for (int i = 0; i < 4; i++)
        #pragma unroll
        for (int j = 0; j < 3; j++)
          acc[i][j] = __builtin_amdgcn_mfma_f32_16x16x32_bf16(af[i], bf[j], acc[i][j], 0, 0, 0);
    }
  }
  #pragma unroll
  for (int i = 0; i < 4; i++)
    #pragma unroll
    for (int reg = 0; reg < 4; reg++) {
      int rr = wr * 64 + i * 16 + lg * 4 + reg;
      if (t0 + rr < cnt) {
        int tok = tok_s[rr];
        u16* qp = qall + (size_t)tok * EC + e * HD + wc * 48;
        #pragma unroll
        for (int j = 0; j < 3; j++)
          qp[j * 16 + lr] = f2b(acc[i][j][reg]);
      }
    }
}

// -------- kv projection -> kvbk (padded 128, pre-swizzled K) + vtb (V^T, pre-swizzled)
__global__ __launch_bounds__(256) void kvproj_kernel(
    const u16* __restrict__ xb, const u16* __restrict__ wkvT,
    u16* __restrict__ kvbk, u16* __restrict__ vtb)
{
  __shared__ u16 As[128][64];
  __shared__ u16 Bs[64][64];
  int t = threadIdx.x;
  int w = t >> 6, l = t & 63;
  int lr = l & 15, lg = l >> 4;
  int wr = w >> 1, wc = w & 1;
  int nwg = gridDim.x * gridDim.y;
  int logical = xcd_remap(blockIdx.y * gridDim.x + blockIdx.x, nwg);
  int col0 = (logical % gridDim.x) * 64, row0 = (logical / gridDim.x) * 128;

  f32x4 acc[4][2];
  #pragma unroll
  for (int i = 0; i < 4; i++)
    #pragma unroll
    for (int j = 0; j < 2; j++) acc[i][j] = (f32x4)(0.f);

  int sr = t >> 3, sc = t & 7;
  for (int kb = 0; kb < CC; kb += 64) {
    __syncthreads();
    #pragma unroll
    for (int i = 0; i < 4; i++) {
      int rr = i * 32 + sr;
      int ch = sc ^ (rr & 7);
      gload16(xb + (size_t)(row0 + rr) * CC + kb + ch * 8, &As[rr][sc * 8]);
    }
    #pragma unroll
    for (int i = 0; i < 2; i++) {
      int rr = i * 32 + sr;
      int ch = sc ^ (rr & 7);
      gload16(wkvT + (size_t)(col0 + rr) * CC + kb + ch * 8, &Bs[rr][sc * 8]);
    }
    __syncthreads();
    #pragma unroll
    for (int ks = 0; ks < 2; ks++) {
      s16x8 af[4], bf[2];
      #pragma unroll
      for (int i = 0; i < 4; i++)
        af[i] = *(const s16x8*)&As[wr * 64 + i * 16 + lr][8 * ((ks * 4 + lg) ^ (lr & 7))];
      #pragma unroll
      for (int j = 0; j < 2; j++)
        bf[j] = *(const s16x8*)&Bs[wc * 32 + j * 16 + lr][8 * ((ks * 4 + lg) ^ (lr & 7))];
      #pragma unroll
      for (int i = 0; i < 4; i++)
        #pragma unroll
        for (int j = 0; j < 2; j++)
          acc[i][j] = __builtin_amdgcn_mfma_f32_16x16x32_bf16(af[i], bf[j], acc[i][j], 0, 0, 0);
    }
  }
  #pragma unroll
  for (int i = 0; i < 4; i++)
    #pragma unroll
    for (int j = 0; j < 2; j++) {
      int cb = col0 + wc * 32 + j * 16 + lr;
      int rb = row0 + wr * 64 + i * 16 + lg * 4;
      if (cb < 96) {
        int ch = cb >> 3, ci = cb & 7;
        #pragma unroll
        for (int reg = 0; reg < 4; reg++) {
          int tok = rb + reg;
          kvbk[(size_t)tok * 128 + 8 * (ch ^ (tok & 7)) + ci] = f2b(acc[i][j][reg]);
        }
      } else {
        int d = cb - 96;
        u64 pk = (u64)f2b(acc[i][j][0]) | ((u64)f2b(acc[i][j][1]) << 16) |
                 ((u64)f2b(acc[i][j][2]) << 32) | ((u64)f2b(acc[i][j][3]) << 48);
        int blkbase = rb & ~63;
        int ch = (rb & 63) >> 3;
        *(u64*)&vtb[(size_t)d * NT + blkbase + 8 * (ch ^ (d & 7)) + (rb & 7)] = pk;
      }
    }
}

// ---- flash attention: 32x32x16 MFMA, 4 waves = 4 heads (z splits 8 heads) ----
__global__ __launch_bounds__(256, 2) void attn_kernel(
    const u16* __restrict__ qall, const u16* __restrict__ kvbk,
    const u16* __restrict__ vtb, const u8* __restrict__ eids,
    const float* __restrict__ gbuf, u16* __restrict__ z)
{
  __shared__ u16 Ks[2][64][128];
  __shared__ u16 Vt[2][96][64];
  int b = blockIdx.y;
  int tok0 = blockIdx.x * 32;
  int t = threadIdx.x;
  int w = t >> 6, l = t & 63;
  int h = blockIdx.z * 4 + w;
  int lo = l & 31, hi = l >> 5;

  s16x8 qf[6];
  {
    int tok = b * NN + tok0 + lo;
    int e = eids[tok * HH + h];
    const u16* qp = qall + (size_t)tok * EC + e * HD + hi * 8;
    #pragma unroll
    for (int ks = 0; ks < 6; ks++)
      qf[ks] = *(const s16x8*)(qp + ks * 16);
  }

  const u16* kvwin = kvbk + (size_t)(b * NN) * 128;
  const u16* vwin  = vtb + (size_t)(b * NN);

  f32x16 o0 = (f32x16)(0.f), o1 = (f32x16)(0.f), o2 = (f32x16)(0.f);
  float m = -1e30f, lsum = 0.f;

  #pragma unroll
  for (int k2 = 0; k2 < 4; k2++) {
    int c = t + k2 * 256;
    gload16(kvwin + c * 8, &Ks[0][0][0] + c * 8);
  }
  #pragma unroll
  for (int k2 = 0; k2 < 3; k2++) {
    int c = t + k2 * 256;
    gload16(vwin + (size_t)(c >> 3) * NT + (c & 7) * 8, &Vt[0][0][0] + c * 8);
  }

  for (int jt = 0; jt < 16; jt++) {
    __syncthreads();
    if (jt < 15) {
      int j0 = (jt + 1) * 64;
      int nb = (jt + 1) & 1;
      const u16* kb_ = kvwin + (size_t)j0 * 128;
      #pragma unroll
      for (int k2 = 0; k2 < 4; k2++) {
        int c = t + k2 * 256;
        gload16(kb_ + c * 8, &Ks[nb][0][0] + c * 8);
      }
      const u16* vb_ = vwin + j0;
      #pragma unroll
      for (int k2 = 0; k2 < 3; k2++) {
        int c = t + k2 * 256;
        gload16(vb_ + (size_t)(c >> 3) * NT + (c & 7) * 8, &Vt[nb][0][0] + c * 8);
      }
    }
    int buf = jt & 1;

    f32x16 s0 = (f32x16)(0.f), s1 = (f32x16)(0.f);
    #pragma unroll
    for (int ks = 0; ks < 6; ks++) {
      int pos = 8 * ((2 * ks + hi) ^ (lo & 7));
      s16x8 a0 = *(const s16x8*)&Ks[buf][lo][pos];
      s16x8 a1 = *(const s16x8*)&Ks[buf][32 + lo][pos];
      s0 = __builtin_amdgcn_mfma_f32_32x32x16_bf16(a0, qf[ks], s0, 0, 0, 0);
      s1 = __builtin_amdgcn_mfma_f32_32x32x16_bf16(a1, qf[ks], s1, 0, 0, 0);
    }

    float pm = s0[0];
    #pragma unroll
    for (int rg = 1; rg < 16; rg++) pm = fmaxf(pm, s0[rg]);
    #pragma unroll
    for (int rg = 0; rg < 16; rg++) pm = fmaxf(pm, s1[rg]);
    pm = fmaxf(pm, __shfl_xor(pm, 32));
    pm *= ASCALE;

    if (!__all(pm - m <= 8.f)) {
      float mn = fmaxf(m, pm);
      float al = __expf(m - mn);
      m = mn; lsum *= al;
      #pragma unroll
      for (int rg = 0; rg < 16; rg++) {
        int qrow = (rg & 3) + 8 * (rg >> 2) + 4 * hi;
        float alr = __shfl(al, qrow);
        o0[rg] *= alr; o1[rg] *= alr; o2[rg] *= alr;
      }
    }

    float ts = 0.f;
    u32 wpk[2][4][2];
    #pragma unroll
    for (int kb2 = 0; kb2 < 2; kb2++)
      #pragma unroll
      for (int rr = 0; rr < 4; rr++)
        #pragma unroll
        for (int pp = 0; pp < 2; pp++) {
          float eA = __expf((kb2 ? s1[rr * 4 + 2 * pp]     : s0[rr * 4 + 2 * pp])     * ASCALE - m);
          float eB = __expf((kb2 ? s1[rr * 4 + 2 * pp + 1] : s0[rr * 4 + 2 * pp + 1]) * ASCALE - m);
          ts += eA + eB;
          wpk[kb2][rr][pp] = (u32)f2b(eA) | ((u32)f2b(eB) << 16);
        }
    lsum += ts;

    s16x8 pa[4];
    #pragma unroll
    for (int ks = 0; ks < 4; ks++) {
      int kb2 = ks >> 1;
      int rlo = (ks & 1) * 2, rhi = rlo + 1;
      u32 own_lo0 = wpk[kb2][rlo][0], own_lo1 = wpk[kb2][rlo][1];
      u32 own_hi0 = wpk[kb2][rhi][0], own_hi1 = wpk[kb2][rhi][1];
      u32 send0 = hi ? own_lo0 : own_hi0;
      u32 send1 = hi ? own_lo1 : own_hi1;
      u32 recv0 = (u32)__shfl_xor((int)send0, 32);
      u32 recv1 = (u32)__shfl_xor((int)send1, 32);
      union { s16x8 v; u32 u[4]; } pu;
      pu.u[0] = hi ? recv0 : own_lo0;
      pu.u[1] = hi ? recv1 : own_lo1;
      pu.u[2] = hi ? own_hi0 : recv0;
      pu.u[3] = hi ? own_hi1 : recv1;
      pa[ks] = pu.v;
    }

    #pragma unroll
    for (int ks = 0; ks < 4; ks++) {
      int pos = 8 * ((2 * ks + hi) ^ (lo & 7));
      s16x8 v0 = *(const s16x8*)&Vt[buf][lo][pos];
      s16x8 v1 = *(const s16x8*)&Vt[buf][32 + lo][pos];
      s16x8 v2 = *(const s16x8*)&Vt[buf][64 + lo][pos];
      o0 = __builtin_amdgcn_mfma_f32_32x32x16_bf16(pa[ks], v0, o0, 0, 0, 0);
      o1 = __builtin_amdgcn_mfma_f32_32x32x16_bf16(pa[ks], v1, o1, 0, 0, 0);
      o2 = __builtin_amdgcn_mfma_f32_32x32x16_bf16(pa[ks], v2, o2, 0, 0, 0);
    }
  }

  float lt = lsum + __shfl_xor(lsum, 32);
  #pragma unroll
  for (int rg = 0; rg < 16; rg++) {
    int qrow = (rg & 3) + 8 * (rg >> 2) + 4 * hi;
    float lv = __shfl(lt, qrow);
    int tok = b * NN + tok0 + qrow;
    int slot = tok * HH + h;
    float scl = gbuf[slot] / lv;
    int e = eids[slot];
    u16* zp = z + (size_t)tok * EC + e * HD + lo;
    zp[0]  = f2b(o0[rg] * scl);
    zp[32] = f2b(o1[rg] * scl);
    zp[64] = f2b(o2[rg] * scl);
  }
}

// ---------------- aux loss ----------------
__global__ void aux_kernel(const float* __restrict__ ws_f,
                           const int* __restrict__ ws_i, float* __restrict__ out)
{
  if (threadIdx.x == 0 && blockIdx.x == 0) {
    float sw = 0.f;
    for (int e = 0; e < EE; e++) {
      float imp = ws_f[WS_IMP / 4 + e] / (float)NT;
      float load = (float)ws_i[e] / (float)(NT * HH);
      sw += imp * load;
    }
    float zl = ws_f[WS_ZSUM / 4] / (float)NT;
    out[(size_t)NT * CC] = 0.1f * ((float)EE * sw) + 0.001f * zl;
  }
}

extern "C" void kernel_launch(void* const* d_in, const int* in_sizes, int n_in,
                              void* d_out, int out_size, void* d_ws, size_t ws_size,
                              hipStream_t stream)
{
  const float* x    = (const float*)d_in[0];
  const float* Wg   = (const float*)d_in[1];
  const float* Win  = (const float*)d_in[2];
  const float* Wout = (const float*)d_in[3];
  const float* Wkv  = (const float*)d_in[4];
  const int*   task = (const int*)d_in[5];
  float* out = (float*)d_out;
  float* ws_f = (float*)d_ws;
  int*   ws_i = (int*)d_ws;
  u8*  eids = (u8*)((char*)d_ws + WS_EID);
  u16* kvbk = (u16*)((char*)d_ws + WS_KVK);
  u16* vtb  = (u16*)((char*)d_ws + WS_VT);
  u16* winT = (u16*)((char*)d_ws + WS_WIN);
  u16* woutT= (u16*)((char*)d_ws + WS_WOUT);
  u16* wkvT = (u16*)((char*)d_ws + WS_WKV);
  u16* qall = (u16*)((char*)d_ws + WS_QA);
  u16* z    = (u16*)((char*)d_ws + WS_Z);
  u16* xb   = (u16*)((char*)d_ws + WS_XB);
  int* bucket = (int*)((char*)d_ws + WS_BUCKET);

  hipMemsetAsync(d_ws, 0, 256, stream);

  transpose_kernel<<<dim3(CC/32, HD/32, EE), 256, 0, stream>>>(Win, winT, CC, HD, CC*HD, CC, HD*CC);
  transpose_kernel<<<dim3(HD/32, CC/32, EE), 256, 0, stream>>>(Wout, woutT, HD, CC, HD*CC, EC, HD);
  transpose_kernel<<<dim3(CC/32, 192/32, 1), 256, 0, stream>>>(Wkv, wkvT, CC, 192, 0, CC, 0);

  gate_kernel<<<NT / 64, 256, 0, stream>>>(x, Wg, task, ws_f, ws_i, eids, xb, bucket);

  kvproj_kernel<<<dim3(3, NT/128), 256, 0, stream>>>(xb, wkvT, kvbk, vtb);
  qproj_kernel<<<dim3(NT/128, EE), 256, 0, stream>>>(xb, winT, ws_i, bucket, qall);

  hipMemsetAsync(z, 0, (size_t)NT * EC * 2, stream);   // xb+bucket dead; z aliases them

  attn_kernel<<<dim3(NN/32, BB, 2), 256, 0, stream>>>(qall, kvbk, vtb, eids, ws_f + WS_G/4, z);

  gemm_kernel<128, 128, true><<<dim3(CC/128, NT/128), 256, 0, stream>>>(
      z, woutT, out, NT, CC, EC);

  aux_kernel<<<1, 64, 0, stream>>>(ws_f, ws_i, out);
}

// Round 10
// 185.520 us; speedup vs baseline: 7.2292x; 1.0787x over previous
//
#include <hip/hip_runtime.h>
#include <hip/hip_bf16.h>
#include <math.h>

#define BB 8
#define NN 1024
#define CC 768
#define HH 8
#define HD 96
#define EE 24
#define NT (BB*NN)          // 8192 tokens
#define NSLOT (NT*HH)       // 65536 (token,h) slots
#define EC (EE*HD)          // 2304
#define CAPQ 8192           // per-expert bucket capacity
#define ASCALE 0.10206207261596575f  // 96^-0.5
#define AL2 0.14724446f              // ASCALE * log2(e)
#define DEFER_THR 11.5415603f        // 8 * log2(e)

typedef unsigned short u16;
typedef unsigned char u8;
typedef unsigned int u32;
typedef unsigned long long u64;
typedef __attribute__((ext_vector_type(8))) short s16x8;
typedef __attribute__((ext_vector_type(4))) float f32x4;
typedef __attribute__((ext_vector_type(16))) float f32x16;

__device__ __forceinline__ u16 f2b(float f) {  // RNE float->bf16 bits
  unsigned u = __builtin_bit_cast(unsigned, f);
  unsigned r = u + 0x7fffu + ((u >> 16) & 1u);
  return (u16)(r >> 16);
}

__device__ __forceinline__ float fexp2(float x) {  // native 2^x
  float r; asm("v_exp_f32 %0, %1" : "=v"(r) : "v"(x)); return r;
}

__device__ __forceinline__ u32 cvtpk(float a, float b) {  // HW RNE pack
  u32 d; asm("v_cvt_pk_bf16_f32 %0, %1, %2" : "=v"(d) : "v"(a), "v"(b)); return d;
}

__device__ __forceinline__ void gload16(const u16* g, u16* lds) {
  __builtin_amdgcn_global_load_lds(
      (const __attribute__((address_space(1))) void*)g,
      (__attribute__((address_space(3))) void*)lds, 16, 0, 0);
}

// bijective XCD remap (8 XCDs): contiguous logical chunks per XCD
__device__ __forceinline__ int xcd_remap(int bid, int nwg) {
  int q = nwg >> 3, r = nwg & 7;
  int xcd = bid & 7, idx = bid >> 3;
  return (xcd < r ? xcd * (q + 1) : r * (q + 1) + (xcd - r) * q) + idx;
}

// ws layout (bytes)
#define WS_CNT   0
#define WS_IMP   96
#define WS_ZSUM  192
#define WS_G     256
#define WS_EID   (WS_G + NSLOT*4)
#define WS_KVK   (WS_EID + NSLOT)             // NT*128 u16 (K, padded+pre-swizzled)
#define WS_VT    (WS_KVK + NT*128*2)          // 96*NT u16 (V^T, in-block pre-swizzled)
#define WS_WIN   (WS_VT + (size_t)96*NT*2)
#define WS_WOUT  (WS_WIN + (size_t)EC*CC*2)
#define WS_WKV   (WS_WOUT + (size_t)CC*EC*2)
#define WS_QA    (WS_WKV + 192*CC*2)
#define WS_Z     (WS_QA + (size_t)NT*EC*2)
#define WS_XB    WS_Z                          // aliases z; xb dead before z memset
#define WS_BUCKET (WS_Z + (size_t)16*1024*1024) // aliases z tail; dead before z memset

// ---- gating: tiled fp32 GEMM + softmax + top-8 + buckets; emits xb=bf16(x)
__global__ __launch_bounds__(256) void gate_kernel(
    const float* __restrict__ x, const float* __restrict__ Wg_all,
    const int* __restrict__ task_p, float* __restrict__ ws_f,
    int* __restrict__ ws_i, u8* __restrict__ eids, u16* __restrict__ xb,
    int* __restrict__ bucket)
{
  __shared__ float xs[64][65];
  __shared__ float wgs[64][24];
  __shared__ float lgt[64][26];
  __shared__ float zlo[64];
  __shared__ int hist[EE];
  __shared__ int gbase[EE];

  int t = threadIdx.x;
  int w = t >> 6, r = t & 63;
  int e0 = w * 6;
  int tok0 = blockIdx.x * 64;
  const float* Wg = Wg_all + (size_t)task_p[0] * CC * EE;

  if (t < EE) hist[t] = 0;

  float acc[6];
  #pragma unroll
  for (int c = 0; c < 6; c++) acc[c] = 0.f;

  for (int kb = 0; kb < CC; kb += 64) {
    __syncthreads();
    #pragma unroll
    for (int i = 0; i < 4; i++) {
      int idx = i * 256 + t;
      int rr = idx >> 4, cc = (idx & 15) << 2;
      float4 v = *(const float4*)&x[(size_t)(tok0 + rr) * CC + kb + cc];
      *(float4*)&xs[rr][cc] = v;
      u64 pk = (u64)f2b(v.x) | ((u64)f2b(v.y) << 16) |
               ((u64)f2b(v.z) << 32) | ((u64)f2b(v.w) << 48);
      *(u64*)&xb[(size_t)(tok0 + rr) * CC + kb + cc] = pk;
    }
    #pragma unroll
    for (int i = 0; i < 3; i++) {
      int idx = i * 256 + t;
      int kk = idx / 12, c2 = idx % 12;
      *(float2*)&wgs[kk][c2 * 2] = *(const float2*)&Wg[(size_t)(kb + kk) * EE + c2 * 2];
    }
    __syncthreads();
    #pragma unroll 16
    for (int k = 0; k < 64; k++) {
      float xv = xs[r][k];
      float2 w01 = *(const float2*)&wgs[k][e0];
      float2 w23 = *(const float2*)&wgs[k][e0 + 2];
      float2 w45 = *(const float2*)&wgs[k][e0 + 4];
      acc[0] += xv * w01.x; acc[1] += xv * w01.y;
      acc[2] += xv * w23.x; acc[3] += xv * w23.y;
      acc[4] += xv * w45.x; acc[5] += xv * w45.y;
    }
  }
  __syncthreads();
  #pragma unroll
  for (int c = 0; c < 6; c++) lgt[r][e0 + c] = acc[c];
  __syncthreads();

  int my_e[8], loc[8];
  if (t < 64) {
    int token = tok0 + t;
    float l[EE];
    #pragma unroll
    for (int e = 0; e < EE; e++) l[e] = lgt[t][e];
    float mx = l[0];
    #pragma unroll
    for (int e = 1; e < EE; e++) mx = fmaxf(mx, l[e]);
    float se = 0.f; float probs[EE];
    #pragma unroll
    for (int e = 0; e < EE; e++) { probs[e] = __expf(l[e] - mx); se += probs[e]; }
    float inv = 1.f / se;
    #pragma unroll
    for (int e = 0; e < EE; e++) probs[e] *= inv;
    float lse = mx + __logf(se);
    zlo[t] = lse * lse;

    unsigned taken = 0u;
    float gsum = 0.f;
    float my_g[8];
    #pragma unroll
    for (int h = 0; h < HH; h++) {
      float best = -1.f; int bi = 0;
      #pragma unroll
      for (int e = 0; e < EE; e++) {
        bool ok = !((taken >> e) & 1u) && (probs[e] > best);
        best = ok ? probs[e] : best;
        bi   = ok ? e : bi;
      }
      taken |= 1u << bi;
      gsum += best;
      my_g[h] = best; my_e[h] = bi;
    }
    float ginv = 1.f / (gsum + 1e-6f);
    float4 g0, g1;
    g0.x = my_g[0] * ginv; g0.y = my_g[1] * ginv; g0.z = my_g[2] * ginv; g0.w = my_g[3] * ginv;
    g1.x = my_g[4] * ginv; g1.y = my_g[5] * ginv; g1.z = my_g[6] * ginv; g1.w = my_g[7] * ginv;
    float* gbuf = ws_f + WS_G / 4;
    *(float4*)&gbuf[(size_t)token * HH]     = g0;
    *(float4*)&gbuf[(size_t)token * HH + 4] = g1;
    u64 pk = 0;
    #pragma unroll
    for (int h = 0; h < HH; h++) pk |= (u64)(u8)my_e[h] << (8 * h);
    *(u64*)&eids[(size_t)token * HH] = pk;
    #pragma unroll
    for (int h = 0; h < HH; h++) loc[h] = atomicAdd(&hist[my_e[h]], 1);
    #pragma unroll
    for (int e = 0; e < EE; e++) lgt[t][e] = probs[e];
  }
  __syncthreads();
  if (t < EE) {
    float s = 0.f;
    #pragma unroll 8
    for (int rr = 0; rr < 64; rr++) s += lgt[rr][t];
    atomicAdd(ws_f + WS_IMP / 4 + t, s);
    gbase[t] = atomicAdd(&ws_i[t], hist[t]);
  } else if (t == 32) {
    float s = 0.f;
    #pragma unroll 8
    for (int rr = 0; rr < 64; rr++) s += zlo[rr];
    atomicAdd(ws_f + WS_ZSUM / 4, s);
  }
  __syncthreads();
  if (t < 64) {
    int token = tok0 + t;
    #pragma unroll
    for (int h = 0; h < HH; h++)
      bucket[my_e[h] * CAPQ + gbase[my_e[h]] + loc[h]] = token;
  }
}

// -------- batched transpose + f32->bf16 --------
__global__ __launch_bounds__(256) void transpose_kernel(
    const float* __restrict__ src, u16* __restrict__ dst,
    int R, int C, int sB, int dR, int dB)
{
  __shared__ float tile[32][33];
  int e = blockIdx.z;
  const float* s = src + (size_t)e * sB;
  int t = threadIdx.x;
  int tr = t >> 5, tc = t & 31;
  #pragma unroll
  for (int i = 0; i < 4; i++) {
    int r = blockIdx.x * 32 + tr + i * 8;
    int c = blockIdx.y * 32 + tc;
    tile[tr + i * 8][tc] = s[(size_t)r * C + c];
  }
  __syncthreads();
  #pragma unroll
  for (int i = 0; i < 4; i++) {
    int sc = blockIdx.y * 32 + tr + i * 8;
    int sr = blockIdx.x * 32 + tc;
    dst[(size_t)e * dB + (size_t)sc * dR + sr] = f2b(tile[tc][tr + i * 8]);
  }
}

// -------- dense MFMA GEMM (oproj), bf16 A/B, gload_lds, XCD-swizzled --------
template<int BM, int BN, bool OUT_F32>
__global__ __launch_bounds__(256) void gemm_kernel(
    const u16* __restrict__ A, const u16* __restrict__ Bt,
    void* __restrict__ Cp, int M, int N, int K)
{
  constexpr int WM = BM / 2, WN = BN / 2;
  constexpr int FM = WM / 16, FN = WN / 16;
  __shared__ u16 As[BM][64];
  __shared__ u16 Bs[BN][64];
  int t = threadIdx.x;
  int w = t >> 6, l = t & 63;
  int lr = l & 15, lg = l >> 4;
  int wr = w >> 1, wc = w & 1;
  int nwg = gridDim.x * gridDim.y;
  int logical = xcd_remap(blockIdx.y * gridDim.x + blockIdx.x, nwg);
  int col0 = (logical % gridDim.x) * BN, row0 = (logical / gridDim.x) * BM;

  f32x4 acc[FM][FN];
  #pragma unroll
  for (int i = 0; i < FM; i++)
    #pragma unroll
    for (int j = 0; j < FN; j++) acc[i][j] = (f32x4)(0.f);

  int sr = t >> 3;
  int sc = t & 7;
  for (int kb = 0; kb < K; kb += 64) {
    __syncthreads();
    #pragma unroll
    for (int i = 0; i < BM / 32; i++) {
      int rr = i * 32 + sr;
      int ch = sc ^ (rr & 7);
      gload16(A + (size_t)(row0 + rr) * K + kb + ch * 8, &As[rr][sc * 8]);
    }
    #pragma unroll
    for (int i = 0; i < BN / 32; i++) {
      int rr = i * 32 + sr;
      int ch = sc ^ (rr & 7);
      gload16(Bt + (size_t)(col0 + rr) * K + kb + ch * 8, &Bs[rr][sc * 8]);
    }
    __syncthreads();
    #pragma unroll
    for (int ks = 0; ks < 2; ks++) {
      s16x8 af[FM], bf[FN];
      #pragma unroll
      for (int i = 0; i < FM; i++)
        af[i] = *(const s16x8*)&As[wr * WM + i * 16 + lr][8 * ((ks * 4 + lg) ^ (lr & 7))];
      #pragma unroll
      for (int j = 0; j < FN; j++)
        bf[j] = *(const s16x8*)&Bs[wc * WN + j * 16 + lr][8 * ((ks * 4 + lg) ^ (lr & 7))];
      #pragma unroll
      for (int i = 0; i < FM; i++)
        #pragma unroll
        for (int j = 0; j < FN; j++)
          acc[i][j] = __builtin_amdgcn_mfma_f32_16x16x32_bf16(af[i], bf[j], acc[i][j], 0, 0, 0);
    }
  }
  #pragma unroll
  for (int i = 0; i < FM; i++)
    #pragma unroll
    for (int j = 0; j < FN; j++)
      #pragma unroll
      for (int reg = 0; reg < 4; reg++) {
        int rr = row0 + wr * WM + i * 16 + lg * 4 + reg;
        int cc = col0 + wc * WN + j * 16 + lr;
        if (OUT_F32) ((float*)Cp)[(size_t)rr * N + cc] = acc[i][j][reg];
        else ((u16*)Cp)[(size_t)rr * N + cc] = f2b(acc[i][j][reg]);
      }
}

// -------- gathered q projection: per-expert tiles, 128 rows x 96 cols, K=768
__global__ __launch_bounds__(256) void qproj_kernel(
    const u16* __restrict__ xb, const u16* __restrict__ winT,
    const int* __restrict__ ws_i, const int* __restrict__ bucket,
    u16* __restrict__ qall)
{
  int e = blockIdx.y;
  int t0 = blockIdx.x * 128;
  int cnt = ws_i[e];
  if (t0 >= cnt) return;
  __shared__ u16 As[128][64];
  __shared__ u16 Bs[96][64];
  __shared__ int tok_s[128];
  int t = threadIdx.x;
  if (t < 128) tok_s[t] = bucket[e * CAPQ + min(t0 + t, cnt - 1)];
  __syncthreads();
  int w = t >> 6, l = t & 63;
  int lr = l & 15, lg = l >> 4;
  int wr = w >> 1, wc = w & 1;
  const u16* Bt = winT + (size_t)e * HD * CC;

  f32x4 acc[4][3];
  #pragma unroll
  for (int i = 0; i < 4; i++)
    #pragma unroll
    for (int j = 0; j < 3; j++) acc[i][j] = (f32x4)(0.f);

  int sr = t >> 3, sc = t & 7;
  int atok[4];
  #pragma unroll
  for (int i = 0; i < 4; i++) atok[i] = tok_s[i * 32 + sr];

  for (int kb = 0; kb < CC; kb += 64) {
    __syncthreads();
    #pragma unroll
    for (int i = 0; i < 4; i++) {
      int rr = i * 32 + sr;
      int ch = sc ^ (rr & 7);
      gload16(xb + (size_t)atok[i] * CC + kb + ch * 8, &As[rr][sc * 8]);
    }
    #pragma unroll
    for (int i = 0; i < 3; i++) {
      int rr = i * 32 + sr;
      int ch = sc ^ (rr & 7);
      gload16(Bt + (size_t)rr * CC + kb + ch * 8, &Bs[rr][sc * 8]);
    }
    __syncthreads();
    #pragma unroll
    for (int ks = 0; ks < 2; ks++) {
      s16x8 af[4], bf[3];
      #pragma unroll
      for (int i = 0; i < 4; i++)
        af[i] = *(const s16x8*)&As[wr * 64 + i * 16 + lr][8 * ((ks * 4 + lg) ^ (lr & 7))];
      #pragma unroll
      for (int j = 0; j < 3; j++)
        bf[j] = *(const s16x8*)&Bs[wc * 48 + j * 16 + lr][8 * ((ks * 4 + lg) ^ (lr & 7))];
      #pragma unroll
      for (int i = 0; i < 4; i++)
        #pragma unroll
        for (int j = 0; j < 3; j++)
          acc[i][j] = __builtin_amdgcn_mfma_f32_16x16x32_bf16(af[i], bf[j], acc[i][j], 0, 0, 0);
    }
  }
  #pragma unroll
  for (int i = 0; i < 4; i++)
    #pragma unroll
    for (int reg = 0; reg < 4; reg++) {
      int rr = wr * 64 + i * 16 + lg * 4 + reg;
      if (t0 + rr < cnt) {
        int tok = tok_s[rr];
        u16* qp = qall + (size_t)tok * EC + e * HD + wc * 48;
        #pragma unroll
        for (int j = 0; j < 3; j++)
          qp[j * 16 + lr] = f2b(acc[i][j][reg]);
      }
    }
}

// -------- kv projection -> kvbk (padded 128, pre-swizzled K) + vtb (V^T, pre-swizzled)
__global__ __launch_bounds__(256) void kvproj_kernel(
    const u16* __restrict__ xb, const u16* __restrict__ wkvT,
    u16* __restrict__ kvbk, u16* __restrict__ vtb)
{
  __shared__ u16 As[128][64];
  __shared__ u16 Bs[64][64];
  int t = threadIdx.x;
  int w = t >> 6, l = t & 63;
  int lr = l & 15, lg = l >> 4;
  int wr = w >> 1, wc = w & 1;
  int nwg = gridDim.x * gridDim.y;
  int logical = xcd_remap(blockIdx.y * gridDim.x + blockIdx.x, nwg);
  int col0 = (logical % gridDim.x) * 64, row0 = (logical / gridDim.x) * 128;

  f32x4 acc[4][2];
  #pragma unroll
  for (int i = 0; i < 4; i++)
    #pragma unroll
    for (int j = 0; j < 2; j++) acc[i][j] = (f32x4)(0.f);

  int sr = t >> 3, sc = t & 7;
  for (int kb = 0; kb < CC; kb += 64) {
    __syncthreads();
    #pragma unroll
    for (int i = 0; i < 4; i++) {
      int rr = i * 32 + sr;
      int ch = sc ^ (rr & 7);
      gload16(xb + (size_t)(row0 + rr) * CC + kb + ch * 8, &As[rr][sc * 8]);
    }
    #pragma unroll
    for (int i = 0; i < 2; i++) {
      int rr = i * 32 + sr;
      int ch = sc ^ (rr & 7);
      gload16(wkvT + (size_t)(col0 + rr) * CC + kb + ch * 8, &Bs[rr][sc * 8]);
    }
    __syncthreads();
    #pragma unroll
    for (int ks = 0; ks < 2; ks++) {
      s16x8 af[4], bf[2];
      #pragma unroll
      for (int i = 0; i < 4; i++)
        af[i] = *(const s16x8*)&As[wr * 64 + i * 16 + lr][8 * ((ks * 4 + lg) ^ (lr & 7))];
      #pragma unroll
      for (int j = 0; j < 2; j++)
        bf[j] = *(const s16x8*)&Bs[wc * 32 + j * 16 + lr][8 * ((ks * 4 + lg) ^ (lr & 7))];
      #pragma unroll
      for (int i = 0; i < 4; i++)
        #pragma unroll
        for (int j = 0; j < 2; j++)
          acc[i][j] = __builtin_amdgcn_mfma_f32_16x16x32_bf16(af[i], bf[j], acc[i][j], 0, 0, 0);
    }
  }
  #pragma unroll
  for (int i = 0; i < 4; i++)
    #pragma unroll
    for (int j = 0; j < 2; j++) {
      int cb = col0 + wc * 32 + j * 16 + lr;
      int rb = row0 + wr * 64 + i * 16 + lg * 4;
      if (cb < 96) {
        int ch = cb >> 3, ci = cb & 7;
        #pragma unroll
        for (int reg = 0; reg < 4; reg++) {
          int tok = rb + reg;
          kvbk[(size_t)tok * 128 + 8 * (ch ^ (tok & 7)) + ci] = f2b(acc[i][j][reg]);
        }
      } else {
        int d = cb - 96;
        u64 pk = (u64)f2b(acc[i][j][0]) | ((u64)f2b(acc[i][j][1]) << 16) |
                 ((u64)f2b(acc[i][j][2]) << 32) | ((u64)f2b(acc[i][j][3]) << 48);
        int blkbase = rb & ~63;
        int ch = (rb & 63) >> 3;
        *(u64*)&vtb[(size_t)d * NT + blkbase + 8 * (ch ^ (d & 7)) + (rb & 7)] = pk;
      }
    }
}

// ---- flash attention: 32x32x16 MFMA, 4 waves = 4 heads (z splits 8 heads) ----
__global__ __launch_bounds__(256, 2) void attn_kernel(
    const u16* __restrict__ qall, const u16* __restrict__ kvbk,
    const u16* __restrict__ vtb, const u8* __restrict__ eids,
    const float* __restrict__ gbuf, u16* __restrict__ z)
{
  __shared__ u16 Ks[2][64][128];
  __shared__ u16 Vt[2][96][64];
  int b = blockIdx.y;
  int tok0 = blockIdx.x * 32;
  int t = threadIdx.x;
  int w = t >> 6, l = t & 63;
  int h = blockIdx.z * 4 + w;
  int lo = l & 31, hi = l >> 5;

  s16x8 qf[6];
  {
    int tok = b * NN + tok0 + lo;
    int e = eids[tok * HH + h];
    const u16* qp = qall + (size_t)tok * EC + e * HD + hi * 8;
    #pragma unroll
    for (int ks = 0; ks < 6; ks++)
      qf[ks] = *(const s16x8*)(qp + ks * 16);
  }

  const u16* kvwin = kvbk + (size_t)(b * NN) * 128;
  const u16* vwin  = vtb + (size_t)(b * NN);

  f32x16 o0 = (f32x16)(0.f), o1 = (f32x16)(0.f), o2 = (f32x16)(0.f);
  float m = -1e30f, lsum = 0.f;   // m in log2 units

  #pragma unroll
  for (int k2 = 0; k2 < 4; k2++) {
    int c = t + k2 * 256;
    gload16(kvwin + c * 8, &Ks[0][0][0] + c * 8);
  }
  #pragma unroll
  for (int k2 = 0; k2 < 3; k2++) {
    int c = t + k2 * 256;
    gload16(vwin + (size_t)(c >> 3) * NT + (c & 7) * 8, &Vt[0][0][0] + c * 8);
  }

  for (int jt = 0; jt < 16; jt++) {
    __syncthreads();
    if (jt < 15) {
      int j0 = (jt + 1) * 64;
      int nb = (jt + 1) & 1;
      const u16* kb_ = kvwin + (size_t)j0 * 128;
      #pragma unroll
      for (int k2 = 0; k2 < 4; k2++) {
        int c = t + k2 * 256;
        gload16(kb_ + c * 8, &Ks[nb][0][0] + c * 8);
      }
      const u16* vb_ = vwin + j0;
      #pragma unroll
      for (int k2 = 0; k2 < 3; k2++) {
        int c = t + k2 * 256;
        gload16(vb_ + (size_t)(c >> 3) * NT + (c & 7) * 8, &Vt[nb][0][0] + c * 8);
      }
    }
    int buf = jt & 1;

    f32x16 s0 = (f32x16)(0.f), s1 = (f32x16)(0.f);
    #pragma unroll
    for (int ks = 0; ks < 6; ks++) {
      int pos = 8 * ((2 * ks + hi) ^ (lo & 7));
      s16x8 a0 = *(const s16x8*)&Ks[buf][lo][pos];
      s16x8 a1 = *(const s16x8*)&Ks[buf][32 + lo][pos];
      s0 = __builtin_amdgcn_mfma_f32_32x32x16_bf16(a0, qf[ks], s0, 0, 0, 0);
      s1 = __builtin_amdgcn_mfma_f32_32x32x16_bf16(a1, qf[ks], s1, 0, 0, 0);
    }

    // row max via fmax triples (v_max3), then convert to log2 units
    float pm = fmaxf(s0[0], s0[1]);
    #pragma unroll
    for (int rg = 2; rg < 16; rg += 2) pm = fmaxf(pm, fmaxf(s0[rg], s0[rg + 1]));
    #pragma unroll
    for (int rg = 0; rg < 16; rg += 2) pm = fmaxf(pm, fmaxf(s1[rg], s1[rg + 1]));
    pm = fmaxf(pm, __shfl_xor(pm, 32));
    pm *= AL2;

    if (!__all(pm - m <= DEFER_THR)) {
      float mn = fmaxf(m, pm);
      float al = fexp2(m - mn);
      m = mn; lsum *= al;
      #pragma unroll
      for (int rg = 0; rg < 16; rg++) {
        int qrow = (rg & 3) + 8 * (rg >> 2) + 4 * hi;
        float alr = __shfl(al, qrow);
        o0[rg] *= alr; o1[rg] *= alr; o2[rg] *= alr;
      }
    }

    // P = 2^(s*AL2 - m); HW cvt_pk pack; local row-sum
    float ts = 0.f;
    u32 wpk[2][4][2];
    #pragma unroll
    for (int kb2 = 0; kb2 < 2; kb2++)
      #pragma unroll
      for (int rr = 0; rr < 4; rr++)
        #pragma unroll
        for (int pp = 0; pp < 2; pp++) {
          float sA = kb2 ? s1[rr * 4 + 2 * pp]     : s0[rr * 4 + 2 * pp];
          float sB = kb2 ? s1[rr * 4 + 2 * pp + 1] : s0[rr * 4 + 2 * pp + 1];
          float eA = fexp2(fmaf(sA, AL2, -m));
          float eB = fexp2(fmaf(sB, AL2, -m));
          ts += eA + eB;
          wpk[kb2][rr][pp] = cvtpk(eA, eB);
        }
    lsum += ts;

    s16x8 pa[4];
    #pragma unroll
    for (int ks = 0; ks < 4; ks++) {
      int kb2 = ks >> 1;
      int rlo = (ks & 1) * 2, rhi = rlo + 1;
      u32 own_lo0 = wpk[kb2][rlo][0], own_lo1 = wpk[kb2][rlo][1];
      u32 own_hi0 = wpk[kb2][rhi][0], own_hi1 = wpk[kb2][rhi][1];
      u32 send0 = hi ? own_lo0 : own_hi0;
      u32 send1 = hi ? own_lo1 : own_hi1;
      u32 recv0 = (u32)__shfl_xor((int)send0, 32);
      u32 recv1 = (u32)__shfl_xor((int)send1, 32);
      union { s16x8 v; u32 u[4]; } pu;
      pu.u[0] = hi ? recv0 : own_lo0;
      pu.u[1] = hi ? recv1 : own_lo1;
      pu.u[2] = hi ? own_hi0 : recv0;
      pu.u[3] = hi ? own_hi1 : recv1;
      pa[ks] = pu.v;
    }

    #pragma unroll
    for (int ks = 0; ks < 4; ks++) {
      int pos = 8 * ((2 * ks + hi) ^ (lo & 7));
      s16x8 v0 = *(const s16x8*)&Vt[buf][lo][pos];
      s16x8 v1 = *(const s16x8*)&Vt[buf][32 + lo][pos];
      s16x8 v2 = *(const s16x8*)&Vt[buf][64 + lo][pos];
      o0 = __builtin_amdgcn_mfma_f32_32x32x16_bf16(pa[ks], v0, o0, 0, 0, 0);
      o1 = __builtin_amdgcn_mfma_f32_32x32x16_bf16(pa[ks], v1, o1, 0, 0, 0);
      o2 = __builtin_amdgcn_mfma_f32_32x32x16_bf16(pa[ks], v2, o2, 0, 0, 0);
    }
  }

  float lt = lsum + __shfl_xor(lsum, 32);
  #pragma unroll
  for (int rg = 0; rg < 16; rg++) {
    int qrow = (rg & 3) + 8 * (rg >> 2) + 4 * hi;
    float lv = __shfl(lt, qrow);
    int tok = b * NN + tok0 + qrow;
    int slot = tok * HH + h;
    float scl = gbuf[slot] / lv;
    int e = eids[slot];
    u16* zp = z + (size_t)tok * EC + e * HD + lo;
    zp[0]  = f2b(o0[rg] * scl);
    zp[32] = f2b(o1[rg] * scl);
    zp[64] = f2b(o2[rg] * scl);
  }
}

// ---------------- aux loss ----------------
__global__ void aux_kernel(const float* __restrict__ ws_f,
                           const int* __restrict__ ws_i, float* __restrict__ out)
{
  if (threadIdx.x == 0 && blockIdx.x == 0) {
    float sw = 0.f;
    for (int e = 0; e < EE; e++) {
      float imp = ws_f[WS_IMP / 4 + e] / (float)NT;
      float load = (float)ws_i[e] / (float)(NT * HH);
      sw += imp * load;
    }
    float zl = ws_f[WS_ZSUM / 4] / (float)NT;
    out[(size_t)NT * CC] = 0.1f * ((float)EE * sw) + 0.001f * zl;
  }
}

extern "C" void kernel_launch(void* const* d_in, const int* in_sizes, int n_in,
                              void* d_out, int out_size, void* d_ws, size_t ws_size,
                              hipStream_t stream)
{
  const float* x    = (const float*)d_in[0];
  const float* Wg   = (const float*)d_in[1];
  const float* Win  = (const float*)d_in[2];
  const float* Wout = (const float*)d_in[3];
  const float* Wkv  = (const float*)d_in[4];
  const int*   task = (const int*)d_in[5];
  float* out = (float*)d_out;
  float* ws_f = (float*)d_ws;
  int*   ws_i = (int*)d_ws;
  u8*  eids = (u8*)((char*)d_ws + WS_EID);
  u16* kvbk = (u16*)((char*)d_ws + WS_KVK);
  u16* vtb  = (u16*)((char*)d_ws + WS_VT);
  u16* winT = (u16*)((char*)d_ws + WS_WIN);
  u16* woutT= (u16*)((char*)d_ws + WS_WOUT);
  u16* wkvT = (u16*)((char*)d_ws + WS_WKV);
  u16* qall = (u16*)((char*)d_ws + WS_QA);
  u16* z    = (u16*)((char*)d_ws + WS_Z);
  u16* xb   = (u16*)((char*)d_ws + WS_XB);
  int* bucket = (int*)((char*)d_ws + WS_BUCKET);

  hipMemsetAsync(d_ws, 0, 256, stream);

  transpose_kernel<<<dim3(CC/32, HD/32, EE), 256, 0, stream>>>(Win, winT, CC, HD, CC*HD, CC, HD*CC);
  transpose_kernel<<<dim3(HD/32, CC/32, EE), 256, 0, stream>>>(Wout, woutT, HD, CC, HD*CC, EC, HD);
  transpose_kernel<<<dim3(CC/32, 192/32, 1), 256, 0, stream>>>(Wkv, wkvT, CC, 192, 0, CC, 0);

  gate_kernel<<<NT / 64, 256, 0, stream>>>(x, Wg, task, ws_f, ws_i, eids, xb, bucket);

  kvproj_kernel<<<dim3(3, NT/128), 256, 0, stream>>>(xb, wkvT, kvbk, vtb);
  qproj_kernel<<<dim3(NT/128, EE), 256, 0, stream>>>(xb, winT, ws_i, bucket, qall);

  hipMemsetAsync(z, 0, (size_t)NT * EC * 2, stream);   // xb+bucket dead; z aliases them

  attn_kernel<<<dim3(NN/32, BB, 2), 256, 0, stream>>>(qall, kvbk, vtb, eids, ws_f + WS_G/4, z);

  // out = z @ W_out^T  (128x64 tiles -> 768 blocks, ~3-5/CU)
  gemm_kernel<128, 64, true><<<dim3(CC/64, NT/128), 256, 0, stream>>>(
      z, woutT, out, NT, CC, EC);

  aux_kernel<<<1, 64, 0, stream>>>(ws_f, ws_i, out);
}

// Round 11
// 178.808 us; speedup vs baseline: 7.5005x; 1.0375x over previous
//
#include <hip/hip_runtime.h>
#include <hip/hip_bf16.h>
#include <math.h>

#define BB 8
#define NN 1024
#define CC 768
#define HH 8
#define HD 96
#define EE 24
#define NT (BB*NN)          // 8192 tokens
#define NSLOT (NT*HH)       // 65536 (token,h) slots
#define EC (EE*HD)          // 2304
#define CAPQ 8192           // per-expert bucket capacity
#define ASCALE 0.10206207261596575f  // 96^-0.5
#define AL2 0.14724446f              // ASCALE * log2(e)
#define DEFER_THR 11.5415603f        // 8 * log2(e)

typedef unsigned short u16;
typedef unsigned char u8;
typedef unsigned int u32;
typedef unsigned long long u64;
typedef __attribute__((ext_vector_type(8))) short s16x8;
typedef __attribute__((ext_vector_type(4))) float f32x4;
typedef __attribute__((ext_vector_type(16))) float f32x16;

__device__ __forceinline__ u16 f2b(float f) {  // RNE float->bf16 bits
  unsigned u = __builtin_bit_cast(unsigned, f);
  unsigned r = u + 0x7fffu + ((u >> 16) & 1u);
  return (u16)(r >> 16);
}

__device__ __forceinline__ float fexp2(float x) {  // native 2^x
  float r; asm("v_exp_f32 %0, %1" : "=v"(r) : "v"(x)); return r;
}

__device__ __forceinline__ u32 cvtpk(float a, float b) {  // HW RNE pack
  u32 d; asm("v_cvt_pk_bf16_f32 %0, %1, %2" : "=v"(d) : "v"(a), "v"(b)); return d;
}

__device__ __forceinline__ void gload16(const u16* g, u16* lds) {
  __builtin_amdgcn_global_load_lds(
      (const __attribute__((address_space(1))) void*)g,
      (__attribute__((address_space(3))) void*)lds, 16, 0, 0);
}

// bijective XCD remap (8 XCDs): contiguous logical chunks per XCD
__device__ __forceinline__ int xcd_remap(int bid, int nwg) {
  int q = nwg >> 3, r = nwg & 7;
  int xcd = bid & 7, idx = bid >> 3;
  return (xcd < r ? xcd * (q + 1) : r * (q + 1) + (xcd - r) * q) + idx;
}

// ws layout (bytes)
#define WS_CNT   0
#define WS_IMP   96
#define WS_ZSUM  192
#define WS_G     256
#define WS_EID   (WS_G + NSLOT*4)
#define WS_KVK   (WS_EID + NSLOT)             // NT*128 u16 (K, padded+pre-swizzled)
#define WS_VT    (WS_KVK + NT*128*2)          // 96*NT u16 (V^T, in-block pre-swizzled)
#define WS_WIN   (WS_VT + (size_t)96*NT*2)
#define WS_WOUT  (WS_WIN + (size_t)EC*CC*2)
#define WS_WKV   (WS_WOUT + (size_t)CC*EC*2)
#define WS_QA    (WS_WKV + 192*CC*2)
#define WS_Z     (WS_QA + (size_t)NT*EC*2)
#define WS_XB    WS_Z                          // aliases z; xb dead before z memset
#define WS_BUCKET (WS_Z + (size_t)16*1024*1024) // aliases z tail; dead before z memset

// ---- gating: 512 thr / 32 tok; k split 4-way; fp32; emits xb=bf16(x) ----
__global__ __launch_bounds__(512) void gate_kernel(
    const float* __restrict__ x, const float* __restrict__ Wg_all,
    const int* __restrict__ task_p, float* __restrict__ ws_f,
    int* __restrict__ ws_i, u8* __restrict__ eids, u16* __restrict__ xb,
    int* __restrict__ bucket)
{
  __shared__ float xs[32][65];
  __shared__ float wgs[64][24];
  __shared__ float scr[4][32][6];
  __shared__ float lgt[32][26];
  __shared__ float zlo[32];
  __shared__ int hist[EE];
  __shared__ int gbase[EE];

  int t = threadIdx.x;
  int w = t >> 6, l = t & 63;
  int eg = w & 3, e0 = eg * 6;
  int r = l & 31;
  int q = ((w >> 2) << 1) | (l >> 5);   // k-quarter 0..3
  int tok0 = blockIdx.x * 32;
  const float* Wg = Wg_all + (size_t)task_p[0] * CC * EE;

  if (t < EE) hist[t] = 0;

  float acc[6];
  #pragma unroll
  for (int c = 0; c < 6; c++) acc[c] = 0.f;

  for (int kb = 0; kb < CC; kb += 64) {
    __syncthreads();
    // stage x tile [32][64] (1 float4/thread) + emit xb
    {
      int rr = t >> 4, cc = (t & 15) << 2;
      float4 v = *(const float4*)&x[(size_t)(tok0 + rr) * CC + kb + cc];
      *(float4*)&xs[rr][cc] = v;
      u64 pk = (u64)f2b(v.x) | ((u64)f2b(v.y) << 16) |
               ((u64)f2b(v.z) << 32) | ((u64)f2b(v.w) << 48);
      *(u64*)&xb[(size_t)(tok0 + rr) * CC + kb + cc] = pk;
    }
    // stage Wg tile [64][24]
    #pragma unroll
    for (int i = 0; i < 2; i++) {
      int idx = i * 512 + t;
      if (idx < 768) {
        int kk = idx / 12, c2 = idx % 12;
        *(float2*)&wgs[kk][c2 * 2] = *(const float2*)&Wg[(size_t)(kb + kk) * EE + c2 * 2];
      }
    }
    __syncthreads();
    int k0 = q * 16;
    #pragma unroll
    for (int k = 0; k < 16; k++) {
      float xv = xs[r][k0 + k];
      float2 w01 = *(const float2*)&wgs[k0 + k][e0];
      float2 w23 = *(const float2*)&wgs[k0 + k][e0 + 2];
      float2 w45 = *(const float2*)&wgs[k0 + k][e0 + 4];
      acc[0] += xv * w01.x; acc[1] += xv * w01.y;
      acc[2] += xv * w23.x; acc[3] += xv * w23.y;
      acc[4] += xv * w45.x; acc[5] += xv * w45.y;
    }
  }
  // combine k-quarters: xor-32 within wave, LDS across wave pairs
  #pragma unroll
  for (int c = 0; c < 6; c++) acc[c] += __shfl_xor(acc[c], 32);
  if (w >= 4 && l < 32) {
    #pragma unroll
    for (int c = 0; c < 6; c++) scr[eg][r][c] = acc[c];
  }
  __syncthreads();
  if (w < 4 && l < 32) {
    #pragma unroll
    for (int c = 0; c < 6; c++) lgt[r][e0 + c] = acc[c] + scr[eg][r][c];
  }
  __syncthreads();

  int my_e[8], loc[8];
  if (t < 32) {
    int token = tok0 + t;
    float lg[EE];
    #pragma unroll
    for (int e = 0; e < EE; e++) lg[e] = lgt[t][e];
    float mx = lg[0];
    #pragma unroll
    for (int e = 1; e < EE; e++) mx = fmaxf(mx, lg[e]);
    float se = 0.f; float probs[EE];
    #pragma unroll
    for (int e = 0; e < EE; e++) { probs[e] = __expf(lg[e] - mx); se += probs[e]; }
    float inv = 1.f / se;
    #pragma unroll
    for (int e = 0; e < EE; e++) probs[e] *= inv;
    float lse = mx + __logf(se);
    zlo[t] = lse * lse;

    unsigned taken = 0u;
    float gsum = 0.f;
    float my_g[8];
    #pragma unroll
    for (int h = 0; h < HH; h++) {
      float best = -1.f; int bi = 0;
      #pragma unroll
      for (int e = 0; e < EE; e++) {
        bool ok = !((taken >> e) & 1u) && (probs[e] > best);
        best = ok ? probs[e] : best;
        bi   = ok ? e : bi;
      }
      taken |= 1u << bi;
      gsum += best;
      my_g[h] = best; my_e[h] = bi;
    }
    float ginv = 1.f / (gsum + 1e-6f);
    float4 g0, g1;
    g0.x = my_g[0] * ginv; g0.y = my_g[1] * ginv; g0.z = my_g[2] * ginv; g0.w = my_g[3] * ginv;
    g1.x = my_g[4] * ginv; g1.y = my_g[5] * ginv; g1.z = my_g[6] * ginv; g1.w = my_g[7] * ginv;
    float* gbuf = ws_f + WS_G / 4;
    *(float4*)&gbuf[(size_t)token * HH]     = g0;
    *(float4*)&gbuf[(size_t)token * HH + 4] = g1;
    u64 pk = 0;
    #pragma unroll
    for (int h = 0; h < HH; h++) pk |= (u64)(u8)my_e[h] << (8 * h);
    *(u64*)&eids[(size_t)token * HH] = pk;
    #pragma unroll
    for (int h = 0; h < HH; h++) loc[h] = atomicAdd(&hist[my_e[h]], 1);
    #pragma unroll
    for (int e = 0; e < EE; e++) lgt[t][e] = probs[e];
  }
  __syncthreads();
  if (t < EE) {
    float s = 0.f;
    #pragma unroll 8
    for (int rr = 0; rr < 32; rr++) s += lgt[rr][t];
    atomicAdd(ws_f + WS_IMP / 4 + t, s);
    gbase[t] = atomicAdd(&ws_i[t], hist[t]);
  } else if (t == 32) {
    float s = 0.f;
    #pragma unroll 8
    for (int rr = 0; rr < 32; rr++) s += zlo[rr];
    atomicAdd(ws_f + WS_ZSUM / 4, s);
  }
  __syncthreads();
  if (t < 32) {
    int token = tok0 + t;
    #pragma unroll
    for (int h = 0; h < HH; h++)
      bucket[my_e[h] * CAPQ + gbase[my_e[h]] + loc[h]] = token;
  }
}

// -------- batched transpose + f32->bf16 --------
__global__ __launch_bounds__(256) void transpose_kernel(
    const float* __restrict__ src, u16* __restrict__ dst,
    int R, int C, int sB, int dR, int dB)
{
  __shared__ float tile[32][33];
  int e = blockIdx.z;
  const float* s = src + (size_t)e * sB;
  int t = threadIdx.x;
  int tr = t >> 5, tc = t & 31;
  #pragma unroll
  for (int i = 0; i < 4; i++) {
    int r = blockIdx.x * 32 + tr + i * 8;
    int c = blockIdx.y * 32 + tc;
    tile[tr + i * 8][tc] = s[(size_t)r * C + c];
  }
  __syncthreads();
  #pragma unroll
  for (int i = 0; i < 4; i++) {
    int sc = blockIdx.y * 32 + tr + i * 8;
    int sr = blockIdx.x * 32 + tc;
    dst[(size_t)e * dB + (size_t)sc * dR + sr] = f2b(tile[tc][tr + i * 8]);
  }
}

// -------- dense MFMA GEMM (oproj), bf16 A/B, gload_lds, XCD-swizzled --------
template<int BM, int BN, bool OUT_F32>
__global__ __launch_bounds__(256) void gemm_kernel(
    const u16* __restrict__ A, const u16* __restrict__ Bt,
    void* __restrict__ Cp, int M, int N, int K)
{
  constexpr int WM = BM / 2, WN = BN / 2;
  constexpr int FM = WM / 16, FN = WN / 16;
  __shared__ u16 As[BM][64];
  __shared__ u16 Bs[BN][64];
  int t = threadIdx.x;
  int w = t >> 6, l = t & 63;
  int lr = l & 15, lg = l >> 4;
  int wr = w >> 1, wc = w & 1;
  int nwg = gridDim.x * gridDim.y;
  int logical = xcd_remap(blockIdx.y * gridDim.x + blockIdx.x, nwg);
  int col0 = (logical % gridDim.x) * BN, row0 = (logical / gridDim.x) * BM;

  f32x4 acc[FM][FN];
  #pragma unroll
  for (int i = 0; i < FM; i++)
    #pragma unroll
    for (int j = 0; j < FN; j++) acc[i][j] = (f32x4)(0.f);

  int sr = t >> 3;
  int sc = t & 7;
  for (int kb = 0; kb < K; kb += 64) {
    __syncthreads();
    #pragma unroll
    for (int i = 0; i < BM / 32; i++) {
      int rr = i * 32 + sr;
      int ch = sc ^ (rr & 7);
      gload16(A + (size_t)(row0 + rr) * K + kb + ch * 8, &As[rr][sc * 8]);
    }
    #pragma unroll
    for (int i = 0; i < BN / 32; i++) {
      int rr = i * 32 + sr;
      int ch = sc ^ (rr & 7);
      gload16(Bt + (size_t)(col0 + rr) * K + kb + ch * 8, &Bs[rr][sc * 8]);
    }
    __syncthreads();
    #pragma unroll
    for (int ks = 0; ks < 2; ks++) {
      s16x8 af[FM], bf[FN];
      #pragma unroll
      for (int i = 0; i < FM; i++)
        af[i] = *(const s16x8*)&As[wr * WM + i * 16 + lr][8 * ((ks * 4 + lg) ^ (lr & 7))];
      #pragma unroll
      for (int j = 0; j < FN; j++)
        bf[j] = *(const s16x8*)&Bs[wc * WN + j * 16 + lr][8 * ((ks * 4 + lg) ^ (lr & 7))];
      #pragma unroll
      for (int i = 0; i < FM; i++)
        #pragma unroll
        for (int j = 0; j < FN; j++)
          acc[i][j] = __builtin_amdgcn_mfma_f32_16x16x32_bf16(af[i], bf[j], acc[i][j], 0, 0, 0);
    }
  }
  #pragma unroll
  for (int i = 0; i < FM; i++)
    #pragma unroll
    for (int j = 0; j < FN; j++)
      #pragma unroll
      for (int reg = 0; reg < 4; reg++) {
        int rr = row0 + wr * WM + i * 16 + lg * 4 + reg;
        int cc = col0 + wc * WN + j * 16 + lr;
        if (OUT_F32) ((float*)Cp)[(size_t)rr * N + cc] = acc[i][j][reg];
        else ((u16*)Cp)[(size_t)rr * N + cc] = f2b(acc[i][j][reg]);
      }
}

// -------- gathered q projection: per-expert tiles, 128 rows x 96 cols, K=768
__global__ __launch_bounds__(256) void qproj_kernel(
    const u16* __restrict__ xb, const u16* __restrict__ winT,
    const int* __restrict__ ws_i, const int* __restrict__ bucket,
    u16* __restrict__ qall)
{
  int e = blockIdx.y;
  int t0 = blockIdx.x * 128;
  int cnt = ws_i[e];
  if (t0 >= cnt) return;
  __shared__ u16 As[128][64];
  __shared__ u16 Bs[96][64];
  __shared__ int tok_s[128];
  int t = threadIdx.x;
  if (t < 128) tok_s[t] = bucket[e * CAPQ + min(t0 + t, cnt - 1)];
  __syncthreads();
  int w = t >> 6, l = t & 63;
  int lr = l & 15, lg = l >> 4;
  int wr = w >> 1, wc = w & 1;
  const u16* Bt = winT + (size_t)e * HD * CC;

  f32x4 acc[4][3];
  #pragma unroll
  for (int i = 0; i < 4; i++)
    #pragma unroll
    for (int j = 0; j < 3; j++) acc[i][j] = (f32x4)(0.f);

  int sr = t >> 3, sc = t & 7;
  int atok[4];
  #pragma unroll
  for (int i = 0; i < 4; i++) atok[i] = tok_s[i * 32 + sr];

  for (int kb = 0; kb < CC; kb += 64) {
    __syncthreads();
    #pragma unroll
    for (int i = 0; i < 4; i++) {
      int rr = i * 32 + sr;
      int ch = sc ^ (rr & 7);
      gload16(xb + (size_t)atok[i] * CC + kb + ch * 8, &As[rr][sc * 8]);
    }
    #pragma unroll
    for (int i = 0; i < 3; i++) {
      int rr = i * 32 + sr;
      int ch = sc ^ (rr & 7);
      gload16(Bt + (size_t)rr * CC + kb + ch * 8, &Bs[rr][sc * 8]);
    }
    __syncthreads();
    #pragma unroll
    for (int ks = 0; ks < 2; ks++) {
      s16x8 af[4], bf[3];
      #pragma unroll
      for (int i = 0; i < 4; i++)
        af[i] = *(const s16x8*)&As[wr * 64 + i * 16 + lr][8 * ((ks * 4 + lg) ^ (lr & 7))];
      #pragma unroll
      for (int j = 0; j < 3; j++)
        bf[j] = *(const s16x8*)&Bs[wc * 48 + j * 16 + lr][8 * ((ks * 4 + lg) ^ (lr & 7))];
      #pragma unroll
      for (int i = 0; i < 4; i++)
        #pragma unroll
        for (int j = 0; j < 3; j++)
          acc[i][j] = __builtin_amdgcn_mfma_f32_16x16x32_bf16(af[i], bf[j], acc[i][j], 0, 0, 0);
    }
  }
  #pragma unroll
  for (int i = 0; i < 4; i++)
    #pragma unroll
    for (int reg = 0; reg < 4; reg++) {
      int rr = wr * 64 + i * 16 + lg * 4 + reg;
      if (t0 + rr < cnt) {
        int tok = tok_s[rr];
        u16* qp = qall + (size_t)tok * EC + e * HD + wc * 48;
        #pragma unroll
        for (int j = 0; j < 3; j++)
          qp[j * 16 + lr] = f2b(acc[i][j][reg]);
      }
    }
}

// -------- kv projection -> kvbk (padded 128, pre-swizzled K) + vtb (V^T, pre-swizzled)
__global__ __launch_bounds__(256) void kvproj_kernel(
    const u16* __restrict__ xb, const u16* __restrict__ wkvT,
    u16* __restrict__ kvbk, u16* __restrict__ vtb)
{
  __shared__ u16 As[128][64];
  __shared__ u16 Bs[64][64];
  int t = threadIdx.x;
  int w = t >> 6, l = t & 63;
  int lr = l & 15, lg = l >> 4;
  int wr = w >> 1, wc = w & 1;
  int nwg = gridDim.x * gridDim.y;
  int logical = xcd_remap(blockIdx.y * gridDim.x + blockIdx.x, nwg);
  int col0 = (logical % gridDim.x) * 64, row0 = (logical / gridDim.x) * 128;

  f32x4 acc[4][2];
  #pragma unroll
  for (int i = 0; i < 4; i++)
    #pragma unroll
    for (int j = 0; j < 2; j++) acc[i][j] = (f32x4)(0.f);

  int sr = t >> 3, sc = t & 7;
  for (int kb = 0; kb < CC; kb += 64) {
    __syncthreads();
    #pragma unroll
    for (int i = 0; i < 4; i++) {
      int rr = i * 32 + sr;
      int ch = sc ^ (rr & 7);
      gload16(xb + (size_t)(row0 + rr) * CC + kb + ch * 8, &As[rr][sc * 8]);
    }
    #pragma unroll
    for (int i = 0; i < 2; i++) {
      int rr = i * 32 + sr;
      int ch = sc ^ (rr & 7);
      gload16(wkvT + (size_t)(col0 + rr) * CC + kb + ch * 8, &Bs[rr][sc * 8]);
    }
    __syncthreads();
    #pragma unroll
    for (int ks = 0; ks < 2; ks++) {
      s16x8 af[4], bf[2];
      #pragma unroll
      for (int i = 0; i < 4; i++)
        af[i] = *(const s16x8*)&As[wr * 64 + i * 16 + lr][8 * ((ks * 4 + lg) ^ (lr & 7))];
      #pragma unroll
      for (int j = 0; j < 2; j++)
        bf[j] = *(const s16x8*)&Bs[wc * 32 + j * 16 + lr][8 * ((ks * 4 + lg) ^ (lr & 7))];
      #pragma unroll
      for (int i = 0; i < 4; i++)
        #pragma unroll
        for (int j = 0; j < 2; j++)
          acc[i][j] = __builtin_amdgcn_mfma_f32_16x16x32_bf16(af[i], bf[j], acc[i][j], 0, 0, 0);
    }
  }
  #pragma unroll
  for (int i = 0; i < 4; i++)
    #pragma unroll
    for (int j = 0; j < 2; j++) {
      int cb = col0 + wc * 32 + j * 16 + lr;
      int rb = row0 + wr * 64 + i * 16 + lg * 4;
      if (cb < 96) {
        int ch = cb >> 3, ci = cb & 7;
        #pragma unroll
        for (int reg = 0; reg < 4; reg++) {
          int tok = rb + reg;
          kvbk[(size_t)tok * 128 + 8 * (ch ^ (tok & 7)) + ci] = f2b(acc[i][j][reg]);
        }
      } else {
        int d = cb - 96;
        u64 pk = (u64)f2b(acc[i][j][0]) | ((u64)f2b(acc[i][j][1]) << 16) |
                 ((u64)f2b(acc[i][j][2]) << 32) | ((u64)f2b(acc[i][j][3]) << 48);
        int blkbase = rb & ~63;
        int ch = (rb & 63) >> 3;
        *(u64*)&vtb[(size_t)d * NT + blkbase + 8 * (ch ^ (d & 7)) + (rb & 7)] = pk;
      }
    }
}

// ---- flash attention: 32x32x16 MFMA, 4 waves = 4 heads (z splits 8 heads) ----
__global__ __launch_bounds__(256, 2) void attn_kernel(
    const u16* __restrict__ qall, const u16* __restrict__ kvbk,
    const u16* __restrict__ vtb, const u8* __restrict__ eids,
    const float* __restrict__ gbuf, u16* __restrict__ z)
{
  __shared__ u16 Ks[2][64][128];
  __shared__ u16 Vt[2][96][64];
  int b = blockIdx.y;
  int tok0 = blockIdx.x * 32;
  int t = threadIdx.x;
  int w = t >> 6, l = t & 63;
  int h = blockIdx.z * 4 + w;
  int lo = l & 31, hi = l >> 5;

  s16x8 qf[6];
  {
    int tok = b * NN + tok0 + lo;
    int e = eids[tok * HH + h];
    const u16* qp = qall + (size_t)tok * EC + e * HD + hi * 8;
    #pragma unroll
    for (int ks = 0; ks < 6; ks++)
      qf[ks] = *(const s16x8*)(qp + ks * 16);
  }

  const u16* kvwin = kvbk + (size_t)(b * NN) * 128;
  const u16* vwin  = vtb + (size_t)(b * NN);

  f32x16 o0 = (f32x16)(0.f), o1 = (f32x16)(0.f), o2 = (f32x16)(0.f);
  float m = -1e30f, lsum = 0.f;   // m in log2 units

  #pragma unroll
  for (int k2 = 0; k2 < 4; k2++) {
    int c = t + k2 * 256;
    gload16(kvwin + c * 8, &Ks[0][0][0] + c * 8);
  }
  #pragma unroll
  for (int k2 = 0; k2 < 3; k2++) {
    int c = t + k2 * 256;
    gload16(vwin + (size_t)(c >> 3) * NT + (c & 7) * 8, &Vt[0][0][0] + c * 8);
  }

  for (int jt = 0; jt < 16; jt++) {
    __syncthreads();
    if (jt < 15) {
      int j0 = (jt + 1) * 64;
      int nb = (jt + 1) & 1;
      const u16* kb_ = kvwin + (size_t)j0 * 128;
      #pragma unroll
      for (int k2 = 0; k2 < 4; k2++) {
        int c = t + k2 * 256;
        gload16(kb_ + c * 8, &Ks[nb][0][0] + c * 8);
      }
      const u16* vb_ = vwin + j0;
      #pragma unroll
      for (int k2 = 0; k2 < 3; k2++) {
        int c = t + k2 * 256;
        gload16(vb_ + (size_t)(c >> 3) * NT + (c & 7) * 8, &Vt[nb][0][0] + c * 8);
      }
    }
    int buf = jt & 1;

    f32x16 s0 = (f32x16)(0.f), s1 = (f32x16)(0.f);
    #pragma unroll
    for (int ks = 0; ks < 6; ks++) {
      int pos = 8 * ((2 * ks + hi) ^ (lo & 7));
      s16x8 a0 = *(const s16x8*)&Ks[buf][lo][pos];
      s16x8 a1 = *(const s16x8*)&Ks[buf][32 + lo][pos];
      s0 = __builtin_amdgcn_mfma_f32_32x32x16_bf16(a0, qf[ks], s0, 0, 0, 0);
      s1 = __builtin_amdgcn_mfma_f32_32x32x16_bf16(a1, qf[ks], s1, 0, 0, 0);
    }

    // row max via fmax triples (v_max3), then convert to log2 units
    float pm = fmaxf(s0[0], s0[1]);
    #pragma unroll
    for (int rg = 2; rg < 16; rg += 2) pm = fmaxf(pm, fmaxf(s0[rg], s0[rg + 1]));
    #pragma unroll
    for (int rg = 0; rg < 16; rg += 2) pm = fmaxf(pm, fmaxf(s1[rg], s1[rg + 1]));
    pm = fmaxf(pm, __shfl_xor(pm, 32));
    pm *= AL2;

    if (!__all(pm - m <= DEFER_THR)) {
      float mn = fmaxf(m, pm);
      float al = fexp2(m - mn);
      m = mn; lsum *= al;
      #pragma unroll
      for (int rg = 0; rg < 16; rg++) {
        int qrow = (rg & 3) + 8 * (rg >> 2) + 4 * hi;
        float alr = __shfl(al, qrow);
        o0[rg] *= alr; o1[rg] *= alr; o2[rg] *= alr;
      }
    }

    // P = 2^(s*AL2 - m); HW cvt_pk pack; local row-sum
    float ts = 0.f;
    u32 wpk[2][4][2];
    #pragma unroll
    for (int kb2 = 0; kb2 < 2; kb2++)
      #pragma unroll
      for (int rr = 0; rr < 4; rr++)
        #pragma unroll
        for (int pp = 0; pp < 2; pp++) {
          float sA = kb2 ? s1[rr * 4 + 2 * pp]     : s0[rr * 4 + 2 * pp];
          float sB = kb2 ? s1[rr * 4 + 2 * pp + 1] : s0[rr * 4 + 2 * pp + 1];
          float eA = fexp2(fmaf(sA, AL2, -m));
          float eB = fexp2(fmaf(sB, AL2, -m));
          ts += eA + eB;
          wpk[kb2][rr][pp] = cvtpk(eA, eB);
        }
    lsum += ts;

    s16x8 pa[4];
    #pragma unroll
    for (int ks = 0; ks < 4; ks++) {
      int kb2 = ks >> 1;
      int rlo = (ks & 1) * 2, rhi = rlo + 1;
      u32 own_lo0 = wpk[kb2][rlo][0], own_lo1 = wpk[kb2][rlo][1];
      u32 own_hi0 = wpk[kb2][rhi][0], own_hi1 = wpk[kb2][rhi][1];
      u32 send0 = hi ? own_lo0 : own_hi0;
      u32 send1 = hi ? own_lo1 : own_hi1;
      u32 recv0 = (u32)__shfl_xor((int)send0, 32);
      u32 recv1 = (u32)__shfl_xor((int)send1, 32);
      union { s16x8 v; u32 u[4]; } pu;
      pu.u[0] = hi ? recv0 : own_lo0;
      pu.u[1] = hi ? recv1 : own_lo1;
      pu.u[2] = hi ? own_hi0 : recv0;
      pu.u[3] = hi ? own_hi1 : recv1;
      pa[ks] = pu.v;
    }

    #pragma unroll
    for (int ks = 0; ks < 4; ks++) {
      int pos = 8 * ((2 * ks + hi) ^ (lo & 7));
      s16x8 v0 = *(const s16x8*)&Vt[buf][lo][pos];
      s16x8 v1 = *(const s16x8*)&Vt[buf][32 + lo][pos];
      s16x8 v2 = *(const s16x8*)&Vt[buf][64 + lo][pos];
      o0 = __builtin_amdgcn_mfma_f32_32x32x16_bf16(pa[ks], v0, o0, 0, 0, 0);
      o1 = __builtin_amdgcn_mfma_f32_32x32x16_bf16(pa[ks], v1, o1, 0, 0, 0);
      o2 = __builtin_amdgcn_mfma_f32_32x32x16_bf16(pa[ks], v2, o2, 0, 0, 0);
    }
  }

  float lt = lsum + __shfl_xor(lsum, 32);
  #pragma unroll
  for (int rg = 0; rg < 16; rg++) {
    int qrow = (rg & 3) + 8 * (rg >> 2) + 4 * hi;
    float lv = __shfl(lt, qrow);
    int tok = b * NN + tok0 + qrow;
    int slot = tok * HH + h;
    float scl = gbuf[slot] / lv;
    int e = eids[slot];
    u16* zp = z + (size_t)tok * EC + e * HD + lo;
    zp[0]  = f2b(o0[rg] * scl);
    zp[32] = f2b(o1[rg] * scl);
    zp[64] = f2b(o2[rg] * scl);
  }
}

// ---------------- aux loss ----------------
__global__ void aux_kernel(const float* __restrict__ ws_f,
                           const int* __restrict__ ws_i, float* __restrict__ out)
{
  if (threadIdx.x == 0 && blockIdx.x == 0) {
    float sw = 0.f;
    for (int e = 0; e < EE; e++) {
      float imp = ws_f[WS_IMP / 4 + e] / (float)NT;
      float load = (float)ws_i[e] / (float)(NT * HH);
      sw += imp * load;
    }
    float zl = ws_f[WS_ZSUM / 4] / (float)NT;
    out[(size_t)NT * CC] = 0.1f * ((float)EE * sw) + 0.001f * zl;
  }
}

extern "C" void kernel_launch(void* const* d_in, const int* in_sizes, int n_in,
                              void* d_out, int out_size, void* d_ws, size_t ws_size,
                              hipStream_t stream)
{
  const float* x    = (const float*)d_in[0];
  const float* Wg   = (const float*)d_in[1];
  const float* Win  = (const float*)d_in[2];
  const float* Wout = (const float*)d_in[3];
  const float* Wkv  = (const float*)d_in[4];
  const int*   task = (const int*)d_in[5];
  float* out = (float*)d_out;
  float* ws_f = (float*)d_ws;
  int*   ws_i = (int*)d_ws;
  u8*  eids = (u8*)((char*)d_ws + WS_EID);
  u16* kvbk = (u16*)((char*)d_ws + WS_KVK);
  u16* vtb  = (u16*)((char*)d_ws + WS_VT);
  u16* winT = (u16*)((char*)d_ws + WS_WIN);
  u16* woutT= (u16*)((char*)d_ws + WS_WOUT);
  u16* wkvT = (u16*)((char*)d_ws + WS_WKV);
  u16* qall = (u16*)((char*)d_ws + WS_QA);
  u16* z    = (u16*)((char*)d_ws + WS_Z);
  u16* xb   = (u16*)((char*)d_ws + WS_XB);
  int* bucket = (int*)((char*)d_ws + WS_BUCKET);

  hipMemsetAsync(d_ws, 0, 256, stream);

  transpose_kernel<<<dim3(CC/32, HD/32, EE), 256, 0, stream>>>(Win, winT, CC, HD, CC*HD, CC, HD*CC);
  transpose_kernel<<<dim3(HD/32, CC/32, EE), 256, 0, stream>>>(Wout, woutT, HD, CC, HD*CC, EC, HD);
  transpose_kernel<<<dim3(CC/32, 192/32, 1), 256, 0, stream>>>(Wkv, wkvT, CC, 192, 0, CC, 0);

  gate_kernel<<<NT / 32, 512, 0, stream>>>(x, Wg, task, ws_f, ws_i, eids, xb, bucket);

  kvproj_kernel<<<dim3(3, NT/128), 256, 0, stream>>>(xb, wkvT, kvbk, vtb);
  qproj_kernel<<<dim3(NT/128, EE), 256, 0, stream>>>(xb, winT, ws_i, bucket, qall);

  hipMemsetAsync(z, 0, (size_t)NT * EC * 2, stream);   // xb+bucket dead; z aliases them

  attn_kernel<<<dim3(NN/32, BB, 2), 256, 0, stream>>>(qall, kvbk, vtb, eids, ws_f + WS_G/4, z);

  // out = z @ W_out^T  (128x64 tiles -> 768 blocks, ~3-5/CU)
  gemm_kernel<128, 64, true><<<dim3(CC/64, NT/128), 256, 0, stream>>>(
      z, woutT, out, NT, CC, EC);

  aux_kernel<<<1, 64, 0, stream>>>(ws_f, ws_i, out);
}